// Round 2
// baseline (1548.965 us; speedup 1.0000x reference)
//
#include <hip/hip_runtime.h>
#include <math.h>

#define DD 128

// ---------------- wave helpers ----------------
__device__ __forceinline__ float wsum(float v){
  #pragma unroll
  for(int off=32; off; off>>=1) v += __shfl_xor(v, off, 64);
  return v;
}

// ---------------- CSR build ----------------
__global__ void k_count(const int* __restrict__ rows, int* __restrict__ cnt, int E){
  int e = blockIdx.x*256 + threadIdx.x;
  if(e < E) atomicAdd(&cnt[rows[e]], 1);
}

__global__ void k_block_sums(const int* __restrict__ cnt, int* __restrict__ bsum, int n){
  __shared__ int sh[256];
  int t = threadIdx.x;
  int base = blockIdx.x*1024 + t*4;
  int s = 0;
  #pragma unroll
  for(int j=0;j<4;++j){ int i=base+j; if(i<n) s += cnt[i]; }
  sh[t]=s; __syncthreads();
  for(int off=128; off; off>>=1){ if(t<off) sh[t]+=sh[t+off]; __syncthreads(); }
  if(t==0) bsum[blockIdx.x]=sh[0];
}

__global__ void k_scan_bsum(int* __restrict__ bsum, int nb){
  __shared__ int sh[1024];
  int t=threadIdx.x;
  int v = (t<nb)? bsum[t] : 0;
  sh[t]=v; __syncthreads();
  for(int off=1; off<1024; off<<=1){
    int add = (t>=off)? sh[t-off] : 0;
    __syncthreads();
    sh[t] += add;
    __syncthreads();
  }
  if(t<nb) bsum[t] = sh[t]-v;   // exclusive prefix of block sums
}

__global__ void k_scan_write(const int* __restrict__ cnt, const int* __restrict__ bexcl,
                             int* __restrict__ rstart, int n){
  __shared__ int sh[256];
  int t=threadIdx.x;
  int base = blockIdx.x*1024 + t*4;
  int v[4]; int s=0;
  #pragma unroll
  for(int j=0;j<4;++j){ v[j] = (base+j<n)? cnt[base+j]:0; s+=v[j]; }
  sh[t]=s; __syncthreads();
  for(int off=1; off<256; off<<=1){
    int add=(t>=off)? sh[t-off]:0;
    __syncthreads();
    sh[t]+=add;
    __syncthreads();
  }
  int p = bexcl[blockIdx.x] + sh[t]-s;
  #pragma unroll
  for(int j=0;j<4;++j){ p += v[j]; if(base+j<n) rstart[base+j+1]=p; }
  if(blockIdx.x==0 && t==0) rstart[0]=0;
}

__global__ void k_scatter(const int* __restrict__ rows, const int* __restrict__ cols,
                          const float* __restrict__ vals, const int* __restrict__ rstart,
                          int* __restrict__ cur, int* __restrict__ ccol, float* __restrict__ cval, int E){
  int e = blockIdx.x*256+threadIdx.x;
  if(e>=E) return;
  int r = rows[e];
  int p = rstart[r] + atomicAdd(&cur[r], 1);
  ccol[p] = cols[e];
  cval[p] = vals[e];
}

// ---------------- dense GEMM: out = scale * (A @ W), A: n x 128, W: 128 x 128 ----------------
__global__ __launch_bounds__(256) void k_gemm128(const float* __restrict__ A, const float* __restrict__ W,
                                                 float* __restrict__ out, float scale, int n){
  __shared__ float xs[16*DD];
  __shared__ float ws[32*DD];
  int t = threadIdx.x;
  int row0 = blockIdx.x*16;
  {
    int r = t>>4, c = (t&15)*8;
    float4 z = make_float4(0.f,0.f,0.f,0.f);
    float4 a0=z, a1=z;
    if(row0+r < n){
      const float4* src = (const float4*)(A + (size_t)(row0+r)*DD + c);
      a0 = src[0]; a1 = src[1];
    }
    float4* dst = (float4*)(xs + r*DD + c);
    dst[0]=a0; dst[1]=a1;
  }
  int r = t>>4;
  int j0 = (t&15)*4;
  float acc[8];
  #pragma unroll
  for(int j=0;j<8;++j) acc[j]=0.f;
  for(int k0=0;k0<DD;k0+=32){
    __syncthreads();
    {
      int kk = t>>3, cc = (t&7)*16;
      const float4* src = (const float4*)(W + (size_t)(k0+kk)*DD + cc);
      float4* dst = (float4*)(ws + kk*DD + cc);
      dst[0]=src[0]; dst[1]=src[1]; dst[2]=src[2]; dst[3]=src[3];
    }
    __syncthreads();
    #pragma unroll
    for(int k=0;k<32;++k){
      float a = xs[r*DD + k0 + k];
      float4 w0 = *(const float4*)(ws + k*DD + j0);
      float4 w1 = *(const float4*)(ws + k*DD + j0 + 64);
      acc[0] += a*w0.x; acc[1] += a*w0.y; acc[2] += a*w0.z; acc[3] += a*w0.w;
      acc[4] += a*w1.x; acc[5] += a*w1.y; acc[6] += a*w1.z; acc[7] += a*w1.w;
    }
  }
  if(row0+r < n){
    float* o = out + (size_t)(row0+r)*DD;
    *(float4*)(o + j0)      = make_float4(acc[0]*scale, acc[1]*scale, acc[2]*scale, acc[3]*scale);
    *(float4*)(o + j0 + 64) = make_float4(acc[4]*scale, acc[5]*scale, acc[6]*scale, acc[7]*scale);
  }
}

// ---------------- CSR spmm + bias + tanh (wave per row) ----------------
__global__ void k_spmm_tanh(const int* __restrict__ rs, const int* __restrict__ cols,
                            const float* __restrict__ vals, const float* __restrict__ h,
                            const float* __restrict__ bias, float* __restrict__ out, int n){
  int row = blockIdx.x*4 + (threadIdx.x>>6);
  if(row>=n) return;
  int lane = threadIdx.x & 63;
  int beg = rs[row], end = rs[row+1];
  float ax=0.f, ay=0.f;
  for(int k=beg; k<end; ++k){
    int c = cols[k]; float v = vals[k];
    float2 hh = ((const float2*)(h + (size_t)c*DD))[lane];
    ax += v*hh.x; ay += v*hh.y;
  }
  float2 b = ((const float2*)bias)[lane];
  ((float2*)(out + (size_t)row*DD))[lane] = make_float2(tanhf(ax+b.x), tanhf(ay+b.y));
}

// ---------------- per-row dot + tanh: out[i] = tanh(scale * dot(t_i, x_i)) ----------------
__global__ void k_rowdot_tanh(const float* __restrict__ t, const float* __restrict__ x,
                              float* __restrict__ out, float scale, int n){
  int row = blockIdx.x*4 + (threadIdx.x>>6);
  if(row>=n) return;
  int lane = threadIdx.x & 63;
  float2 a = ((const float2*)(t + (size_t)row*DD))[lane];
  float2 b = ((const float2*)(x + (size_t)row*DD))[lane];
  float d = a.x*b.x + a.y*b.y;
  d = wsum(d);
  if(lane==0) out[row] = tanhf(scale*d);
}

// ---------------- fused attention row kernel ----------------
__global__ void k_attn(const int* __restrict__ rs, const int* __restrict__ cols,
                       const float* __restrict__ vals, const float* __restrict__ s1,
                       const float* __restrict__ s2, const float* __restrict__ mapped,
                       float* __restrict__ out, int n){
  int row = blockIdx.x*4 + (threadIdx.x>>6);
  if(row>=n) return;
  int lane = threadIdx.x & 63;
  int beg = rs[row], end = rs[row+1];
  float s1r = s1[row];
  // pass 1: row max of leaky_relu scores (lanes parallel over edges)
  float mx = -1e30f;
  for(int k=beg+lane; k<end; k+=64){
    int c = cols[k]; float v = vals[k];
    float e = v * (s1r + s2[c]);
    e = (e >= 0.f) ? e : 0.2f*e;
    mx = fmaxf(mx, e);
  }
  #pragma unroll
  for(int off=32; off; off>>=1) mx = fmaxf(mx, __shfl_xor(mx, off, 64));
  // pass 2: unnormalized weighted gather + denominator
  float ax=0.f, ay=0.f, den=0.f;
  for(int k=beg; k<end; ++k){
    int c = cols[k]; float v = vals[k];
    float e = v * (s1r + s2[c]);
    e = (e >= 0.f) ? e : 0.2f*e;
    float ex = __expf(e - mx);
    den += ex;
    float2 m = ((const float2*)(mapped + (size_t)c*DD))[lane];
    ax += ex*m.x; ay += ex*m.y;
  }
  float inv = (end > beg) ? 1.0f/den : 0.0f;
  ((float2*)(out + (size_t)row*DD))[lane] = make_float2(ax*inv, ay*inv);
}

// ---------------- highway: y3 = tanh(s*y1*(1-g) + s*y2*g), g = relu(tanh(gp)) ----------------
__global__ void k_highway(const float* __restrict__ y1, const float* __restrict__ y2,
                          const float* __restrict__ gp, float* __restrict__ y3,
                          float s, int total4){
  int stride = gridDim.x*blockDim.x;
  for(int i=blockIdx.x*blockDim.x+threadIdx.x; i<total4; i+=stride){
    float4 a = ((const float4*)y1)[i];
    float4 b = ((const float4*)y2)[i];
    float4 g4 = ((const float4*)gp)[i];
    float4 r;
    #define HW(c) { float g = tanhf(g4.c); g = (g>0.f)?g:0.f; r.c = tanhf(s*a.c*(1.f-g) + s*b.c*g); }
    HW(x) HW(y) HW(z) HW(w)
    #undef HW
    ((float4*)y3)[i] = r;
  }
}

// ---------------- final: out = l2norm(concat(l2norm(y3), l2norm(y4), l2norm(x))) ----------------
__global__ void k_final(const float* __restrict__ y3, const float* __restrict__ y4,
                        const float* __restrict__ x, float* __restrict__ out, int n){
  int row = blockIdx.x*4 + (threadIdx.x>>6);
  if(row>=n) return;
  int lane = threadIdx.x & 63;
  float2 a = ((const float2*)(y3 + (size_t)row*DD))[lane];
  float2 b = ((const float2*)(y4 + (size_t)row*DD))[lane];
  float2 c = ((const float2*)(x  + (size_t)row*DD))[lane];
  float sa = a.x*a.x + a.y*a.y;
  float sb = b.x*b.x + b.y*b.y;
  float sc = c.x*c.x + c.y*c.y;
  #pragma unroll
  for(int off=32; off; off>>=1){
    sa += __shfl_xor(sa, off, 64);
    sb += __shfl_xor(sb, off, 64);
    sc += __shfl_xor(sc, off, 64);
  }
  float ia = rsqrtf(fmaxf(sa, 1e-12f));
  float ib = rsqrtf(fmaxf(sb, 1e-12f));
  float ic = rsqrtf(fmaxf(sc, 1e-12f));
  float tot = sa*ia*ia + sb*ib*ib + sc*ic*ic;
  float f = rsqrtf(fmaxf(tot, 1e-12f));
  float fa = ia*f, fb = ib*f, fc = ic*f;
  float2* o = (float2*)(out + (size_t)row*(3*DD));
  o[lane]     = make_float2(a.x*fa, a.y*fa);
  o[64+lane]  = make_float2(b.x*fb, b.y*fb);
  o[128+lane] = make_float2(c.x*fc, c.y*fc);
}

// ---------------- launch ----------------
extern "C" void kernel_launch(void* const* d_in, const int* in_sizes, int n_in,
                              void* d_out, int out_size, void* d_ws, size_t ws_size,
                              hipStream_t stream){
  const float* x   = (const float*)d_in[0];
  const int*   a1r = (const int*)d_in[1];
  const int*   a1c = (const int*)d_in[2];
  const float* a1v = (const float*)d_in[3];
  const int*   a2r = (const int*)d_in[4];
  const int*   a2c = (const int*)d_in[5];
  const float* a2v = (const float*)d_in[6];
  const float* w1  = (const float*)d_in[7];
  const float* b1  = (const float*)d_in[8];
  const float* watt= (const float*)d_in[9];
  const float* m1  = (const float*)d_in[10];
  const float* m2  = (const float*)d_in[11];
  const float* whw = (const float*)d_in[12];
  const float* w2  = (const float*)d_in[13];
  const float* b2  = (const float*)d_in[14];

  const int N = in_sizes[0]/DD;
  const int E = in_sizes[1];
  const float BN = (float)(1.0/sqrt(1.0+1e-3));
  const size_t NB = (size_t)N*DD;

  // workspace layout
  float* big0 = (float*)d_ws;       // N*128
  float* big1 = big0 + NB;          // N*128
  float* big2 = big1 + NB;          // N*128
  float* s1   = big2 + NB;          // N
  float* s2   = s1 + N;             // N
  int*   rs1  = (int*)(s2 + N);     // N+1
  int*   col1 = rs1 + (N+1);        // E
  float* val1 = (float*)(col1 + E); // E
  int*   rs2  = (int*)(val1 + E);   // N+1
  int*   col2 = rs2 + (N+1);        // E
  float* val2 = (float*)(col2 + E); // E
  int*   cnt  = (int*)(val2 + E);   // N
  int*   bsum = cnt + N;            // up to 1024

  const int nb = (N+1023)/1024;
  const int gE = (E+255)/256;
  const int gR = (N+3)/4;
  const int gG = (N+15)/16;
  float* out = (float*)d_out;

  // ---- CSR build for a1 ----
  hipMemsetAsync(cnt, 0, (size_t)N*4, stream);
  k_count<<<gE,256,0,stream>>>(a1r, cnt, E);
  k_block_sums<<<nb,256,0,stream>>>(cnt, bsum, N);
  k_scan_bsum<<<1,1024,0,stream>>>(bsum, nb);
  k_scan_write<<<nb,256,0,stream>>>(cnt, bsum, rs1, N);
  hipMemsetAsync(cnt, 0, (size_t)N*4, stream);
  k_scatter<<<gE,256,0,stream>>>(a1r,a1c,a1v, rs1, cnt, col1,val1, E);
  // ---- CSR build for a2 ----
  hipMemsetAsync(cnt, 0, (size_t)N*4, stream);
  k_count<<<gE,256,0,stream>>>(a2r, cnt, E);
  k_block_sums<<<nb,256,0,stream>>>(cnt, bsum, N);
  k_scan_bsum<<<1,1024,0,stream>>>(bsum, nb);
  k_scan_write<<<nb,256,0,stream>>>(cnt, bsum, rs2, N);
  hipMemsetAsync(cnt, 0, (size_t)N*4, stream);
  k_scatter<<<gE,256,0,stream>>>(a2r,a2c,a2v, rs2, cnt, col2,val2, E);

  // ---- GCN layer 1: h1 = BN*(x@w1) -> big0 ; y1 = tanh(spmm(a1,h1)+b1) -> big1 ----
  k_gemm128<<<gG,256,0,stream>>>(x, w1, big0, BN, N);
  k_spmm_tanh<<<gR,256,0,stream>>>(rs1,col1,val1, big0, b1, big1, N);

  // ---- attention scores: s1 = tanh(BN^2 * x M1 x^T), s2 likewise ----
  k_gemm128<<<gG,256,0,stream>>>(x, m1, big0, 1.f, N);
  k_rowdot_tanh<<<gR,256,0,stream>>>(big0, x, s1, BN*BN, N);
  k_gemm128<<<gG,256,0,stream>>>(x, m2, big0, 1.f, N);
  k_rowdot_tanh<<<gR,256,0,stream>>>(big0, x, s2, BN*BN, N);

  // ---- attention: mapped = BN*(x@watt) -> big0 ; y2 -> big2 ----
  k_gemm128<<<gG,256,0,stream>>>(x, watt, big0, BN, N);
  k_attn<<<gR,256,0,stream>>>(rs2,col2,val2, s1,s2, big0, big2, N);

  // ---- highway: gatepre = BN*(y2@whw) -> big0 ; y3 -> big0 ----
  k_gemm128<<<gG,256,0,stream>>>(big2, whw, big0, BN, N);
  k_highway<<<2048,256,0,stream>>>(big1, big2, big0, big0, BN, (int)(NB/4));

  // ---- GCN layer 2: h3 = BN*(y3@w2) -> big1 ; y4 = tanh(spmm(a1,h3)+b2) -> big2 ----
  k_gemm128<<<gG,256,0,stream>>>(big0, w2, big1, BN, N);
  k_spmm_tanh<<<gR,256,0,stream>>>(rs1,col1,val1, big1, b2, big2, N);

  // ---- final concat + l2norms ----
  k_final<<<gR,256,0,stream>>>(big0, big2, x, out, N);
}

// Round 3
// 1050.979 us; speedup vs baseline: 1.4738x; 1.4738x over previous
//
#include <hip/hip_runtime.h>
#include <hip/hip_fp16.h>
#include <math.h>

#define DD 128

// ---------------- wave helpers ----------------
__device__ __forceinline__ float wsum(float v){
  #pragma unroll
  for(int off=32; off; off>>=1) v += __shfl_xor(v, off, 64);
  return v;
}

// ---------------- CSR build ----------------
__global__ void k_count(const int* __restrict__ rows, int* __restrict__ cnt, int E){
  int e = blockIdx.x*256 + threadIdx.x;
  if(e < E) atomicAdd(&cnt[rows[e]], 1);
}

__global__ void k_block_sums(const int* __restrict__ cnt, int* __restrict__ bsum, int n){
  __shared__ int sh[256];
  int t = threadIdx.x;
  int base = blockIdx.x*1024 + t*4;
  int s = 0;
  #pragma unroll
  for(int j=0;j<4;++j){ int i=base+j; if(i<n) s += cnt[i]; }
  sh[t]=s; __syncthreads();
  for(int off=128; off; off>>=1){ if(t<off) sh[t]+=sh[t+off]; __syncthreads(); }
  if(t==0) bsum[blockIdx.x]=sh[0];
}

__global__ void k_scan_bsum(int* __restrict__ bsum, int nb){
  __shared__ int sh[1024];
  int t=threadIdx.x;
  int v = (t<nb)? bsum[t] : 0;
  sh[t]=v; __syncthreads();
  for(int off=1; off<1024; off<<=1){
    int add = (t>=off)? sh[t-off] : 0;
    __syncthreads();
    sh[t] += add;
    __syncthreads();
  }
  if(t<nb) bsum[t] = sh[t]-v;   // exclusive prefix of block sums
}

__global__ void k_scan_write(const int* __restrict__ cnt, const int* __restrict__ bexcl,
                             int* __restrict__ rstart, int n){
  __shared__ int sh[256];
  int t=threadIdx.x;
  int base = blockIdx.x*1024 + t*4;
  int v[4]; int s=0;
  #pragma unroll
  for(int j=0;j<4;++j){ v[j] = (base+j<n)? cnt[base+j]:0; s+=v[j]; }
  sh[t]=s; __syncthreads();
  for(int off=1; off<256; off<<=1){
    int add=(t>=off)? sh[t-off]:0;
    __syncthreads();
    sh[t]+=add;
    __syncthreads();
  }
  int p = bexcl[blockIdx.x] + sh[t]-s;
  #pragma unroll
  for(int j=0;j<4;++j){ p += v[j]; if(base+j<n) rstart[base+j+1]=p; }
  if(blockIdx.x==0 && t==0) rstart[0]=0;
}

__global__ void k_scatter(const int* __restrict__ rows, const int* __restrict__ cols,
                          const float* __restrict__ vals, const int* __restrict__ rstart,
                          int* __restrict__ cur, int* __restrict__ ccol, float* __restrict__ cval, int E){
  int e = blockIdx.x*256+threadIdx.x;
  if(e>=E) return;
  int r = rows[e];
  int p = rstart[r] + atomicAdd(&cur[r], 1);
  ccol[p] = cols[e];
  cval[p] = vals[e];
}

// ---------------- dense GEMM v2: out = scale*(A@W), A n x 128, W 128 x 128 ----------------
// block: 128 rows x 128 cols, 256 threads, thread tile 8x8, A transposed in LDS.
template<typename OT>
__global__ __launch_bounds__(256) void k_gemm128v2(const float* __restrict__ A, const float* __restrict__ W,
                                                   OT* __restrict__ out, float scale, int n){
  __shared__ float at[32][132];   // A^T chunk: [k][row], pad 132 (16B-aligned rows, 2-way read alias)
  __shared__ float wt[32][128];   // W chunk: [k][col]
  int t = threadIdx.x;
  int r0 = blockIdx.x*128;
  int tx = t & 15, ty = t >> 4;

  float acc[8][8];
  #pragma unroll
  for(int i=0;i<8;++i)
    #pragma unroll
    for(int j=0;j<8;++j) acc[i][j]=0.f;

  for(int kc=0; kc<DD; kc+=32){
    __syncthreads();
    // stage W chunk (straight copy, coalesced)
    #pragma unroll
    for(int j=0;j<4;++j){
      int flat = t + j*256;
      int kl = flat >> 5, c4 = flat & 31;
      float4 w4 = *(const float4*)(W + (size_t)(kc+kl)*DD + c4*4);
      *(float4*)&wt[kl][c4*4] = w4;
    }
    // stage A chunk transposed
    #pragma unroll
    for(int j=0;j<4;++j){
      int flat = t + j*256;
      int row = flat >> 3, k4 = flat & 7;
      float4 a4 = make_float4(0.f,0.f,0.f,0.f);
      if(r0+row < n) a4 = *(const float4*)(A + (size_t)(r0+row)*DD + kc + k4*4);
      at[k4*4+0][row]=a4.x; at[k4*4+1][row]=a4.y; at[k4*4+2][row]=a4.z; at[k4*4+3][row]=a4.w;
    }
    __syncthreads();
    #pragma unroll
    for(int k=0;k<32;++k){
      float4 a0 = *(const float4*)&at[k][tx*4];
      float4 a1 = *(const float4*)&at[k][64+tx*4];
      float4 w0 = *(const float4*)&wt[k][ty*8];
      float4 w1 = *(const float4*)&wt[k][ty*8+4];
      float av[8] = {a0.x,a0.y,a0.z,a0.w,a1.x,a1.y,a1.z,a1.w};
      float wv[8] = {w0.x,w0.y,w0.z,w0.w,w1.x,w1.y,w1.z,w1.w};
      #pragma unroll
      for(int i=0;i<8;++i)
        #pragma unroll
        for(int j=0;j<8;++j) acc[i][j] += av[i]*wv[j];
    }
  }
  // epilogue
  #pragma unroll
  for(int i=0;i<8;++i){
    int row = (i<4) ? tx*4+i : 64+tx*4+(i-4);
    if(r0+row >= n) continue;
    if constexpr (sizeof(OT)==4){
      float* o = (float*)out + (size_t)(r0+row)*DD + ty*8;
      *(float4*)o = make_float4(acc[i][0]*scale, acc[i][1]*scale, acc[i][2]*scale, acc[i][3]*scale);
      *(float4*)(o+4) = make_float4(acc[i][4]*scale, acc[i][5]*scale, acc[i][6]*scale, acc[i][7]*scale);
    } else {
      union { __half2 h[4]; float4 f; } u;
      u.h[0] = __floats2half2_rn(acc[i][0]*scale, acc[i][1]*scale);
      u.h[1] = __floats2half2_rn(acc[i][2]*scale, acc[i][3]*scale);
      u.h[2] = __floats2half2_rn(acc[i][4]*scale, acc[i][5]*scale);
      u.h[3] = __floats2half2_rn(acc[i][6]*scale, acc[i][7]*scale);
      *(float4*)((__half*)out + (size_t)(r0+row)*DD + ty*8) = u.f;
    }
  }
}

// ---------------- CSR spmm + bias + tanh (wave per row, half payload, unroll 4) ----------------
__global__ void k_spmm_tanh(const int* __restrict__ rs, const int* __restrict__ cols,
                            const float* __restrict__ vals, const __half* __restrict__ h,
                            const float* __restrict__ bias, float* __restrict__ out, int n){
  int row = blockIdx.x*4 + (threadIdx.x>>6);
  if(row>=n) return;
  int lane = threadIdx.x & 63;
  int beg = rs[row], end = rs[row+1];
  float ax=0.f, ay=0.f;
  int k = beg;
  for(; k+4<=end; k+=4){
    int c0=cols[k], c1=cols[k+1], c2=cols[k+2], c3=cols[k+3];
    float v0=vals[k], v1=vals[k+1], v2=vals[k+2], v3=vals[k+3];
    float2 h0 = __half22float2(((const __half2*)(h + (size_t)c0*DD))[lane]);
    float2 h1 = __half22float2(((const __half2*)(h + (size_t)c1*DD))[lane]);
    float2 h2 = __half22float2(((const __half2*)(h + (size_t)c2*DD))[lane]);
    float2 h3 = __half22float2(((const __half2*)(h + (size_t)c3*DD))[lane]);
    ax += v0*h0.x + v1*h1.x + v2*h2.x + v3*h3.x;
    ay += v0*h0.y + v1*h1.y + v2*h2.y + v3*h3.y;
  }
  for(; k<end; ++k){
    int c = cols[k]; float v = vals[k];
    float2 hh = __half22float2(((const __half2*)(h + (size_t)c*DD))[lane]);
    ax += v*hh.x; ay += v*hh.y;
  }
  float2 b = ((const float2*)bias)[lane];
  ((float2*)(out + (size_t)row*DD))[lane] = make_float2(tanhf(ax+b.x), tanhf(ay+b.y));
}

// ---------------- fused dual rowdot: s_i = tanh(scale * dot(t_i, x)) ----------------
__global__ void k_rowdot2(const __half* __restrict__ t1, const __half* __restrict__ t2,
                          const float* __restrict__ x, float* __restrict__ s1, float* __restrict__ s2,
                          float scale, int n){
  int row = blockIdx.x*4 + (threadIdx.x>>6);
  if(row>=n) return;
  int lane = threadIdx.x & 63;
  float2 a1 = __half22float2(((const __half2*)(t1 + (size_t)row*DD))[lane]);
  float2 a2 = __half22float2(((const __half2*)(t2 + (size_t)row*DD))[lane]);
  float2 b  = ((const float2*)(x + (size_t)row*DD))[lane];
  float d1 = a1.x*b.x + a1.y*b.y;
  float d2 = a2.x*b.x + a2.y*b.y;
  #pragma unroll
  for(int off=32; off; off>>=1){
    d1 += __shfl_xor(d1, off, 64);
    d2 += __shfl_xor(d2, off, 64);
  }
  if(lane==0){ s1[row] = tanhf(scale*d1); s2[row] = tanhf(scale*d2); }
}

// ---------------- fused attention (no max pass: scores bounded, softmax shift-invariant) ----------------
__global__ void k_attn(const int* __restrict__ rs, const int* __restrict__ cols,
                       const float* __restrict__ vals, const float* __restrict__ s1,
                       const float* __restrict__ s2, const __half* __restrict__ mapped,
                       float* __restrict__ out, int n){
  int row = blockIdx.x*4 + (threadIdx.x>>6);
  if(row>=n) return;
  int lane = threadIdx.x & 63;
  int beg = rs[row], end = rs[row+1];
  float s1r = s1[row];
  float ax=0.f, ay=0.f, den=0.f;
  int k = beg;
  for(; k+4<=end; k+=4){
    int c0=cols[k], c1=cols[k+1], c2=cols[k+2], c3=cols[k+3];
    float v0=vals[k], v1=vals[k+1], v2=vals[k+2], v3=vals[k+3];
    float e0 = v0*(s1r + s2[c0]); e0 = (e0>=0.f)? e0 : 0.2f*e0;
    float e1 = v1*(s1r + s2[c1]); e1 = (e1>=0.f)? e1 : 0.2f*e1;
    float e2 = v2*(s1r + s2[c2]); e2 = (e2>=0.f)? e2 : 0.2f*e2;
    float e3 = v3*(s1r + s2[c3]); e3 = (e3>=0.f)? e3 : 0.2f*e3;
    float2 m0 = __half22float2(((const __half2*)(mapped + (size_t)c0*DD))[lane]);
    float2 m1 = __half22float2(((const __half2*)(mapped + (size_t)c1*DD))[lane]);
    float2 m2 = __half22float2(((const __half2*)(mapped + (size_t)c2*DD))[lane]);
    float2 m3 = __half22float2(((const __half2*)(mapped + (size_t)c3*DD))[lane]);
    float x0 = __expf(e0), x1 = __expf(e1), x2 = __expf(e2), x3 = __expf(e3);
    den += x0+x1+x2+x3;
    ax += x0*m0.x + x1*m1.x + x2*m2.x + x3*m3.x;
    ay += x0*m0.y + x1*m1.y + x2*m2.y + x3*m3.y;
  }
  for(; k<end; ++k){
    int c = cols[k]; float v = vals[k];
    float e = v*(s1r + s2[c]); e = (e>=0.f)? e : 0.2f*e;
    float ex = __expf(e);
    float2 m = __half22float2(((const __half2*)(mapped + (size_t)c*DD))[lane]);
    den += ex; ax += ex*m.x; ay += ex*m.y;
  }
  float inv = (end > beg) ? 1.0f/den : 0.0f;
  ((float2*)(out + (size_t)row*DD))[lane] = make_float2(ax*inv, ay*inv);
}

// ---------------- highway: y3 = tanh(s*y1*(1-g) + s*y2*g), g = relu(tanh(gp)) ----------------
__global__ void k_highway(const float* __restrict__ y1, const float* __restrict__ y2,
                          const float* __restrict__ gp, float* __restrict__ y3,
                          float s, int total4){
  int stride = gridDim.x*blockDim.x;
  for(int i=blockIdx.x*blockDim.x+threadIdx.x; i<total4; i+=stride){
    float4 a = ((const float4*)y1)[i];
    float4 b = ((const float4*)y2)[i];
    float4 g4 = ((const float4*)gp)[i];
    float4 r;
    #define HW(c) { float g = tanhf(g4.c); g = (g>0.f)?g:0.f; r.c = tanhf(s*a.c*(1.f-g) + s*b.c*g); }
    HW(x) HW(y) HW(z) HW(w)
    #undef HW
    ((float4*)y3)[i] = r;
  }
}

// ---------------- final: out = l2norm(concat(l2norm(y3), l2norm(y4), l2norm(x))) ----------------
__global__ void k_final(const float* __restrict__ y3, const float* __restrict__ y4,
                        const float* __restrict__ x, float* __restrict__ out, int n){
  int row = blockIdx.x*4 + (threadIdx.x>>6);
  if(row>=n) return;
  int lane = threadIdx.x & 63;
  float2 a = ((const float2*)(y3 + (size_t)row*DD))[lane];
  float2 b = ((const float2*)(y4 + (size_t)row*DD))[lane];
  float2 c = ((const float2*)(x  + (size_t)row*DD))[lane];
  float sa = a.x*a.x + a.y*a.y;
  float sb = b.x*b.x + b.y*b.y;
  float sc = c.x*c.x + c.y*c.y;
  #pragma unroll
  for(int off=32; off; off>>=1){
    sa += __shfl_xor(sa, off, 64);
    sb += __shfl_xor(sb, off, 64);
    sc += __shfl_xor(sc, off, 64);
  }
  float ia = rsqrtf(fmaxf(sa, 1e-12f));
  float ib = rsqrtf(fmaxf(sb, 1e-12f));
  float ic = rsqrtf(fmaxf(sc, 1e-12f));
  float tot = sa*ia*ia + sb*ib*ib + sc*ic*ic;
  float f = rsqrtf(fmaxf(tot, 1e-12f));
  float fa = ia*f, fb = ib*f, fc = ic*f;
  float2* o = (float2*)(out + (size_t)row*(3*DD));
  o[lane]     = make_float2(a.x*fa, a.y*fa);
  o[64+lane]  = make_float2(b.x*fb, b.y*fb);
  o[128+lane] = make_float2(c.x*fc, c.y*fc);
}

// ---------------- launch ----------------
extern "C" void kernel_launch(void* const* d_in, const int* in_sizes, int n_in,
                              void* d_out, int out_size, void* d_ws, size_t ws_size,
                              hipStream_t stream){
  const float* x   = (const float*)d_in[0];
  const int*   a1r = (const int*)d_in[1];
  const int*   a1c = (const int*)d_in[2];
  const float* a1v = (const float*)d_in[3];
  const int*   a2r = (const int*)d_in[4];
  const int*   a2c = (const int*)d_in[5];
  const float* a2v = (const float*)d_in[6];
  const float* w1  = (const float*)d_in[7];
  const float* b1  = (const float*)d_in[8];
  const float* watt= (const float*)d_in[9];
  const float* m1  = (const float*)d_in[10];
  const float* m2  = (const float*)d_in[11];
  const float* whw = (const float*)d_in[12];
  const float* w2  = (const float*)d_in[13];
  const float* b2  = (const float*)d_in[14];

  const int N = in_sizes[0]/DD;
  const int E = in_sizes[1];
  const float BN = (float)(1.0/sqrt(1.0+1e-3));
  const size_t NB = (size_t)N*DD;

  // workspace layout (half payloads alias into the f32 big buffers)
  float* B0 = (float*)d_ws;         // N*128 f32  (t1h/t2h as half | mapped-half | gp | y3)
  float* B1 = B0 + NB;              // N*128 f32  (y1 | y4)
  float* B2 = B1 + NB;              // N*128 f32  (h1h as half | y2 | h3h as half)
  float* s1 = B2 + NB;              // N
  float* s2 = s1 + N;               // N
  int*   rs1  = (int*)(s2 + N);     // N+1
  int*   col1 = rs1 + (N+1);        // E
  float* val1 = (float*)(col1 + E); // E
  int*   rs2  = (int*)(val1 + E);   // N+1
  int*   col2 = rs2 + (N+1);        // E
  float* val2 = (float*)(col2 + E); // E
  int*   cnt  = (int*)(val2 + E);   // N
  int*   bsum = cnt + N;            // up to 1024

  __half* H0a = (__half*)B0;        // N*128 half
  __half* H0b = H0a + NB;           // N*128 half (second half of B0)
  __half* H2  = (__half*)B2;        // N*128 half

  const int nb = (N+1023)/1024;
  const int gE = (E+255)/256;
  const int gR = (N+3)/4;
  const int gG = (N+127)/128;
  float* out = (float*)d_out;

  // ---- CSR build for a1 ----
  hipMemsetAsync(cnt, 0, (size_t)N*4, stream);
  k_count<<<gE,256,0,stream>>>(a1r, cnt, E);
  k_block_sums<<<nb,256,0,stream>>>(cnt, bsum, N);
  k_scan_bsum<<<1,1024,0,stream>>>(bsum, nb);
  k_scan_write<<<nb,256,0,stream>>>(cnt, bsum, rs1, N);
  hipMemsetAsync(cnt, 0, (size_t)N*4, stream);
  k_scatter<<<gE,256,0,stream>>>(a1r,a1c,a1v, rs1, cnt, col1,val1, E);
  // ---- CSR build for a2 ----
  hipMemsetAsync(cnt, 0, (size_t)N*4, stream);
  k_count<<<gE,256,0,stream>>>(a2r, cnt, E);
  k_block_sums<<<nb,256,0,stream>>>(cnt, bsum, N);
  k_scan_bsum<<<1,1024,0,stream>>>(bsum, nb);
  k_scan_write<<<nb,256,0,stream>>>(cnt, bsum, rs2, N);
  hipMemsetAsync(cnt, 0, (size_t)N*4, stream);
  k_scatter<<<gE,256,0,stream>>>(a2r,a2c,a2v, rs2, cnt, col2,val2, E);

  // ---- GCN layer 1: h1h = half(BN*(x@w1)) -> H2 ; y1 = tanh(spmm(a1,h1h)+b1) -> B1 ----
  k_gemm128v2<__half><<<gG,256,0,stream>>>(x, w1, H2, BN, N);
  k_spmm_tanh<<<gR,256,0,stream>>>(rs1,col1,val1, H2, b1, B1, N);

  // ---- attention scores: t1h = x@m1, t2h = x@m2 (half), then fused rowdots ----
  k_gemm128v2<__half><<<gG,256,0,stream>>>(x, m1, H0a, 1.f, N);
  k_gemm128v2<__half><<<gG,256,0,stream>>>(x, m2, H0b, 1.f, N);
  k_rowdot2<<<gR,256,0,stream>>>(H0a, H0b, x, s1, s2, BN*BN, N);

  // ---- attention: mapped = half(BN*(x@watt)) -> H0a ; y2 -> B2 ----
  k_gemm128v2<__half><<<gG,256,0,stream>>>(x, watt, H0a, BN, N);
  k_attn<<<gR,256,0,stream>>>(rs2,col2,val2, s1,s2, H0a, B2, N);

  // ---- highway: gp = BN*(y2@whw) -> B0 ; y3 -> B0 (in-place) ----
  k_gemm128v2<float><<<gG,256,0,stream>>>(B2, whw, B0, BN, N);
  k_highway<<<2048,256,0,stream>>>(B1, B2, B0, B0, BN, (int)(NB/4));

  // ---- GCN layer 2: h3h = half(BN*(y3@w2)) -> H2 ; y4 = tanh(spmm(a1,h3h)+b2) -> B1 ----
  k_gemm128v2<__half><<<gG,256,0,stream>>>(B0, w2, H2, BN, N);
  k_spmm_tanh<<<gR,256,0,stream>>>(rs1,col1,val1, H2, b2, B1, N);

  // ---- final concat + l2norms ----
  k_final<<<gR,256,0,stream>>>(B0, B1, x, out, N);
}

// Round 4
// 1006.467 us; speedup vs baseline: 1.5390x; 1.0442x over previous
//
#include <hip/hip_runtime.h>
#include <hip/hip_fp16.h>
#include <math.h>

#define DD 128

// ---------------- CSR build (dual: a1 and a2 in one pass) ----------------
__global__ void k_count2(const int* __restrict__ r1, const int* __restrict__ r2,
                         int* __restrict__ cnt, int n, int E){
  int e = blockIdx.x*256 + threadIdx.x;
  if(e < E){
    atomicAdd(&cnt[r1[e]], 1);
    atomicAdd(&cnt[n + r2[e]], 1);
  }
}

// grid = 2*nb blocks; blocks [0,nb) -> half0, [nb,2nb) -> half1
__global__ void k_block_sums2(const int* __restrict__ cnt, int* __restrict__ bsum, int n, int nb){
  __shared__ int sh[256];
  int half = blockIdx.x / nb, lb = blockIdx.x % nb;
  const int* src = cnt + (size_t)half*n;
  int t = threadIdx.x;
  int base = lb*1024 + t*4;
  int s = 0;
  #pragma unroll
  for(int j=0;j<4;++j){ int i=base+j; if(i<n) s += src[i]; }
  sh[t]=s; __syncthreads();
  for(int off=128; off; off>>=1){ if(t<off) sh[t]+=sh[t+off]; __syncthreads(); }
  if(t==0) bsum[blockIdx.x]=sh[0];
}

// one block, 1024 threads: segment 0 = threads [0,512) scans bsum[0..nb),
// segment 1 = threads [512,1024) scans bsum[nb..2nb).  requires nb <= 512.
__global__ void k_scan_bsum2(int* __restrict__ bsum, int nb){
  __shared__ int sh[1024];
  int t = threadIdx.x;
  int seg = t >> 9, st = t & 511;
  int v = (st<nb)? bsum[seg*nb+st] : 0;
  sh[t]=v; __syncthreads();
  for(int off=1; off<512; off<<=1){
    int add = (st>=off)? sh[t-off] : 0;
    __syncthreads();
    sh[t] += add;
    __syncthreads();
  }
  if(st<nb) bsum[seg*nb+st] = sh[t]-v;   // exclusive prefix within segment
}

__global__ void k_scan_write2(const int* __restrict__ cnt, const int* __restrict__ bexcl,
                              int* __restrict__ rs, int n, int nb){
  __shared__ int sh[256];
  int half = blockIdx.x / nb, lb = blockIdx.x % nb;
  const int* src = cnt + (size_t)half*n;
  int* rdst = rs + (size_t)half*(n+1);
  int t=threadIdx.x;
  int base = lb*1024 + t*4;
  int v[4]; int s=0;
  #pragma unroll
  for(int j=0;j<4;++j){ v[j] = (base+j<n)? src[base+j]:0; s+=v[j]; }
  sh[t]=s; __syncthreads();
  for(int off=1; off<256; off<<=1){
    int add=(t>=off)? sh[t-off]:0;
    __syncthreads();
    sh[t]+=add;
    __syncthreads();
  }
  int p = bexcl[blockIdx.x] + sh[t]-s;
  #pragma unroll
  for(int j=0;j<4;++j){ p += v[j]; if(base+j<n) rdst[base+j+1]=p; }
  if(lb==0 && t==0) rdst[0]=0;
}

// packed scatter: a1 -> int2{col, val bits}; a2 -> col only (vals are all 1.0)
__global__ void k_scatter2(const int* __restrict__ r1, const int* __restrict__ c1, const float* __restrict__ v1,
                           const int* __restrict__ r2, const int* __restrict__ c2,
                           const int* __restrict__ rs, int* __restrict__ cur,
                           int2* __restrict__ e1, int* __restrict__ e2, int n, int E){
  int e = blockIdx.x*256+threadIdx.x;
  if(e>=E) return;
  {
    int r = r1[e];
    int p = rs[r] + atomicAdd(&cur[r], 1);
    e1[p] = make_int2(c1[e], __float_as_int(v1[e]));
  }
  {
    int r = r2[e];
    int p = rs[(n+1)+r] + atomicAdd(&cur[n+r], 1);
    e2[p] = c2[e];
  }
}

// ---------------- dense GEMM: out = scale*(A@W), A n x 128, W 128 x 128 ----------------
template<typename OT>
__global__ __launch_bounds__(256) void k_gemm128v2(const float* __restrict__ A, const float* __restrict__ W,
                                                   OT* __restrict__ out, float scale, int n){
  __shared__ float at[32][132];
  __shared__ float wt[32][128];
  int t = threadIdx.x;
  int r0 = blockIdx.x*128;
  int tx = t & 15, ty = t >> 4;

  float acc[8][8];
  #pragma unroll
  for(int i=0;i<8;++i)
    #pragma unroll
    for(int j=0;j<8;++j) acc[i][j]=0.f;

  for(int kc=0; kc<DD; kc+=32){
    __syncthreads();
    #pragma unroll
    for(int j=0;j<4;++j){
      int flat = t + j*256;
      int kl = flat >> 5, c4 = flat & 31;
      float4 w4 = *(const float4*)(W + (size_t)(kc+kl)*DD + c4*4);
      *(float4*)&wt[kl][c4*4] = w4;
    }
    #pragma unroll
    for(int j=0;j<4;++j){
      int flat = t + j*256;
      int row = flat >> 3, k4 = flat & 7;
      float4 a4 = make_float4(0.f,0.f,0.f,0.f);
      if(r0+row < n) a4 = *(const float4*)(A + (size_t)(r0+row)*DD + kc + k4*4);
      at[k4*4+0][row]=a4.x; at[k4*4+1][row]=a4.y; at[k4*4+2][row]=a4.z; at[k4*4+3][row]=a4.w;
    }
    __syncthreads();
    #pragma unroll
    for(int k=0;k<32;++k){
      float4 a0 = *(const float4*)&at[k][tx*4];
      float4 a1 = *(const float4*)&at[k][64+tx*4];
      float4 w0 = *(const float4*)&wt[k][ty*8];
      float4 w1 = *(const float4*)&wt[k][ty*8+4];
      float av[8] = {a0.x,a0.y,a0.z,a0.w,a1.x,a1.y,a1.z,a1.w};
      float wv[8] = {w0.x,w0.y,w0.z,w0.w,w1.x,w1.y,w1.z,w1.w};
      #pragma unroll
      for(int i=0;i<8;++i)
        #pragma unroll
        for(int j=0;j<8;++j) acc[i][j] += av[i]*wv[j];
    }
  }
  #pragma unroll
  for(int i=0;i<8;++i){
    int row = (i<4) ? tx*4+i : 64+tx*4+(i-4);
    if(r0+row >= n) continue;
    if constexpr (sizeof(OT)==4){
      float* o = (float*)out + (size_t)(r0+row)*DD + ty*8;
      *(float4*)o = make_float4(acc[i][0]*scale, acc[i][1]*scale, acc[i][2]*scale, acc[i][3]*scale);
      *(float4*)(o+4) = make_float4(acc[i][4]*scale, acc[i][5]*scale, acc[i][6]*scale, acc[i][7]*scale);
    } else {
      union { __half2 h[4]; float4 f; } u;
      u.h[0] = __floats2half2_rn(acc[i][0]*scale, acc[i][1]*scale);
      u.h[1] = __floats2half2_rn(acc[i][2]*scale, acc[i][3]*scale);
      u.h[2] = __floats2half2_rn(acc[i][4]*scale, acc[i][5]*scale);
      u.h[3] = __floats2half2_rn(acc[i][6]*scale, acc[i][7]*scale);
      *(float4*)((__half*)out + (size_t)(r0+row)*DD + ty*8) = u.f;
    }
  }
}

// ---------------- fused scores: s_w[i] = tanh(scale * x_i . (x_i @ m_w)), w = 1,2 ----------------
__global__ __launch_bounds__(256) void k_gemm_scores(const float* __restrict__ x,
                                                     const float* __restrict__ m1, const float* __restrict__ m2,
                                                     float* __restrict__ s1, float* __restrict__ s2,
                                                     float scale, int n){
  __shared__ float at[32][132];
  __shared__ float wt[32][128];
  __shared__ float red[16][132];
  int t = threadIdx.x;
  int r0 = blockIdx.x*128;
  int tx = t & 15, ty = t >> 4;

  for(int wsel=0; wsel<2; ++wsel){
    const float* W = wsel ? m2 : m1;
    float acc[8][8];
    #pragma unroll
    for(int i=0;i<8;++i)
      #pragma unroll
      for(int j=0;j<8;++j) acc[i][j]=0.f;

    for(int kc=0; kc<DD; kc+=32){
      __syncthreads();
      #pragma unroll
      for(int j=0;j<4;++j){
        int flat = t + j*256;
        int kl = flat >> 5, c4 = flat & 31;
        float4 w4 = *(const float4*)(W + (size_t)(kc+kl)*DD + c4*4);
        *(float4*)&wt[kl][c4*4] = w4;
      }
      #pragma unroll
      for(int j=0;j<4;++j){
        int flat = t + j*256;
        int row = flat >> 3, k4 = flat & 7;
        float4 a4 = make_float4(0.f,0.f,0.f,0.f);
        if(r0+row < n) a4 = *(const float4*)(x + (size_t)(r0+row)*DD + kc + k4*4);
        at[k4*4+0][row]=a4.x; at[k4*4+1][row]=a4.y; at[k4*4+2][row]=a4.z; at[k4*4+3][row]=a4.w;
      }
      __syncthreads();
      #pragma unroll
      for(int k=0;k<32;++k){
        float4 a0 = *(const float4*)&at[k][tx*4];
        float4 a1 = *(const float4*)&at[k][64+tx*4];
        float4 w0 = *(const float4*)&wt[k][ty*8];
        float4 w1 = *(const float4*)&wt[k][ty*8+4];
        float av[8] = {a0.x,a0.y,a0.z,a0.w,a1.x,a1.y,a1.z,a1.w};
        float wv[8] = {w0.x,w0.y,w0.z,w0.w,w1.x,w1.y,w1.z,w1.w};
        #pragma unroll
        for(int i=0;i<8;++i)
          #pragma unroll
          for(int j=0;j<8;++j) acc[i][j] += av[i]*wv[j];
      }
    }
    // per-row partial dot with x over this thread's 8 cols
    #pragma unroll
    for(int i=0;i<8;++i){
      int row = (i<4) ? tx*4+i : 64+tx*4+(i-4);
      float pd = 0.f;
      if(r0+row < n){
        float4 xa = *(const float4*)(x + (size_t)(r0+row)*DD + ty*8);
        float4 xb = *(const float4*)(x + (size_t)(r0+row)*DD + ty*8 + 4);
        pd = acc[i][0]*xa.x + acc[i][1]*xa.y + acc[i][2]*xa.z + acc[i][3]*xa.w
           + acc[i][4]*xb.x + acc[i][5]*xb.y + acc[i][6]*xb.z + acc[i][7]*xb.w;
      }
      red[ty][row] = pd;
    }
    __syncthreads();
    if(t < 128 && r0+t < n){
      float s = 0.f;
      #pragma unroll
      for(int j=0;j<16;++j) s += red[j][t];
      (wsel ? s2 : s1)[r0+t] = tanhf(scale*s);
    }
  }
}

// ---------------- fused highway GEMM: gp = bn*(y2@W); g=relu(tanh(gp)); y3=tanh(bn*(y1*(1-g)+y2*g)) ----------------
__global__ __launch_bounds__(256) void k_gemm_hw(const float* __restrict__ A /*y2*/, const float* __restrict__ W,
                                                 const float* __restrict__ y1, float* __restrict__ y3,
                                                 float bn, int n){
  __shared__ float at[32][132];
  __shared__ float wt[32][128];
  int t = threadIdx.x;
  int r0 = blockIdx.x*128;
  int tx = t & 15, ty = t >> 4;

  float acc[8][8];
  #pragma unroll
  for(int i=0;i<8;++i)
    #pragma unroll
    for(int j=0;j<8;++j) acc[i][j]=0.f;

  for(int kc=0; kc<DD; kc+=32){
    __syncthreads();
    #pragma unroll
    for(int j=0;j<4;++j){
      int flat = t + j*256;
      int kl = flat >> 5, c4 = flat & 31;
      float4 w4 = *(const float4*)(W + (size_t)(kc+kl)*DD + c4*4);
      *(float4*)&wt[kl][c4*4] = w4;
    }
    #pragma unroll
    for(int j=0;j<4;++j){
      int flat = t + j*256;
      int row = flat >> 3, k4 = flat & 7;
      float4 a4 = make_float4(0.f,0.f,0.f,0.f);
      if(r0+row < n) a4 = *(const float4*)(A + (size_t)(r0+row)*DD + kc + k4*4);
      at[k4*4+0][row]=a4.x; at[k4*4+1][row]=a4.y; at[k4*4+2][row]=a4.z; at[k4*4+3][row]=a4.w;
    }
    __syncthreads();
    #pragma unroll
    for(int k=0;k<32;++k){
      float4 a0 = *(const float4*)&at[k][tx*4];
      float4 a1 = *(const float4*)&at[k][64+tx*4];
      float4 w0 = *(const float4*)&wt[k][ty*8];
      float4 w1 = *(const float4*)&wt[k][ty*8+4];
      float av[8] = {a0.x,a0.y,a0.z,a0.w,a1.x,a1.y,a1.z,a1.w};
      float wv[8] = {w0.x,w0.y,w0.z,w0.w,w1.x,w1.y,w1.z,w1.w};
      #pragma unroll
      for(int i=0;i<8;++i)
        #pragma unroll
        for(int j=0;j<8;++j) acc[i][j] += av[i]*wv[j];
    }
  }
  #pragma unroll
  for(int i=0;i<8;++i){
    int row = (i<4) ? tx*4+i : 64+tx*4+(i-4);
    if(r0+row >= n) continue;
    const float* p1 = y1 + (size_t)(r0+row)*DD + ty*8;
    const float* p2 = A  + (size_t)(r0+row)*DD + ty*8;
    float4 y1a = *(const float4*)p1, y1b = *(const float4*)(p1+4);
    float4 y2a = *(const float4*)p2, y2b = *(const float4*)(p2+4);
    float v1[8] = {y1a.x,y1a.y,y1a.z,y1a.w,y1b.x,y1b.y,y1b.z,y1b.w};
    float v2[8] = {y2a.x,y2a.y,y2a.z,y2a.w,y2b.x,y2b.y,y2b.z,y2b.w};
    float r[8];
    #pragma unroll
    for(int j=0;j<8;++j){
      float g = tanhf(bn*acc[i][j]);
      g = (g>0.f)? g : 0.f;
      r[j] = tanhf(bn*(v1[j]*(1.f-g) + v2[j]*g));
    }
    float* o = y3 + (size_t)(r0+row)*DD + ty*8;
    *(float4*)o     = make_float4(r[0],r[1],r[2],r[3]);
    *(float4*)(o+4) = make_float4(r[4],r[5],r[6],r[7]);
  }
}

// ---------------- CSR spmm + bias + tanh (wave per row, half payload, packed edges) ----------------
__global__ void k_spmm_tanh(const int* __restrict__ rs, const int2* __restrict__ e1,
                            const __half* __restrict__ h, const float* __restrict__ bias,
                            float* __restrict__ out, int n){
  int row = blockIdx.x*4 + (threadIdx.x>>6);
  if(row>=n) return;
  int lane = threadIdx.x & 63;
  int beg = rs[row], end = rs[row+1];
  float ax=0.f, ay=0.f;
  int k = beg;
  for(; k+4<=end; k+=4){
    int2 cv0=e1[k], cv1=e1[k+1], cv2=e1[k+2], cv3=e1[k+3];
    float v0=__int_as_float(cv0.y), v1=__int_as_float(cv1.y), v2=__int_as_float(cv2.y), v3=__int_as_float(cv3.y);
    float2 h0 = __half22float2(((const __half2*)(h + (size_t)cv0.x*DD))[lane]);
    float2 h1 = __half22float2(((const __half2*)(h + (size_t)cv1.x*DD))[lane]);
    float2 h2 = __half22float2(((const __half2*)(h + (size_t)cv2.x*DD))[lane]);
    float2 h3 = __half22float2(((const __half2*)(h + (size_t)cv3.x*DD))[lane]);
    ax += v0*h0.x + v1*h1.x + v2*h2.x + v3*h3.x;
    ay += v0*h0.y + v1*h1.y + v2*h2.y + v3*h3.y;
  }
  for(; k<end; ++k){
    int2 cv = e1[k];
    float v = __int_as_float(cv.y);
    float2 hh = __half22float2(((const __half2*)(h + (size_t)cv.x*DD))[lane]);
    ax += v*hh.x; ay += v*hh.y;
  }
  float2 b = ((const float2*)bias)[lane];
  ((float2*)(out + (size_t)row*DD))[lane] = make_float2(tanhf(ax+b.x), tanhf(ay+b.y));
}

// ---------------- fused attention (vals==1; no max pass, scores bounded) ----------------
__global__ void k_attn(const int* __restrict__ rs, const int* __restrict__ e2,
                       const float* __restrict__ s1, const float* __restrict__ s2,
                       const __half* __restrict__ mapped, float* __restrict__ out, int n){
  int row = blockIdx.x*4 + (threadIdx.x>>6);
  if(row>=n) return;
  int lane = threadIdx.x & 63;
  int beg = rs[row], end = rs[row+1];
  float s1r = s1[row];
  float ax=0.f, ay=0.f, den=0.f;
  int k = beg;
  for(; k+4<=end; k+=4){
    int c0=e2[k], c1=e2[k+1], c2=e2[k+2], c3=e2[k+3];
    float e0 = s1r + s2[c0]; e0 = (e0>=0.f)? e0 : 0.2f*e0;
    float e1 = s1r + s2[c1]; e1 = (e1>=0.f)? e1 : 0.2f*e1;
    float e2v = s1r + s2[c2]; e2v = (e2v>=0.f)? e2v : 0.2f*e2v;
    float e3 = s1r + s2[c3]; e3 = (e3>=0.f)? e3 : 0.2f*e3;
    float2 m0 = __half22float2(((const __half2*)(mapped + (size_t)c0*DD))[lane]);
    float2 m1 = __half22float2(((const __half2*)(mapped + (size_t)c1*DD))[lane]);
    float2 m2 = __half22float2(((const __half2*)(mapped + (size_t)c2*DD))[lane]);
    float2 m3 = __half22float2(((const __half2*)(mapped + (size_t)c3*DD))[lane]);
    float x0 = __expf(e0), x1 = __expf(e1), x2 = __expf(e2v), x3 = __expf(e3);
    den += x0+x1+x2+x3;
    ax += x0*m0.x + x1*m1.x + x2*m2.x + x3*m3.x;
    ay += x0*m0.y + x1*m1.y + x2*m2.y + x3*m3.y;
  }
  for(; k<end; ++k){
    int c = e2[k];
    float e = s1r + s2[c]; e = (e>=0.f)? e : 0.2f*e;
    float ex = __expf(e);
    float2 m = __half22float2(((const __half2*)(mapped + (size_t)c*DD))[lane]);
    den += ex; ax += ex*m.x; ay += ex*m.y;
  }
  float inv = (end > beg) ? 1.0f/den : 0.0f;
  ((float2*)(out + (size_t)row*DD))[lane] = make_float2(ax*inv, ay*inv);
}

// ---------------- final: out = l2norm(concat(l2norm(y3), l2norm(y4), l2norm(x))) ----------------
__global__ void k_final(const float* __restrict__ y3, const float* __restrict__ y4,
                        const float* __restrict__ x, float* __restrict__ out, int n){
  int row = blockIdx.x*4 + (threadIdx.x>>6);
  if(row>=n) return;
  int lane = threadIdx.x & 63;
  float2 a = ((const float2*)(y3 + (size_t)row*DD))[lane];
  float2 b = ((const float2*)(y4 + (size_t)row*DD))[lane];
  float2 c = ((const float2*)(x  + (size_t)row*DD))[lane];
  float sa = a.x*a.x + a.y*a.y;
  float sb = b.x*b.x + b.y*b.y;
  float sc = c.x*c.x + c.y*c.y;
  #pragma unroll
  for(int off=32; off; off>>=1){
    sa += __shfl_xor(sa, off, 64);
    sb += __shfl_xor(sb, off, 64);
    sc += __shfl_xor(sc, off, 64);
  }
  float ia = rsqrtf(fmaxf(sa, 1e-12f));
  float ib = rsqrtf(fmaxf(sb, 1e-12f));
  float ic = rsqrtf(fmaxf(sc, 1e-12f));
  float tot = sa*ia*ia + sb*ib*ib + sc*ic*ic;
  float f = rsqrtf(fmaxf(tot, 1e-12f));
  float fa = ia*f, fb = ib*f, fc = ic*f;
  float2* o = (float2*)(out + (size_t)row*(3*DD));
  o[lane]     = make_float2(a.x*fa, a.y*fa);
  o[64+lane]  = make_float2(b.x*fb, b.y*fb);
  o[128+lane] = make_float2(c.x*fc, c.y*fc);
}

// ---------------- launch ----------------
extern "C" void kernel_launch(void* const* d_in, const int* in_sizes, int n_in,
                              void* d_out, int out_size, void* d_ws, size_t ws_size,
                              hipStream_t stream){
  const float* x   = (const float*)d_in[0];
  const int*   a1r = (const int*)d_in[1];
  const int*   a1c = (const int*)d_in[2];
  const float* a1v = (const float*)d_in[3];
  const int*   a2r = (const int*)d_in[4];
  const int*   a2c = (const int*)d_in[5];
  const float* w1  = (const float*)d_in[7];
  const float* b1  = (const float*)d_in[8];
  const float* watt= (const float*)d_in[9];
  const float* m1  = (const float*)d_in[10];
  const float* m2  = (const float*)d_in[11];
  const float* whw = (const float*)d_in[12];
  const float* w2  = (const float*)d_in[13];
  const float* b2  = (const float*)d_in[14];

  const int N = in_sizes[0]/DD;
  const int E = in_sizes[1];
  const float BN = (float)(1.0/sqrt(1.0+1e-3));
  const size_t NB = (size_t)N*DD;

  // workspace layout
  float* B0 = (float*)d_ws;         // N*128 f32  (mapped-half | y3)
  float* B1 = B0 + NB;              // N*128 f32  (y1 | y4)
  float* B2 = B1 + NB;              // N*128 f32  (h1h half | y2 | h3h half)
  float* s1 = B2 + NB;              // N
  float* s2 = s1 + N;               // N
  int*   rs   = (int*)(s2 + N);     // 2*(N+1)   [rs1 | rs2]
  int2*  e1   = (int2*)(rs + 2*(N+1)); // E packed {col, val}
  int*   e2   = (int*)(e1 + E);     // E cols (vals are 1.0)
  int*   cnt  = e2 + E;             // 2*N (counts, then cursors)
  int*   bsum = cnt + 2*N;          // up to 1024

  __half* H0 = (__half*)B0;         // N*128 half (mapped)
  __half* H2 = (__half*)B2;         // N*128 half (h1h / h3h)

  const int nb = (N+1023)/1024;
  const int gE = (E+255)/256;
  const int gR = (N+3)/4;
  const int gG = (N+127)/128;
  float* out = (float*)d_out;

  // ---- dual CSR build ----
  hipMemsetAsync(cnt, 0, (size_t)2*N*4, stream);
  k_count2<<<gE,256,0,stream>>>(a1r, a2r, cnt, N, E);
  k_block_sums2<<<2*nb,256,0,stream>>>(cnt, bsum, N, nb);
  k_scan_bsum2<<<1,1024,0,stream>>>(bsum, nb);
  k_scan_write2<<<2*nb,256,0,stream>>>(cnt, bsum, rs, N, nb);
  hipMemsetAsync(cnt, 0, (size_t)2*N*4, stream);
  k_scatter2<<<gE,256,0,stream>>>(a1r,a1c,a1v, a2r,a2c, rs, cnt, e1, e2, N, E);

  // ---- GCN layer 1: h1h = half(BN*(x@w1)) -> H2 ; y1 = tanh(spmm(a1,h1h)+b1) -> B1 ----
  k_gemm128v2<__half><<<gG,256,0,stream>>>(x, w1, H2, BN, N);
  k_spmm_tanh<<<gR,256,0,stream>>>(rs, e1, H2, b1, B1, N);

  // ---- attention scores (fused m1,m2 GEMM + rowdots) ----
  k_gemm_scores<<<gG,256,0,stream>>>(x, m1, m2, s1, s2, BN*BN, N);

  // ---- attention: mapped = half(BN*(x@watt)) -> H0 ; y2 -> B2 ----
  k_gemm128v2<__half><<<gG,256,0,stream>>>(x, watt, H0, BN, N);
  k_attn<<<gR,256,0,stream>>>(rs+(N+1), e2, s1, s2, H0, B2, N);

  // ---- highway fused into whw GEMM: y3 -> B0 ----
  k_gemm_hw<<<gG,256,0,stream>>>(B2, whw, B1, B0, BN, N);

  // ---- GCN layer 2: h3h = half(BN*(y3@w2)) -> H2 ; y4 = tanh(spmm(a1,h3h)+b2) -> B1 ----
  k_gemm128v2<__half><<<gG,256,0,stream>>>(B0, w2, H2, BN, N);
  k_spmm_tanh<<<gR,256,0,stream>>>(rs, e1, H2, b2, B1, N);

  // ---- final concat + l2norms ----
  k_final<<<gR,256,0,stream>>>(B0, B1, x, out, N);
}

// Round 5
// 815.530 us; speedup vs baseline: 1.8993x; 1.2341x over previous
//
#include <hip/hip_runtime.h>
#include <hip/hip_fp16.h>
#include <math.h>

#define DD 128
#define BSH 9            // bucket shift: 512 rows per bucket

// ================= CSR build via bucket counting-sort =================
// bucket(r) = r >> BSH.  All global writes are coalesced or L2-window-local.

// per-tile histograms over 256 buckets, both graphs
__global__ void k_hist(const int* __restrict__ r1, const int* __restrict__ r2,
                       int* __restrict__ hist, int E, int tile, int nt){
  __shared__ int h1[256], h2[256];
  int t = threadIdx.x;
  h1[t]=0; h2[t]=0; __syncthreads();
  int e0 = blockIdx.x*tile, e1 = min(e0+tile, E);
  for(int e=e0+t; e<e1; e+=256){
    atomicAdd(&h1[r1[e]>>BSH], 1);
    atomicAdd(&h2[r2[e]>>BSH], 1);
  }
  __syncthreads();
  hist[(size_t)blockIdx.x*256 + t] = h1[t];
  hist[(size_t)nt*256 + (size_t)blockIdx.x*256 + t] = h2[t];
}

// per-bucket column scan over tiles: hist -> exclusive prefix (in place), colsum out
__global__ void k_colscan(int* __restrict__ hist, int* __restrict__ colsum, int nt){
  __shared__ int sh[256];
  int g = blockIdx.x>>8, b = blockIdx.x&255;
  int t = threadIdx.x;
  int* H = hist + (size_t)g*nt*256;
  int v = (t<nt)? H[(size_t)t*256+b] : 0;
  sh[t]=v; __syncthreads();
  for(int off=1; off<256; off<<=1){
    int add = (t>=off)? sh[t-off] : 0;
    __syncthreads(); sh[t]+=add; __syncthreads();
  }
  if(t<nt) H[(size_t)t*256+b] = sh[t]-v;
  if(t==255) colsum[g*256+b] = sh[255];
}

// scan bucket totals -> bucket bases (2 segments of 256), base[g*257+256] = total
__global__ void k_basescan(const int* __restrict__ colsum, int* __restrict__ base){
  __shared__ int sh[512];
  int t = threadIdx.x;
  int g = t>>8, st = t&255;
  int v = colsum[t];
  sh[t]=v; __syncthreads();
  for(int off=1; off<256; off<<=1){
    int add = (st>=off)? sh[t-off] : 0;
    __syncthreads(); sh[t]+=add; __syncthreads();
  }
  base[g*257+st] = sh[t]-v;
  if(st==255) base[g*257+256] = sh[t];
}

// partition edges into bucket-contiguous staging (coalesced-run writes)
// st1: {(lrow<<17)|col, val bits}; st2: (lrow<<17)|col  (a2 vals are all 1.0)
__global__ void k_partition(const int* __restrict__ r1, const int* __restrict__ c1, const float* __restrict__ v1,
                            const int* __restrict__ r2, const int* __restrict__ c2,
                            const int* __restrict__ hist, const int* __restrict__ base,
                            int2* __restrict__ st1, int* __restrict__ st2, int E, int tile, int nt){
  __shared__ int l1[256], l2[256];
  int t = threadIdx.x;
  l1[t]=0; l2[t]=0; __syncthreads();
  int bx = blockIdx.x;
  int e0 = bx*tile, e1e = min(e0+tile, E);
  const int* off1 = hist + (size_t)bx*256;
  const int* off2 = hist + (size_t)nt*256 + (size_t)bx*256;
  for(int e=e0+t; e<e1e; e+=256){
    {
      int r = r1[e]; int b = r>>BSH;
      int rank = atomicAdd(&l1[b], 1);
      int dst = base[b] + off1[b] + rank;
      st1[dst] = make_int2(((r - (b<<BSH))<<17) | c1[e], __float_as_int(v1[e]));
    }
    {
      int r = r2[e]; int b = r>>BSH;
      int rank = atomicAdd(&l2[b], 1);
      int dst = base[257+b] + off2[b] + rank;
      st2[dst] = ((r - (b<<BSH))<<17) | c2[e];
    }
  }
}

// per-bucket: local row histogram + scan -> rs (coalesced) + row-sorted edges (L2-local scatter)
__global__ void k_csr_bucket(const int2* __restrict__ st1, const int* __restrict__ st2,
                             const int* __restrict__ base,
                             int2* __restrict__ e1, int* __restrict__ e2,
                             int* __restrict__ rs, int N, int nbk){
  __shared__ int cnt[512];
  __shared__ int cur[512];
  __shared__ int sc[256];
  int g = blockIdx.x / nbk;
  int b = blockIdx.x % nbk;
  int t = threadIdx.x;
  cnt[t]=0; cnt[256+t]=0;
  __syncthreads();
  int ebeg = base[g*257+b], eend = base[g*257+b+1];
  if(g==0){
    for(int i=ebeg+t; i<eend; i+=256) atomicAdd(&cnt[st1[i].x>>17], 1);
  } else {
    for(int i=ebeg+t; i<eend; i+=256) atomicAdd(&cnt[st2[i]>>17], 1);
  }
  __syncthreads();
  // exclusive scan of 512 counts (2 per thread)
  int a0 = cnt[2*t], a1 = cnt[2*t+1];
  int s = a0+a1;
  sc[t]=s; __syncthreads();
  for(int off=1; off<256; off<<=1){
    int add = (t>=off)? sc[t-off] : 0;
    __syncthreads(); sc[t]+=add; __syncthreads();
  }
  int ex = sc[t]-s;
  cur[2*t] = ex; cur[2*t+1] = ex + a0;
  __syncthreads();
  // write row starts (coalesced)
  int r0 = b<<BSH;
  int* rsg = rs + (size_t)g*(N+1);
  for(int i=t; i<512; i+=256){
    int r = r0+i;
    if(r<N) rsg[r] = ebeg + cur[i];
  }
  if(b==nbk-1 && t==0) rsg[N] = base[g*257+256];
  __syncthreads();
  // scatter within bucket window (L2-resident)
  if(g==0){
    for(int i=ebeg+t; i<eend; i+=256){
      int2 w = st1[i];
      int lr = w.x>>17;
      int p = ebeg + atomicAdd(&cur[lr], 1);
      e1[p] = make_int2(w.x & 0x1FFFF, w.y);
    }
  } else {
    for(int i=ebeg+t; i<eend; i+=256){
      int w = st2[i];
      int lr = w>>17;
      int p = ebeg + atomicAdd(&cur[lr], 1);
      e2[p] = w & 0x1FFFF;
    }
  }
}

// ---------------- dense GEMM: out = scale*(A@W), A n x 128, W 128 x 128 ----------------
template<typename OT>
__global__ __launch_bounds__(256) void k_gemm128v2(const float* __restrict__ A, const float* __restrict__ W,
                                                   OT* __restrict__ out, float scale, int n){
  __shared__ float at[32][132];
  __shared__ float wt[32][128];
  int t = threadIdx.x;
  int r0 = blockIdx.x*128;
  int tx = t & 15, ty = t >> 4;

  float acc[8][8];
  #pragma unroll
  for(int i=0;i<8;++i)
    #pragma unroll
    for(int j=0;j<8;++j) acc[i][j]=0.f;

  for(int kc=0; kc<DD; kc+=32){
    __syncthreads();
    #pragma unroll
    for(int j=0;j<4;++j){
      int flat = t + j*256;
      int kl = flat >> 5, c4 = flat & 31;
      float4 w4 = *(const float4*)(W + (size_t)(kc+kl)*DD + c4*4);
      *(float4*)&wt[kl][c4*4] = w4;
    }
    #pragma unroll
    for(int j=0;j<4;++j){
      int flat = t + j*256;
      int row = flat >> 3, k4 = flat & 7;
      float4 a4 = make_float4(0.f,0.f,0.f,0.f);
      if(r0+row < n) a4 = *(const float4*)(A + (size_t)(r0+row)*DD + kc + k4*4);
      at[k4*4+0][row]=a4.x; at[k4*4+1][row]=a4.y; at[k4*4+2][row]=a4.z; at[k4*4+3][row]=a4.w;
    }
    __syncthreads();
    #pragma unroll
    for(int k=0;k<32;++k){
      float4 a0 = *(const float4*)&at[k][tx*4];
      float4 a1 = *(const float4*)&at[k][64+tx*4];
      float4 w0 = *(const float4*)&wt[k][ty*8];
      float4 w1 = *(const float4*)&wt[k][ty*8+4];
      float av[8] = {a0.x,a0.y,a0.z,a0.w,a1.x,a1.y,a1.z,a1.w};
      float wv[8] = {w0.x,w0.y,w0.z,w0.w,w1.x,w1.y,w1.z,w1.w};
      #pragma unroll
      for(int i=0;i<8;++i)
        #pragma unroll
        for(int j=0;j<8;++j) acc[i][j] += av[i]*wv[j];
    }
  }
  #pragma unroll
  for(int i=0;i<8;++i){
    int row = (i<4) ? tx*4+i : 64+tx*4+(i-4);
    if(r0+row >= n) continue;
    if constexpr (sizeof(OT)==4){
      float* o = (float*)out + (size_t)(r0+row)*DD + ty*8;
      *(float4*)o = make_float4(acc[i][0]*scale, acc[i][1]*scale, acc[i][2]*scale, acc[i][3]*scale);
      *(float4*)(o+4) = make_float4(acc[i][4]*scale, acc[i][5]*scale, acc[i][6]*scale, acc[i][7]*scale);
    } else {
      union { __half2 h[4]; float4 f; } u;
      u.h[0] = __floats2half2_rn(acc[i][0]*scale, acc[i][1]*scale);
      u.h[1] = __floats2half2_rn(acc[i][2]*scale, acc[i][3]*scale);
      u.h[2] = __floats2half2_rn(acc[i][4]*scale, acc[i][5]*scale);
      u.h[3] = __floats2half2_rn(acc[i][6]*scale, acc[i][7]*scale);
      *(float4*)((__half*)out + (size_t)(r0+row)*DD + ty*8) = u.f;
    }
  }
}

// ---------------- fused scores: s_w[i] = tanh(scale * x_i . (x_i @ m_w)), w = 1,2 ----------------
__global__ __launch_bounds__(256) void k_gemm_scores(const float* __restrict__ x,
                                                     const float* __restrict__ m1, const float* __restrict__ m2,
                                                     float* __restrict__ s1, float* __restrict__ s2,
                                                     float scale, int n){
  __shared__ float at[32][132];
  __shared__ float wt[32][128];
  __shared__ float red[16][132];
  int t = threadIdx.x;
  int r0 = blockIdx.x*128;
  int tx = t & 15, ty = t >> 4;

  for(int wsel=0; wsel<2; ++wsel){
    const float* W = wsel ? m2 : m1;
    float acc[8][8];
    #pragma unroll
    for(int i=0;i<8;++i)
      #pragma unroll
      for(int j=0;j<8;++j) acc[i][j]=0.f;

    for(int kc=0; kc<DD; kc+=32){
      __syncthreads();
      #pragma unroll
      for(int j=0;j<4;++j){
        int flat = t + j*256;
        int kl = flat >> 5, c4 = flat & 31;
        float4 w4 = *(const float4*)(W + (size_t)(kc+kl)*DD + c4*4);
        *(float4*)&wt[kl][c4*4] = w4;
      }
      #pragma unroll
      for(int j=0;j<4;++j){
        int flat = t + j*256;
        int row = flat >> 3, k4 = flat & 7;
        float4 a4 = make_float4(0.f,0.f,0.f,0.f);
        if(r0+row < n) a4 = *(const float4*)(x + (size_t)(r0+row)*DD + kc + k4*4);
        at[k4*4+0][row]=a4.x; at[k4*4+1][row]=a4.y; at[k4*4+2][row]=a4.z; at[k4*4+3][row]=a4.w;
      }
      __syncthreads();
      #pragma unroll
      for(int k=0;k<32;++k){
        float4 a0 = *(const float4*)&at[k][tx*4];
        float4 a1 = *(const float4*)&at[k][64+tx*4];
        float4 w0 = *(const float4*)&wt[k][ty*8];
        float4 w1 = *(const float4*)&wt[k][ty*8+4];
        float av[8] = {a0.x,a0.y,a0.z,a0.w,a1.x,a1.y,a1.z,a1.w};
        float wv[8] = {w0.x,w0.y,w0.z,w0.w,w1.x,w1.y,w1.z,w1.w};
        #pragma unroll
        for(int i=0;i<8;++i)
          #pragma unroll
          for(int j=0;j<8;++j) acc[i][j] += av[i]*wv[j];
      }
    }
    #pragma unroll
    for(int i=0;i<8;++i){
      int row = (i<4) ? tx*4+i : 64+tx*4+(i-4);
      float pd = 0.f;
      if(r0+row < n){
        float4 xa = *(const float4*)(x + (size_t)(r0+row)*DD + ty*8);
        float4 xb = *(const float4*)(x + (size_t)(r0+row)*DD + ty*8 + 4);
        pd = acc[i][0]*xa.x + acc[i][1]*xa.y + acc[i][2]*xa.z + acc[i][3]*xa.w
           + acc[i][4]*xb.x + acc[i][5]*xb.y + acc[i][6]*xb.z + acc[i][7]*xb.w;
      }
      red[ty][row] = pd;
    }
    __syncthreads();
    if(t < 128 && r0+t < n){
      float s = 0.f;
      #pragma unroll
      for(int j=0;j<16;++j) s += red[j][t];
      (wsel ? s2 : s1)[r0+t] = tanhf(scale*s);
    }
    __syncthreads();
  }
}

// ---------------- fused highway GEMM ----------------
__global__ __launch_bounds__(256) void k_gemm_hw(const float* __restrict__ A /*y2*/, const float* __restrict__ W,
                                                 const float* __restrict__ y1, float* __restrict__ y3,
                                                 float bn, int n){
  __shared__ float at[32][132];
  __shared__ float wt[32][128];
  int t = threadIdx.x;
  int r0 = blockIdx.x*128;
  int tx = t & 15, ty = t >> 4;

  float acc[8][8];
  #pragma unroll
  for(int i=0;i<8;++i)
    #pragma unroll
    for(int j=0;j<8;++j) acc[i][j]=0.f;

  for(int kc=0; kc<DD; kc+=32){
    __syncthreads();
    #pragma unroll
    for(int j=0;j<4;++j){
      int flat = t + j*256;
      int kl = flat >> 5, c4 = flat & 31;
      float4 w4 = *(const float4*)(W + (size_t)(kc+kl)*DD + c4*4);
      *(float4*)&wt[kl][c4*4] = w4;
    }
    #pragma unroll
    for(int j=0;j<4;++j){
      int flat = t + j*256;
      int row = flat >> 3, k4 = flat & 7;
      float4 a4 = make_float4(0.f,0.f,0.f,0.f);
      if(r0+row < n) a4 = *(const float4*)(A + (size_t)(r0+row)*DD + kc + k4*4);
      at[k4*4+0][row]=a4.x; at[k4*4+1][row]=a4.y; at[k4*4+2][row]=a4.z; at[k4*4+3][row]=a4.w;
    }
    __syncthreads();
    #pragma unroll
    for(int k=0;k<32;++k){
      float4 a0 = *(const float4*)&at[k][tx*4];
      float4 a1 = *(const float4*)&at[k][64+tx*4];
      float4 w0 = *(const float4*)&wt[k][ty*8];
      float4 w1 = *(const float4*)&wt[k][ty*8+4];
      float av[8] = {a0.x,a0.y,a0.z,a0.w,a1.x,a1.y,a1.z,a1.w};
      float wv[8] = {w0.x,w0.y,w0.z,w0.w,w1.x,w1.y,w1.z,w1.w};
      #pragma unroll
      for(int i=0;i<8;++i)
        #pragma unroll
        for(int j=0;j<8;++j) acc[i][j] += av[i]*wv[j];
    }
  }
  #pragma unroll
  for(int i=0;i<8;++i){
    int row = (i<4) ? tx*4+i : 64+tx*4+(i-4);
    if(r0+row >= n) continue;
    const float* p1 = y1 + (size_t)(r0+row)*DD + ty*8;
    const float* p2 = A  + (size_t)(r0+row)*DD + ty*8;
    float4 y1a = *(const float4*)p1, y1b = *(const float4*)(p1+4);
    float4 y2a = *(const float4*)p2, y2b = *(const float4*)(p2+4);
    float v1[8] = {y1a.x,y1a.y,y1a.z,y1a.w,y1b.x,y1b.y,y1b.z,y1b.w};
    float v2[8] = {y2a.x,y2a.y,y2a.z,y2a.w,y2b.x,y2b.y,y2b.z,y2b.w};
    float r[8];
    #pragma unroll
    for(int j=0;j<8;++j){
      float g = tanhf(bn*acc[i][j]);
      g = (g>0.f)? g : 0.f;
      r[j] = tanhf(bn*(v1[j]*(1.f-g) + v2[j]*g));
    }
    float* o = y3 + (size_t)(r0+row)*DD + ty*8;
    *(float4*)o     = make_float4(r[0],r[1],r[2],r[3]);
    *(float4*)(o+4) = make_float4(r[4],r[5],r[6],r[7]);
  }
}

// ---------------- CSR spmm + bias + tanh (wave per row, half payload, packed edges) ----------------
__global__ void k_spmm_tanh(const int* __restrict__ rs, const int2* __restrict__ e1,
                            const __half* __restrict__ h, const float* __restrict__ bias,
                            float* __restrict__ out, int n){
  int row = blockIdx.x*4 + (threadIdx.x>>6);
  if(row>=n) return;
  int lane = threadIdx.x & 63;
  int beg = rs[row], end = rs[row+1];
  float ax=0.f, ay=0.f;
  int k = beg;
  for(; k+4<=end; k+=4){
    int2 cv0=e1[k], cv1=e1[k+1], cv2=e1[k+2], cv3=e1[k+3];
    float v0=__int_as_float(cv0.y), v1=__int_as_float(cv1.y), v2=__int_as_float(cv2.y), v3=__int_as_float(cv3.y);
    float2 h0 = __half22float2(((const __half2*)(h + (size_t)cv0.x*DD))[lane]);
    float2 h1 = __half22float2(((const __half2*)(h + (size_t)cv1.x*DD))[lane]);
    float2 h2 = __half22float2(((const __half2*)(h + (size_t)cv2.x*DD))[lane]);
    float2 h3 = __half22float2(((const __half2*)(h + (size_t)cv3.x*DD))[lane]);
    ax += v0*h0.x + v1*h1.x + v2*h2.x + v3*h3.x;
    ay += v0*h0.y + v1*h1.y + v2*h2.y + v3*h3.y;
  }
  for(; k<end; ++k){
    int2 cv = e1[k];
    float v = __int_as_float(cv.y);
    float2 hh = __half22float2(((const __half2*)(h + (size_t)cv.x*DD))[lane]);
    ax += v*hh.x; ay += v*hh.y;
  }
  float2 b = ((const float2*)bias)[lane];
  ((float2*)(out + (size_t)row*DD))[lane] = make_float2(tanhf(ax+b.x), tanhf(ay+b.y));
}

// ---------------- fused attention (vals==1; no max pass, scores bounded) ----------------
__global__ void k_attn(const int* __restrict__ rs, const int* __restrict__ e2,
                       const float* __restrict__ s1, const float* __restrict__ s2,
                       const __half* __restrict__ mapped, float* __restrict__ out, int n){
  int row = blockIdx.x*4 + (threadIdx.x>>6);
  if(row>=n) return;
  int lane = threadIdx.x & 63;
  int beg = rs[row], end = rs[row+1];
  float s1r = s1[row];
  float ax=0.f, ay=0.f, den=0.f;
  int k = beg;
  for(; k+4<=end; k+=4){
    int c0=e2[k], c1=e2[k+1], c2=e2[k+2], c3=e2[k+3];
    float e0 = s1r + s2[c0]; e0 = (e0>=0.f)? e0 : 0.2f*e0;
    float e1 = s1r + s2[c1]; e1 = (e1>=0.f)? e1 : 0.2f*e1;
    float e2v = s1r + s2[c2]; e2v = (e2v>=0.f)? e2v : 0.2f*e2v;
    float e3 = s1r + s2[c3]; e3 = (e3>=0.f)? e3 : 0.2f*e3;
    float2 m0 = __half22float2(((const __half2*)(mapped + (size_t)c0*DD))[lane]);
    float2 m1 = __half22float2(((const __half2*)(mapped + (size_t)c1*DD))[lane]);
    float2 m2 = __half22float2(((const __half2*)(mapped + (size_t)c2*DD))[lane]);
    float2 m3 = __half22float2(((const __half2*)(mapped + (size_t)c3*DD))[lane]);
    float x0 = __expf(e0), x1 = __expf(e1), x2 = __expf(e2v), x3 = __expf(e3);
    den += x0+x1+x2+x3;
    ax += x0*m0.x + x1*m1.x + x2*m2.x + x3*m3.x;
    ay += x0*m0.y + x1*m1.y + x2*m2.y + x3*m3.y;
  }
  for(; k<end; ++k){
    int c = e2[k];
    float e = s1r + s2[c]; e = (e>=0.f)? e : 0.2f*e;
    float ex = __expf(e);
    float2 m = __half22float2(((const __half2*)(mapped + (size_t)c*DD))[lane]);
    den += ex; ax += ex*m.x; ay += ex*m.y;
  }
  float inv = (end > beg) ? 1.0f/den : 0.0f;
  ((float2*)(out + (size_t)row*DD))[lane] = make_float2(ax*inv, ay*inv);
}

// ---------------- final: out = l2norm(concat(l2norm(y3), l2norm(y4), l2norm(x))) ----------------
__global__ void k_final(const float* __restrict__ y3, const float* __restrict__ y4,
                        const float* __restrict__ x, float* __restrict__ out, int n){
  int row = blockIdx.x*4 + (threadIdx.x>>6);
  if(row>=n) return;
  int lane = threadIdx.x & 63;
  float2 a = ((const float2*)(y3 + (size_t)row*DD))[lane];
  float2 b = ((const float2*)(y4 + (size_t)row*DD))[lane];
  float2 c = ((const float2*)(x  + (size_t)row*DD))[lane];
  float sa = a.x*a.x + a.y*a.y;
  float sb = b.x*b.x + b.y*b.y;
  float sc = c.x*c.x + c.y*c.y;
  #pragma unroll
  for(int off=32; off; off>>=1){
    sa += __shfl_xor(sa, off, 64);
    sb += __shfl_xor(sb, off, 64);
    sc += __shfl_xor(sc, off, 64);
  }
  float ia = rsqrtf(fmaxf(sa, 1e-12f));
  float ib = rsqrtf(fmaxf(sb, 1e-12f));
  float ic = rsqrtf(fmaxf(sc, 1e-12f));
  float tot = sa*ia*ia + sb*ib*ib + sc*ic*ic;
  float f = rsqrtf(fmaxf(tot, 1e-12f));
  float fa = ia*f, fb = ib*f, fc = ic*f;
  float2* o = (float2*)(out + (size_t)row*(3*DD));
  o[lane]     = make_float2(a.x*fa, a.y*fa);
  o[64+lane]  = make_float2(b.x*fb, b.y*fb);
  o[128+lane] = make_float2(c.x*fc, c.y*fc);
}

// ---------------- launch ----------------
extern "C" void kernel_launch(void* const* d_in, const int* in_sizes, int n_in,
                              void* d_out, int out_size, void* d_ws, size_t ws_size,
                              hipStream_t stream){
  const float* x   = (const float*)d_in[0];
  const int*   a1r = (const int*)d_in[1];
  const int*   a1c = (const int*)d_in[2];
  const float* a1v = (const float*)d_in[3];
  const int*   a2r = (const int*)d_in[4];
  const int*   a2c = (const int*)d_in[5];
  const float* w1  = (const float*)d_in[7];
  const float* b1  = (const float*)d_in[8];
  const float* watt= (const float*)d_in[9];
  const float* m1  = (const float*)d_in[10];
  const float* m2  = (const float*)d_in[11];
  const float* whw = (const float*)d_in[12];
  const float* w2  = (const float*)d_in[13];
  const float* b2  = (const float*)d_in[14];

  const int N = in_sizes[0]/DD;
  const int E = in_sizes[1];
  const float BN = (float)(1.0/sqrt(1.0+1e-3));
  const size_t NB = (size_t)N*DD;

  // tiles for partition (nt <= 256 required by colscan)
  int tile = 8192, nt = (E+tile-1)/tile;
  while(nt > 256){ tile <<= 1; nt = (E+tile-1)/tile; }
  const int nbk = (N + (1<<BSH) - 1) >> BSH;   // buckets (<=256 for N<=131072)

  // workspace layout
  float* B0 = (float*)d_ws;         // N*128 f32  (CSR staging | mapped-half | y3)
  float* B1 = B0 + NB;              // N*128 f32  (y1 | y4)
  float* B2 = B1 + NB;              // N*128 f32  (h1h half | y2 | h3h half)
  float* s1 = B2 + NB;              // N
  float* s2 = s1 + N;               // N
  int*   rs   = (int*)(s2 + N);     // 2*(N+1)   [rs1 | rs2]
  int2*  e1   = (int2*)(rs + 2*(N+1)); // E packed {col, val}
  int*   e2   = (int*)(e1 + E);     // E cols (vals are 1.0)
  int*   hist = e2 + E;             // 2*nt*256
  int*   colsum = hist + (size_t)2*nt*256; // 512
  int*   base = colsum + 512;       // 2*257

  // staging aliased into B0 (free until 4th GEMM, stream-ordered)
  int2* st1 = (int2*)B0;            // E
  int*  st2 = (int*)(st1 + E);      // E

  __half* H0 = (__half*)B0;         // N*128 half (mapped)
  __half* H2 = (__half*)B2;         // N*128 half (h1h / h3h)

  const int gR = (N+3)/4;
  const int gG = (N+127)/128;
  float* out = (float*)d_out;

  // ---- CSR build (counting sort, coalesced writes) ----
  k_hist<<<nt,256,0,stream>>>(a1r, a2r, hist, E, tile, nt);
  k_colscan<<<512,256,0,stream>>>(hist, colsum, nt);
  k_basescan<<<1,512,0,stream>>>(colsum, base);
  k_partition<<<nt,256,0,stream>>>(a1r,a1c,a1v, a2r,a2c, hist, base, st1, st2, E, tile, nt);
  k_csr_bucket<<<2*nbk,256,0,stream>>>(st1, st2, base, e1, e2, rs, N, nbk);

  // ---- GCN layer 1: h1h = half(BN*(x@w1)) -> H2 ; y1 = tanh(spmm(a1,h1h)+b1) -> B1 ----
  k_gemm128v2<__half><<<gG,256,0,stream>>>(x, w1, H2, BN, N);
  k_spmm_tanh<<<gR,256,0,stream>>>(rs, e1, H2, b1, B1, N);

  // ---- attention scores (fused m1,m2 GEMM + rowdots) ----
  k_gemm_scores<<<gG,256,0,stream>>>(x, m1, m2, s1, s2, BN*BN, N);

  // ---- attention: mapped = half(BN*(x@watt)) -> H0 ; y2 -> B2 ----
  k_gemm128v2<__half><<<gG,256,0,stream>>>(x, watt, H0, BN, N);
  k_attn<<<gR,256,0,stream>>>(rs+(N+1), e2, s1, s2, H0, B2, N);

  // ---- highway fused into whw GEMM: y3 -> B0 ----
  k_gemm_hw<<<gG,256,0,stream>>>(B2, whw, B1, B0, BN, N);

  // ---- GCN layer 2: h3h = half(BN*(y3@w2)) -> H2 ; y4 = tanh(spmm(a1,h3h)+b2) -> B1 ----
  k_gemm128v2<__half><<<gG,256,0,stream>>>(B0, w2, H2, BN, N);
  k_spmm_tanh<<<gR,256,0,stream>>>(rs, e1, H2, b2, B1, N);

  // ---- final concat + l2norms ----
  k_final<<<gR,256,0,stream>>>(B0, B1, x, out, N);
}

// Round 6
// 506.094 us; speedup vs baseline: 3.0606x; 1.6114x over previous
//
#include <hip/hip_runtime.h>
#include <hip/hip_fp16.h>
#include <math.h>

#define DD 128
#define BSH 9            // bucket shift: 512 rows per bucket

typedef _Float16 f16;
typedef _Float16 f16x8 __attribute__((ext_vector_type(8)));
typedef float f32x4 __attribute__((ext_vector_type(4)));

// ================= CSR build via bucket counting-sort (R5, proven) =================
__global__ void k_hist(const int* __restrict__ r1, const int* __restrict__ r2,
                       int* __restrict__ hist, int E, int tile, int nt){
  __shared__ int h1[256], h2[256];
  int t = threadIdx.x;
  h1[t]=0; h2[t]=0; __syncthreads();
  int e0 = blockIdx.x*tile, e1 = min(e0+tile, E);
  for(int e=e0+t; e<e1; e+=256){
    atomicAdd(&h1[r1[e]>>BSH], 1);
    atomicAdd(&h2[r2[e]>>BSH], 1);
  }
  __syncthreads();
  hist[(size_t)blockIdx.x*256 + t] = h1[t];
  hist[(size_t)nt*256 + (size_t)blockIdx.x*256 + t] = h2[t];
}

__global__ void k_colscan(int* __restrict__ hist, int* __restrict__ colsum, int nt){
  __shared__ int sh[256];
  int g = blockIdx.x>>8, b = blockIdx.x&255;
  int t = threadIdx.x;
  int* H = hist + (size_t)g*nt*256;
  int v = (t<nt)? H[(size_t)t*256+b] : 0;
  sh[t]=v; __syncthreads();
  for(int off=1; off<256; off<<=1){
    int add = (t>=off)? sh[t-off] : 0;
    __syncthreads(); sh[t]+=add; __syncthreads();
  }
  if(t<nt) H[(size_t)t*256+b] = sh[t]-v;
  if(t==255) colsum[g*256+b] = sh[255];
}

__global__ void k_basescan(const int* __restrict__ colsum, int* __restrict__ base){
  __shared__ int sh[512];
  int t = threadIdx.x;
  int g = t>>8, st = t&255;
  int v = colsum[t];
  sh[t]=v; __syncthreads();
  for(int off=1; off<256; off<<=1){
    int add = (st>=off)? sh[t-off] : 0;
    __syncthreads(); sh[t]+=add; __syncthreads();
  }
  base[g*257+st] = sh[t]-v;
  if(st==255) base[g*257+256] = sh[t];
}

__global__ void k_partition(const int* __restrict__ r1, const int* __restrict__ c1, const float* __restrict__ v1,
                            const int* __restrict__ r2, const int* __restrict__ c2,
                            const int* __restrict__ hist, const int* __restrict__ base,
                            int2* __restrict__ st1, int* __restrict__ st2, int E, int tile, int nt){
  __shared__ int l1[256], l2[256];
  int t = threadIdx.x;
  l1[t]=0; l2[t]=0; __syncthreads();
  int bx = blockIdx.x;
  int e0 = bx*tile, e1e = min(e0+tile, E);
  const int* off1 = hist + (size_t)bx*256;
  const int* off2 = hist + (size_t)nt*256 + (size_t)bx*256;
  for(int e=e0+t; e<e1e; e+=256){
    {
      int r = r1[e]; int b = r>>BSH;
      int rank = atomicAdd(&l1[b], 1);
      int dst = base[b] + off1[b] + rank;
      st1[dst] = make_int2(((r - (b<<BSH))<<17) | c1[e], __float_as_int(v1[e]));
    }
    {
      int r = r2[e]; int b = r>>BSH;
      int rank = atomicAdd(&l2[b], 1);
      int dst = base[257+b] + off2[b] + rank;
      st2[dst] = ((r - (b<<BSH))<<17) | c2[e];
    }
  }
}

__global__ void k_csr_bucket(const int2* __restrict__ st1, const int* __restrict__ st2,
                             const int* __restrict__ base,
                             int2* __restrict__ e1, int* __restrict__ e2,
                             int* __restrict__ rs, int N, int nbk){
  __shared__ int cnt[512];
  __shared__ int cur[512];
  __shared__ int sc[256];
  int g = blockIdx.x / nbk;
  int b = blockIdx.x % nbk;
  int t = threadIdx.x;
  cnt[t]=0; cnt[256+t]=0;
  __syncthreads();
  int ebeg = base[g*257+b], eend = base[g*257+b+1];
  if(g==0){
    for(int i=ebeg+t; i<eend; i+=256) atomicAdd(&cnt[st1[i].x>>17], 1);
  } else {
    for(int i=ebeg+t; i<eend; i+=256) atomicAdd(&cnt[st2[i]>>17], 1);
  }
  __syncthreads();
  int a0 = cnt[2*t], a1 = cnt[2*t+1];
  int s = a0+a1;
  sc[t]=s; __syncthreads();
  for(int off=1; off<256; off<<=1){
    int add = (t>=off)? sc[t-off] : 0;
    __syncthreads(); sc[t]+=add; __syncthreads();
  }
  int ex = sc[t]-s;
  cur[2*t] = ex; cur[2*t+1] = ex + a0;
  __syncthreads();
  int r0 = b<<BSH;
  int* rsg = rs + (size_t)g*(N+1);
  for(int i=t; i<512; i+=256){
    int r = r0+i;
    if(r<N) rsg[r] = ebeg + cur[i];
  }
  if(b==nbk-1 && t==0) rsg[N] = base[g*257+256];
  __syncthreads();
  if(g==0){
    for(int i=ebeg+t; i<eend; i+=256){
      int2 w = st1[i];
      int lr = w.x>>17;
      int p = ebeg + atomicAdd(&cur[lr], 1);
      e1[p] = make_int2(w.x & 0x1FFFF, w.y);
    }
  } else {
    for(int i=ebeg+t; i<eend; i+=256){
      int w = st2[i];
      int lr = w>>17;
      int p = ebeg + atomicAdd(&cur[lr], 1);
      e2[p] = w & 0x1FFFF;
    }
  }
}

// ================= weight prep: W (f32 row-major [k][c]) -> wh[b] = W^T f16 [c][k] =================
__global__ void k_wprep(const float* __restrict__ w0, const float* __restrict__ w1,
                        const float* __restrict__ w2, const float* __restrict__ w3,
                        const float* __restrict__ w4, const float* __restrict__ w5,
                        f16* __restrict__ wh){
  __shared__ __align__(16) f16 tw[128][136];
  int b = blockIdx.x, t = threadIdx.x;
  const float* W = (b==0)?w0:(b==1)?w1:(b==2)?w2:(b==3)?w3:(b==4)?w4:w5;
  for(int j=0;j<16;++j){
    int f = j*256+t; int k = f>>5, c4 = f&31;
    float4 v = *(const float4*)(W + (size_t)k*DD + c4*4);
    tw[c4*4+0][k]=(f16)v.x; tw[c4*4+1][k]=(f16)v.y; tw[c4*4+2][k]=(f16)v.z; tw[c4*4+3][k]=(f16)v.w;
  }
  __syncthreads();
  f16* dst = wh + (size_t)b*16384;
  for(int j=0;j<8;++j){
    int f = j*256+t; int c = f>>4, seg = f&15;
    *(int4*)&dst[(size_t)c*DD + seg*8] = *(int4*)&tw[c][seg*8];
  }
}

// ================= x -> f16 =================
__global__ void k_half(const float* __restrict__ x, f16* __restrict__ xh, int total8){
  int i = blockIdx.x*256+threadIdx.x;
  int stride = gridDim.x*256;
  for(; i<total8; i+=stride){
    float4 a = ((const float4*)x)[2*i], b = ((const float4*)x)[2*i+1];
    union{ f16 h[8]; int4 v; } u;
    u.h[0]=(f16)a.x; u.h[1]=(f16)a.y; u.h[2]=(f16)a.z; u.h[3]=(f16)a.w;
    u.h[4]=(f16)b.x; u.h[5]=(f16)b.y; u.h[6]=(f16)b.z; u.h[7]=(f16)b.w;
    ((int4*)xh)[i] = u.v;
  }
}

// ================= fused x-GEMMs via MFMA: h1h, mapped, s1, s2 =================
// wh slots: 0=w_gcn1, 1=w_att, 2=m1, 3=m2 (pre-transposed f16 [c][k])
__global__ __launch_bounds__(256) void k_xgemms(
    const f16* __restrict__ xh, const f16* __restrict__ wh,
    f16* __restrict__ h1h, f16* __restrict__ mapped,
    float* __restrict__ s1, float* __restrict__ s2,
    float bn, float sscale, int n){
  __shared__ __align__(16) f16 at[64][136];
  __shared__ __align__(16) f16 wt[128][136];
  int t = threadIdx.x;
  int r0 = blockIdx.x*64;
  int l = t&63, w = t>>6, li = l&15, g = l>>4;
  // stage A-tile (64 rows of xh)
  for(int p=0;p<4;++p){
    int row = p*16 + (t>>4), seg = t&15;
    int4 v = make_int4(0,0,0,0);
    if(r0+row < n) v = *(const int4*)(xh + (size_t)(r0+row)*DD + seg*8);
    *(int4*)&at[row][seg*8] = v;
  }
  for(int p=0;p<4;++p){
    __syncthreads();
    const f16* Wp = wh + (size_t)p*16384;
    for(int j=0;j<8;++j){
      int f = j*256+t; int c = f>>4, seg = f&15;
      *(int4*)&wt[c][seg*8] = *(const int4*)(Wp + (size_t)c*DD + seg*8);
    }
    __syncthreads();
    f32x4 acc[8];
    #pragma unroll
    for(int ct=0;ct<8;++ct) acc[ct] = (f32x4){0.f,0.f,0.f,0.f};
    #pragma unroll
    for(int ks=0;ks<4;++ks){
      f16x8 a = *(const f16x8*)&at[w*16+li][ks*32+g*8];
      #pragma unroll
      for(int ct=0;ct<8;++ct){
        f16x8 b = *(const f16x8*)&wt[ct*16+li][ks*32+g*8];
        acc[ct] = __builtin_amdgcn_mfma_f32_16x16x32_f16(a, b, acc[ct], 0,0,0);
      }
    }
    if(p<2){
      f16* out = p ? mapped : h1h;
      __syncthreads();
      #pragma unroll
      for(int ct=0;ct<8;++ct)
        #pragma unroll
        for(int reg=0;reg<4;++reg)
          wt[w*16+g*4+reg][ct*16+li] = (f16)(acc[ct][reg]*bn);
      __syncthreads();
      for(int j=0;j<4;++j){
        int f = j*256+t; int row = f>>4, seg = f&15;
        if(r0+row < n) *(int4*)&out[(size_t)(r0+row)*DD + seg*8] = *(int4*)&wt[row][seg*8];
      }
    } else {
      float* sd = (p==2) ? s1 : s2;
      #pragma unroll
      for(int reg=0;reg<4;++reg){
        float pd = 0.f;
        #pragma unroll
        for(int ct=0;ct<8;++ct)
          pd += acc[ct][reg]*(float)at[w*16+g*4+reg][ct*16+li];
        pd += __shfl_xor(pd,1,64); pd += __shfl_xor(pd,2,64);
        pd += __shfl_xor(pd,4,64); pd += __shfl_xor(pd,8,64);
        if(li==0){
          int grow = r0 + w*16 + g*4 + reg;
          if(grow < n) sd[grow] = tanhf(sscale*pd);
        }
      }
    }
  }
}

// ================= highway GEMM + gcn2 GEMM fused (y2h -> y3h -> h3h) =================
__global__ __launch_bounds__(256) void k_hw2(
    const f16* __restrict__ y2h, const f16* __restrict__ y1h,
    const f16* __restrict__ wh, f16* __restrict__ y3h, f16* __restrict__ h3h,
    float bn, int n){
  __shared__ __align__(16) f16 at[64][136];
  __shared__ __align__(16) f16 wt[128][136];
  int t = threadIdx.x;
  int r0 = blockIdx.x*64;
  int l = t&63, w = t>>6, li = l&15, g = l>>4;
  for(int p=0;p<4;++p){
    int row = p*16 + (t>>4), seg = t&15;
    int4 v = make_int4(0,0,0,0);
    if(r0+row < n) v = *(const int4*)(y2h + (size_t)(r0+row)*DD + seg*8);
    *(int4*)&at[row][seg*8] = v;
  }
  // ---- pass 0: gate GEMM (whw, slot 4) + highway epilogue -> y3 into at ----
  __syncthreads();
  for(int j=0;j<8;++j){
    int f = j*256+t; int c = f>>4, seg = f&15;
    *(int4*)&wt[c][seg*8] = *(const int4*)(wh + (size_t)4*16384 + (size_t)c*DD + seg*8);
  }
  __syncthreads();
  f32x4 acc[8];
  #pragma unroll
  for(int ct=0;ct<8;++ct) acc[ct] = (f32x4){0.f,0.f,0.f,0.f};
  #pragma unroll
  for(int ks=0;ks<4;++ks){
    f16x8 a = *(const f16x8*)&at[w*16+li][ks*32+g*8];
    #pragma unroll
    for(int ct=0;ct<8;++ct){
      f16x8 b = *(const f16x8*)&wt[ct*16+li][ks*32+g*8];
      acc[ct] = __builtin_amdgcn_mfma_f32_16x16x32_f16(a, b, acc[ct], 0,0,0);
    }
  }
  float res[8][4];
  #pragma unroll
  for(int ct=0;ct<8;++ct)
    #pragma unroll
    for(int reg=0;reg<4;++reg){
      int lrow = w*16+g*4+reg, col = ct*16+li;
      int grow = r0+lrow;
      float gt = tanhf(bn*acc[ct][reg]); gt = fmaxf(gt, 0.f);
      float y1v = (grow<n)? (float)y1h[(size_t)grow*DD+col] : 0.f;
      float y2v = (float)at[lrow][col];
      res[ct][reg] = tanhf(bn*(y1v*(1.f-gt) + y2v*gt));
    }
  // each lane owns exactly its (lrow,col) set: safe to overwrite at in place
  #pragma unroll
  for(int ct=0;ct<8;++ct)
    #pragma unroll
    for(int reg=0;reg<4;++reg)
      at[w*16+g*4+reg][ct*16+li] = (f16)res[ct][reg];
  __syncthreads();
  for(int j=0;j<4;++j){
    int f = j*256+t; int row = f>>4, seg = f&15;
    if(r0+row < n) *(int4*)&y3h[(size_t)(r0+row)*DD + seg*8] = *(int4*)&at[row][seg*8];
  }
  // ---- pass 1: gcn2 GEMM (w2, slot 5): h3h = bn*(y3@w2) ----
  __syncthreads();
  for(int j=0;j<8;++j){
    int f = j*256+t; int c = f>>4, seg = f&15;
    *(int4*)&wt[c][seg*8] = *(const int4*)(wh + (size_t)5*16384 + (size_t)c*DD + seg*8);
  }
  __syncthreads();
  #pragma unroll
  for(int ct=0;ct<8;++ct) acc[ct] = (f32x4){0.f,0.f,0.f,0.f};
  #pragma unroll
  for(int ks=0;ks<4;++ks){
    f16x8 a = *(const f16x8*)&at[w*16+li][ks*32+g*8];
    #pragma unroll
    for(int ct=0;ct<8;++ct){
      f16x8 b = *(const f16x8*)&wt[ct*16+li][ks*32+g*8];
      acc[ct] = __builtin_amdgcn_mfma_f32_16x16x32_f16(a, b, acc[ct], 0,0,0);
    }
  }
  __syncthreads();
  #pragma unroll
  for(int ct=0;ct<8;++ct)
    #pragma unroll
    for(int reg=0;reg<4;++reg)
      wt[w*16+g*4+reg][ct*16+li] = (f16)(acc[ct][reg]*bn);
  __syncthreads();
  for(int j=0;j<4;++j){
    int f = j*256+t; int row = f>>4, seg = f&15;
    if(r0+row < n) *(int4*)&h3h[(size_t)(r0+row)*DD + seg*8] = *(int4*)&wt[row][seg*8];
  }
}

// ================= CSR spmm + bias + tanh (wave/row, f16 payload, f16 out) =================
__global__ void k_spmm_tanh(const int* __restrict__ rs, const int2* __restrict__ e1,
                            const __half* __restrict__ h, const float* __restrict__ bias,
                            __half* __restrict__ out, int n){
  int row = blockIdx.x*4 + (threadIdx.x>>6);
  if(row>=n) return;
  int lane = threadIdx.x & 63;
  int beg = rs[row], end = rs[row+1];
  float ax=0.f, ay=0.f;
  int k = beg;
  for(; k+4<=end; k+=4){
    int2 cv0=e1[k], cv1=e1[k+1], cv2=e1[k+2], cv3=e1[k+3];
    float v0=__int_as_float(cv0.y), v1=__int_as_float(cv1.y), v2=__int_as_float(cv2.y), v3=__int_as_float(cv3.y);
    float2 h0 = __half22float2(((const __half2*)(h + (size_t)cv0.x*DD))[lane]);
    float2 h1 = __half22float2(((const __half2*)(h + (size_t)cv1.x*DD))[lane]);
    float2 h2 = __half22float2(((const __half2*)(h + (size_t)cv2.x*DD))[lane]);
    float2 h3 = __half22float2(((const __half2*)(h + (size_t)cv3.x*DD))[lane]);
    ax += v0*h0.x + v1*h1.x + v2*h2.x + v3*h3.x;
    ay += v0*h0.y + v1*h1.y + v2*h2.y + v3*h3.y;
  }
  for(; k<end; ++k){
    int2 cv = e1[k];
    float v = __int_as_float(cv.y);
    float2 hh = __half22float2(((const __half2*)(h + (size_t)cv.x*DD))[lane]);
    ax += v*hh.x; ay += v*hh.y;
  }
  float2 b = ((const float2*)bias)[lane];
  ((__half2*)(out + (size_t)row*DD))[lane] = __floats2half2_rn(tanhf(ax+b.x), tanhf(ay+b.y));
}

// ================= fused attention (vals==1; no max pass) =================
__global__ void k_attn(const int* __restrict__ rs, const int* __restrict__ e2,
                       const float* __restrict__ s1, const float* __restrict__ s2,
                       const __half* __restrict__ mapped, __half* __restrict__ out, int n){
  int row = blockIdx.x*4 + (threadIdx.x>>6);
  if(row>=n) return;
  int lane = threadIdx.x & 63;
  int beg = rs[row], end = rs[row+1];
  float s1r = s1[row];
  float ax=0.f, ay=0.f, den=0.f;
  int k = beg;
  for(; k+4<=end; k+=4){
    int c0=e2[k], c1=e2[k+1], c2=e2[k+2], c3=e2[k+3];
    float e0 = s1r + s2[c0]; e0 = (e0>=0.f)? e0 : 0.2f*e0;
    float e1 = s1r + s2[c1]; e1 = (e1>=0.f)? e1 : 0.2f*e1;
    float e2v = s1r + s2[c2]; e2v = (e2v>=0.f)? e2v : 0.2f*e2v;
    float e3 = s1r + s2[c3]; e3 = (e3>=0.f)? e3 : 0.2f*e3;
    float2 m0 = __half22float2(((const __half2*)(mapped + (size_t)c0*DD))[lane]);
    float2 m1 = __half22float2(((const __half2*)(mapped + (size_t)c1*DD))[lane]);
    float2 m2 = __half22float2(((const __half2*)(mapped + (size_t)c2*DD))[lane]);
    float2 m3 = __half22float2(((const __half2*)(mapped + (size_t)c3*DD))[lane]);
    float x0 = __expf(e0), x1 = __expf(e1), x2 = __expf(e2v), x3 = __expf(e3);
    den += x0+x1+x2+x3;
    ax += x0*m0.x + x1*m1.x + x2*m2.x + x3*m3.x;
    ay += x0*m0.y + x1*m1.y + x2*m2.y + x3*m3.y;
  }
  for(; k<end; ++k){
    int c = e2[k];
    float e = s1r + s2[c]; e = (e>=0.f)? e : 0.2f*e;
    float ex = __expf(e);
    float2 m = __half22float2(((const __half2*)(mapped + (size_t)c*DD))[lane]);
    den += ex; ax += ex*m.x; ay += ex*m.y;
  }
  float inv = (end > beg) ? 1.0f/den : 0.0f;
  ((__half2*)(out + (size_t)row*DD))[lane] = __floats2half2_rn(ax*inv, ay*inv);
}

// ================= final: out = l2norm(concat(l2norm(y3), l2norm(y4), l2norm(x))) =================
__global__ void k_final(const __half* __restrict__ y3, const __half* __restrict__ y4,
                        const float* __restrict__ x, float* __restrict__ out, int n){
  int row = blockIdx.x*4 + (threadIdx.x>>6);
  if(row>=n) return;
  int lane = threadIdx.x & 63;
  float2 a = __half22float2(((const __half2*)(y3 + (size_t)row*DD))[lane]);
  float2 b = __half22float2(((const __half2*)(y4 + (size_t)row*DD))[lane]);
  float2 c = ((const float2*)(x  + (size_t)row*DD))[lane];
  float sa = a.x*a.x + a.y*a.y;
  float sb = b.x*b.x + b.y*b.y;
  float sc = c.x*c.x + c.y*c.y;
  #pragma unroll
  for(int off=32; off; off>>=1){
    sa += __shfl_xor(sa, off, 64);
    sb += __shfl_xor(sb, off, 64);
    sc += __shfl_xor(sc, off, 64);
  }
  float ia = rsqrtf(fmaxf(sa, 1e-12f));
  float ib = rsqrtf(fmaxf(sb, 1e-12f));
  float ic = rsqrtf(fmaxf(sc, 1e-12f));
  float tot = sa*ia*ia + sb*ib*ib + sc*ic*ic;
  float f = rsqrtf(fmaxf(tot, 1e-12f));
  float fa = ia*f, fb = ib*f, fc = ic*f;
  float2* o = (float2*)(out + (size_t)row*(3*DD));
  o[lane]     = make_float2(a.x*fa, a.y*fa);
  o[64+lane]  = make_float2(b.x*fb, b.y*fb);
  o[128+lane] = make_float2(c.x*fc, c.y*fc);
}

// ================= launch =================
extern "C" void kernel_launch(void* const* d_in, const int* in_sizes, int n_in,
                              void* d_out, int out_size, void* d_ws, size_t ws_size,
                              hipStream_t stream){
  const float* x   = (const float*)d_in[0];
  const int*   a1r = (const int*)d_in[1];
  const int*   a1c = (const int*)d_in[2];
  const float* a1v = (const float*)d_in[3];
  const int*   a2r = (const int*)d_in[4];
  const int*   a2c = (const int*)d_in[5];
  const float* w1  = (const float*)d_in[7];
  const float* b1  = (const float*)d_in[8];
  const float* watt= (const float*)d_in[9];
  const float* m1  = (const float*)d_in[10];
  const float* m2  = (const float*)d_in[11];
  const float* whw = (const float*)d_in[12];
  const float* w2  = (const float*)d_in[13];
  const float* b2  = (const float*)d_in[14];

  const int N = in_sizes[0]/DD;
  const int E = in_sizes[1];
  const float BN = (float)(1.0/sqrt(1.0+1e-3));
  const size_t NB = (size_t)N*DD;

  int tile = 8192, nt = (E+tile-1)/tile;
  while(nt > 256){ tile <<= 1; nt = (E+tile-1)/tile; }
  const int nbk = (N + (1<<BSH) - 1) >> BSH;

  // workspace layout (f16 activations)
  f16* xh = (f16*)d_ws;             // N*128
  f16* Bh = xh + NB;                // h1h -> h3h   (also CSR staging alias)
  f16* Ch = Bh + NB;                // mapped -> y3h
  f16* Dh = Ch + NB;                // y1h -> y4h
  f16* Eh = Dh + NB;                // y2h
  f16* wh = Eh + NB;                // 6*16384
  float* s1 = (float*)(wh + 6*16384);   // N
  float* s2 = s1 + N;               // N
  int*  rs  = (int*)(s2 + N);       // 2*(N+1)
  int2* e1  = (int2*)(rs + 2*(N+1));// E
  int*  e2  = (int*)(e1 + E);       // E
  int*  hist = e2 + E;              // 2*nt*256
  int*  colsum = hist + (size_t)2*nt*256; // 512
  int*  base = colsum + 512;        // 2*257

  int2* st1 = (int2*)Bh;            // E (alias, dead before h1h written)
  int*  st2 = (int*)(st1 + E);      // E

  const int gR = (N+3)/4;
  const int gM = (N+63)/64;
  float* out = (float*)d_out;

  // ---- prep: weights + x to f16 ----
  k_wprep<<<6,256,0,stream>>>(w1, watt, m1, m2, whw, w2, wh);
  k_half<<<2048,256,0,stream>>>(x, xh, N*16);

  // ---- CSR build ----
  k_hist<<<nt,256,0,stream>>>(a1r, a2r, hist, E, tile, nt);
  k_colscan<<<512,256,0,stream>>>(hist, colsum, nt);
  k_basescan<<<1,512,0,stream>>>(colsum, base);
  k_partition<<<nt,256,0,stream>>>(a1r,a1c,a1v, a2r,a2c, hist, base, st1, st2, E, tile, nt);
  k_csr_bucket<<<2*nbk,256,0,stream>>>(st1, st2, base, e1, e2, rs, N, nbk);

  // ---- fused x GEMMs: h1h(Bh), mapped(Ch), s1, s2 ----
  k_xgemms<<<gM,256,0,stream>>>(xh, wh, Bh, Ch, s1, s2, BN, BN*BN, N);

  // ---- GCN1 aggregate: y1h(Dh) ----
  k_spmm_tanh<<<gR,256,0,stream>>>(rs, e1, (const __half*)Bh, b1, (__half*)Dh, N);

  // ---- attention aggregate: y2h(Eh) ----
  k_attn<<<gR,256,0,stream>>>(rs+(N+1), e2, s1, s2, (const __half*)Ch, (__half*)Eh, N);

  // ---- highway + gcn2 GEMMs: y3h(Ch), h3h(Bh) ----
  k_hw2<<<gM,256,0,stream>>>(Eh, Dh, wh, Ch, Bh, BN, N);

  // ---- GCN2 aggregate: y4h(Dh) ----
  k_spmm_tanh<<<gR,256,0,stream>>>(rs, e1, (const __half*)Bh, b2, (__half*)Dh, N);

  // ---- final ----
  k_final<<<gR,256,0,stream>>>((const __half*)Ch, (const __half*)Dh, x, out, N);
}

// Round 7
// 497.301 us; speedup vs baseline: 3.1147x; 1.0177x over previous
//
#include <hip/hip_runtime.h>
#include <hip/hip_fp16.h>
#include <math.h>
#include <stdint.h>

#define DD 128
#define BSH 9            // bucket shift: 512 rows per bucket

typedef _Float16 f16;
typedef _Float16 f16x8 __attribute__((ext_vector_type(8)));
typedef float f32x4 __attribute__((ext_vector_type(4)));

// ================= CSR build via bucket counting-sort (proven R5/R6) =================
__global__ void k_hist(const int* __restrict__ r1, const int* __restrict__ r2,
                       int* __restrict__ hist, int E, int tile, int nt){
  __shared__ int h1[256], h2[256];
  int t = threadIdx.x;
  h1[t]=0; h2[t]=0; __syncthreads();
  int e0 = blockIdx.x*tile, e1 = min(e0+tile, E);
  for(int e=e0+t; e<e1; e+=256){
    atomicAdd(&h1[r1[e]>>BSH], 1);
    atomicAdd(&h2[r2[e]>>BSH], 1);
  }
  __syncthreads();
  hist[(size_t)blockIdx.x*256 + t] = h1[t];
  hist[(size_t)nt*256 + (size_t)blockIdx.x*256 + t] = h2[t];
}

__global__ void k_colscan(int* __restrict__ hist, int* __restrict__ colsum, int nt){
  __shared__ int sh[256];
  int g = blockIdx.x>>8, b = blockIdx.x&255;
  int t = threadIdx.x;
  int* H = hist + (size_t)g*nt*256;
  int v = (t<nt)? H[(size_t)t*256+b] : 0;
  sh[t]=v; __syncthreads();
  for(int off=1; off<256; off<<=1){
    int add = (t>=off)? sh[t-off] : 0;
    __syncthreads(); sh[t]+=add; __syncthreads();
  }
  if(t<nt) H[(size_t)t*256+b] = sh[t]-v;
  if(t==255) colsum[g*256+b] = sh[255];
}

__global__ void k_basescan(const int* __restrict__ colsum, int* __restrict__ base){
  __shared__ int sh[512];
  int t = threadIdx.x;
  int g = t>>8, st = t&255;
  int v = colsum[t];
  sh[t]=v; __syncthreads();
  for(int off=1; off<256; off<<=1){
    int add = (st>=off)? sh[t-off] : 0;
    __syncthreads(); sh[t]+=add; __syncthreads();
  }
  base[g*257+st] = sh[t]-v;
  if(st==255) base[g*257+256] = sh[t];
}

__global__ void k_partition(const int* __restrict__ r1, const int* __restrict__ c1, const float* __restrict__ v1,
                            const int* __restrict__ r2, const int* __restrict__ c2,
                            const int* __restrict__ hist, const int* __restrict__ base,
                            int2* __restrict__ st1, int* __restrict__ st2, int E, int tile, int nt){
  __shared__ int l1[256], l2[256];
  int t = threadIdx.x;
  l1[t]=0; l2[t]=0; __syncthreads();
  int bx = blockIdx.x;
  int e0 = bx*tile, e1e = min(e0+tile, E);
  const int* off1 = hist + (size_t)bx*256;
  const int* off2 = hist + (size_t)nt*256 + (size_t)bx*256;
  for(int e=e0+t; e<e1e; e+=256){
    {
      int r = r1[e]; int b = r>>BSH;
      int rank = atomicAdd(&l1[b], 1);
      int dst = base[b] + off1[b] + rank;
      st1[dst] = make_int2(((r - (b<<BSH))<<17) | c1[e], __float_as_int(v1[e]));
    }
    {
      int r = r2[e]; int b = r>>BSH;
      int rank = atomicAdd(&l2[b], 1);
      int dst = base[257+b] + off2[b] + rank;
      st2[dst] = ((r - (b<<BSH))<<17) | c2[e];
    }
  }
}

__global__ void k_csr_bucket(const int2* __restrict__ st1, const int* __restrict__ st2,
                             const int* __restrict__ base,
                             int2* __restrict__ e1, int* __restrict__ e2,
                             int* __restrict__ rs, int N, int nbk){
  __shared__ int cnt[512];
  __shared__ int cur[512];
  __shared__ int sc[256];
  int g = blockIdx.x / nbk;
  int b = blockIdx.x % nbk;
  int t = threadIdx.x;
  cnt[t]=0; cnt[256+t]=0;
  __syncthreads();
  int ebeg = base[g*257+b], eend = base[g*257+b+1];
  if(g==0){
    for(int i=ebeg+t; i<eend; i+=256) atomicAdd(&cnt[st1[i].x>>17], 1);
  } else {
    for(int i=ebeg+t; i<eend; i+=256) atomicAdd(&cnt[st2[i]>>17], 1);
  }
  __syncthreads();
  int a0 = cnt[2*t], a1 = cnt[2*t+1];
  int s = a0+a1;
  sc[t]=s; __syncthreads();
  for(int off=1; off<256; off<<=1){
    int add = (t>=off)? sc[t-off] : 0;
    __syncthreads(); sc[t]+=add; __syncthreads();
  }
  int ex = sc[t]-s;
  cur[2*t] = ex; cur[2*t+1] = ex + a0;
  __syncthreads();
  int r0 = b<<BSH;
  int* rsg = rs + (size_t)g*(N+1);
  for(int i=t; i<512; i+=256){
    int r = r0+i;
    if(r<N) rsg[r] = ebeg + cur[i];
  }
  if(b==nbk-1 && t==0) rsg[N] = base[g*257+256];
  __syncthreads();
  if(g==0){
    for(int i=ebeg+t; i<eend; i+=256){
      int2 w = st1[i];
      int lr = w.x>>17;
      int p = ebeg + atomicAdd(&cur[lr], 1);
      e1[p] = make_int2(w.x & 0x1FFFF, w.y);
    }
  } else {
    for(int i=ebeg+t; i<eend; i+=256){
      int w = st2[i];
      int lr = w>>17;
      int p = ebeg + atomicAdd(&cur[lr], 1);
      e2[p] = w & 0x1FFFF;
    }
  }
}

// ================= weight prep: W (f32 [k][c]) -> wh[b] = W^T f16 [c][k] =================
__global__ void k_wprep(const float* __restrict__ w0, const float* __restrict__ w1,
                        const float* __restrict__ w2, const float* __restrict__ w3,
                        const float* __restrict__ w4, const float* __restrict__ w5,
                        f16* __restrict__ wh){
  __shared__ __align__(16) f16 tw[128][136];
  int b = blockIdx.x, t = threadIdx.x;
  const float* W = (b==0)?w0:(b==1)?w1:(b==2)?w2:(b==3)?w3:(b==4)?w4:w5;
  for(int j=0;j<16;++j){
    int f = j*256+t; int k = f>>5, c4 = f&31;
    float4 v = *(const float4*)(W + (size_t)k*DD + c4*4);
    tw[c4*4+0][k]=(f16)v.x; tw[c4*4+1][k]=(f16)v.y; tw[c4*4+2][k]=(f16)v.z; tw[c4*4+3][k]=(f16)v.w;
  }
  __syncthreads();
  f16* dst = wh + (size_t)b*16384;
  for(int j=0;j<8;++j){
    int f = j*256+t; int c = f>>4, seg = f&15;
    *(int4*)&dst[(size_t)c*DD + seg*8] = *(int4*)&tw[c][seg*8];
  }
}

// ================= fused x-GEMMs via MFMA: h1h, mapped, s1, s2 (x f32 staged->f16) =================
__global__ __launch_bounds__(256) void k_xgemms(
    const float* __restrict__ x, const f16* __restrict__ wh,
    f16* __restrict__ h1h, f16* __restrict__ mapped,
    float* __restrict__ s1, float* __restrict__ s2,
    float bn, float sscale, int n){
  __shared__ __align__(16) f16 at[64][136];
  __shared__ __align__(16) f16 wt[128][136];
  int t = threadIdx.x;
  int r0 = blockIdx.x*64;
  int l = t&63, w = t>>6, li = l&15, g = l>>4;
  // stage A-tile (64 rows of x, f32 -> f16)
  for(int p=0;p<4;++p){
    int row = p*16 + (t>>4), seg = t&15;
    union{ f16 h[8]; int4 v; } u;
    u.v = make_int4(0,0,0,0);
    if(r0+row < n){
      const float* src = x + (size_t)(r0+row)*DD + seg*8;
      float4 a = *(const float4*)src, b = *(const float4*)(src+4);
      u.h[0]=(f16)a.x; u.h[1]=(f16)a.y; u.h[2]=(f16)a.z; u.h[3]=(f16)a.w;
      u.h[4]=(f16)b.x; u.h[5]=(f16)b.y; u.h[6]=(f16)b.z; u.h[7]=(f16)b.w;
    }
    *(int4*)&at[row][seg*8] = u.v;
  }
  for(int p=0;p<4;++p){
    __syncthreads();
    const f16* Wp = wh + (size_t)p*16384;
    for(int j=0;j<8;++j){
      int f = j*256+t; int c = f>>4, seg = f&15;
      *(int4*)&wt[c][seg*8] = *(const int4*)(Wp + (size_t)c*DD + seg*8);
    }
    __syncthreads();
    f32x4 acc[8];
    #pragma unroll
    for(int ct=0;ct<8;++ct) acc[ct] = (f32x4){0.f,0.f,0.f,0.f};
    #pragma unroll
    for(int ks=0;ks<4;++ks){
      f16x8 a = *(const f16x8*)&at[w*16+li][ks*32+g*8];
      #pragma unroll
      for(int ct=0;ct<8;++ct){
        f16x8 b = *(const f16x8*)&wt[ct*16+li][ks*32+g*8];
        acc[ct] = __builtin_amdgcn_mfma_f32_16x16x32_f16(a, b, acc[ct], 0,0,0);
      }
    }
    if(p<2){
      f16* out = p ? mapped : h1h;
      __syncthreads();
      #pragma unroll
      for(int ct=0;ct<8;++ct)
        #pragma unroll
        for(int reg=0;reg<4;++reg)
          wt[w*16+g*4+reg][ct*16+li] = (f16)(acc[ct][reg]*bn);
      __syncthreads();
      for(int j=0;j<4;++j){
        int f = j*256+t; int row = f>>4, seg = f&15;
        if(r0+row < n) *(int4*)&out[(size_t)(r0+row)*DD + seg*8] = *(int4*)&wt[row][seg*8];
      }
    } else {
      float* sd = (p==2) ? s1 : s2;
      #pragma unroll
      for(int reg=0;reg<4;++reg){
        float pd = 0.f;
        #pragma unroll
        for(int ct=0;ct<8;++ct)
          pd += acc[ct][reg]*(float)at[w*16+g*4+reg][ct*16+li];
        pd += __shfl_xor(pd,1,64); pd += __shfl_xor(pd,2,64);
        pd += __shfl_xor(pd,4,64); pd += __shfl_xor(pd,8,64);
        if(li==0){
          int grow = r0 + w*16 + g*4 + reg;
          if(grow < n) sd[grow] = tanhf(sscale*pd);
        }
      }
    }
  }
}

// ================= highway GEMM + gcn2 GEMM fused (y2h -> y3h -> h3h) =================
__global__ __launch_bounds__(256) void k_hw2(
    const f16* __restrict__ y2h, const f16* __restrict__ y1h,
    const f16* __restrict__ wh, f16* __restrict__ y3h, f16* __restrict__ h3h,
    float bn, int n){
  __shared__ __align__(16) f16 at[64][136];
  __shared__ __align__(16) f16 wt[128][136];
  int t = threadIdx.x;
  int r0 = blockIdx.x*64;
  int l = t&63, w = t>>6, li = l&15, g = l>>4;
  for(int p=0;p<4;++p){
    int row = p*16 + (t>>4), seg = t&15;
    int4 v = make_int4(0,0,0,0);
    if(r0+row < n) v = *(const int4*)(y2h + (size_t)(r0+row)*DD + seg*8);
    *(int4*)&at[row][seg*8] = v;
  }
  __syncthreads();
  for(int j=0;j<8;++j){
    int f = j*256+t; int c = f>>4, seg = f&15;
    *(int4*)&wt[c][seg*8] = *(const int4*)(wh + (size_t)4*16384 + (size_t)c*DD + seg*8);
  }
  __syncthreads();
  f32x4 acc[8];
  #pragma unroll
  for(int ct=0;ct<8;++ct) acc[ct] = (f32x4){0.f,0.f,0.f,0.f};
  #pragma unroll
  for(int ks=0;ks<4;++ks){
    f16x8 a = *(const f16x8*)&at[w*16+li][ks*32+g*8];
    #pragma unroll
    for(int ct=0;ct<8;++ct){
      f16x8 b = *(const f16x8*)&wt[ct*16+li][ks*32+g*8];
      acc[ct] = __builtin_amdgcn_mfma_f32_16x16x32_f16(a, b, acc[ct], 0,0,0);
    }
  }
  float res[8][4];
  #pragma unroll
  for(int ct=0;ct<8;++ct)
    #pragma unroll
    for(int reg=0;reg<4;++reg){
      int lrow = w*16+g*4+reg, col = ct*16+li;
      int grow = r0+lrow;
      float gt = tanhf(bn*acc[ct][reg]); gt = fmaxf(gt, 0.f);
      float y1v = (grow<n)? (float)y1h[(size_t)grow*DD+col] : 0.f;
      float y2v = (float)at[lrow][col];
      res[ct][reg] = tanhf(bn*(y1v*(1.f-gt) + y2v*gt));
    }
  #pragma unroll
  for(int ct=0;ct<8;++ct)
    #pragma unroll
    for(int reg=0;reg<4;++reg)
      at[w*16+g*4+reg][ct*16+li] = (f16)res[ct][reg];
  __syncthreads();
  for(int j=0;j<4;++j){
    int f = j*256+t; int row = f>>4, seg = f&15;
    if(r0+row < n) *(int4*)&y3h[(size_t)(r0+row)*DD + seg*8] = *(int4*)&at[row][seg*8];
  }
  __syncthreads();
  for(int j=0;j<8;++j){
    int f = j*256+t; int c = f>>4, seg = f&15;
    *(int4*)&wt[c][seg*8] = *(const int4*)(wh + (size_t)5*16384 + (size_t)c*DD + seg*8);
  }
  __syncthreads();
  #pragma unroll
  for(int ct=0;ct<8;++ct) acc[ct] = (f32x4){0.f,0.f,0.f,0.f};
  #pragma unroll
  for(int ks=0;ks<4;++ks){
    f16x8 a = *(const f16x8*)&at[w*16+li][ks*32+g*8];
    #pragma unroll
    for(int ct=0;ct<8;++ct){
      f16x8 b = *(const f16x8*)&wt[ct*16+li][ks*32+g*8];
      acc[ct] = __builtin_amdgcn_mfma_f32_16x16x32_f16(a, b, acc[ct], 0,0,0);
    }
  }
  __syncthreads();
  #pragma unroll
  for(int ct=0;ct<8;++ct)
    #pragma unroll
    for(int reg=0;reg<4;++reg)
      wt[w*16+g*4+reg][ct*16+li] = (f16)(acc[ct][reg]*bn);
  __syncthreads();
  for(int j=0;j<4;++j){
    int f = j*256+t; int row = f>>4, seg = f&15;
    if(r0+row < n) *(int4*)&h3h[(size_t)(r0+row)*DD + seg*8] = *(int4*)&wt[row][seg*8];
  }
}

// ================= device helpers: spmm row / attn row (unroll 8) =================
__device__ __forceinline__ void spmm_row(const int* __restrict__ rs, const int2* __restrict__ e1,
                                         const __half* __restrict__ h, const float* __restrict__ bias,
                                         __half* __restrict__ out, int row, int lane){
  int beg = rs[row], end = rs[row+1];
  float ax=0.f, ay=0.f;
  int k = beg;
  for(; k+8<=end; k+=8){
    int2 cv[8]; __half2 hh[8];
    #pragma unroll
    for(int j=0;j<8;++j) cv[j] = e1[k+j];
    #pragma unroll
    for(int j=0;j<8;++j) hh[j] = ((const __half2*)(h + (size_t)cv[j].x*DD))[lane];
    #pragma unroll
    for(int j=0;j<8;++j){
      float v = __int_as_float(cv[j].y);
      float2 f = __half22float2(hh[j]);
      ax += v*f.x; ay += v*f.y;
    }
  }
  for(; k<end; ++k){
    int2 cv = e1[k];
    float v = __int_as_float(cv.y);
    float2 f = __half22float2(((const __half2*)(h + (size_t)cv.x*DD))[lane]);
    ax += v*f.x; ay += v*f.y;
  }
  float2 b = ((const float2*)bias)[lane];
  ((__half2*)(out + (size_t)row*DD))[lane] = __floats2half2_rn(tanhf(ax+b.x), tanhf(ay+b.y));
}

__device__ __forceinline__ void attn_row(const int* __restrict__ rs, const int* __restrict__ e2,
                                         const float* __restrict__ s1, const float* __restrict__ s2,
                                         const __half* __restrict__ mapped, __half* __restrict__ out,
                                         int row, int lane){
  int beg = rs[row], end = rs[row+1];
  float s1r = s1[row];
  float ax=0.f, ay=0.f, den=0.f;
  int k = beg;
  for(; k+8<=end; k+=8){
    int cs[8]; float sv[8]; __half2 mh[8];
    #pragma unroll
    for(int j=0;j<8;++j) cs[j] = e2[k+j];
    #pragma unroll
    for(int j=0;j<8;++j) sv[j] = s2[cs[j]];
    #pragma unroll
    for(int j=0;j<8;++j) mh[j] = ((const __half2*)(mapped + (size_t)cs[j]*DD))[lane];
    #pragma unroll
    for(int j=0;j<8;++j){
      float e = s1r + sv[j]; e = (e>=0.f)? e : 0.2f*e;
      float ex = __expf(e);
      float2 f = __half22float2(mh[j]);
      den += ex; ax += ex*f.x; ay += ex*f.y;
    }
  }
  for(; k<end; ++k){
    int c = e2[k];
    float e = s1r + s2[c]; e = (e>=0.f)? e : 0.2f*e;
    float ex = __expf(e);
    float2 f = __half22float2(((const __half2*)(mapped + (size_t)c*DD))[lane]);
    den += ex; ax += ex*f.x; ay += ex*f.y;
  }
  float inv = (end > beg) ? 1.0f/den : 0.0f;
  ((__half2*)(out + (size_t)row*DD))[lane] = __floats2half2_rn(ax*inv, ay*inv);
}

// ================= merged aggregation 1: spmm(a1,h1h)+tanh -> y1h  AND attn -> y2h =================
__global__ void k_agg1(const int* __restrict__ rs, const int2* __restrict__ e1,
                       const __half* __restrict__ h1h, const float* __restrict__ b1, __half* __restrict__ y1h,
                       const int* __restrict__ e2, const float* __restrict__ s1, const float* __restrict__ s2,
                       const __half* __restrict__ mapped, __half* __restrict__ y2h,
                       int n, int gR){
  int lane = threadIdx.x & 63;
  if((int)blockIdx.x < gR){
    int row = blockIdx.x*4 + (threadIdx.x>>6);
    if(row>=n) return;
    spmm_row(rs, e1, h1h, b1, y1h, row, lane);
  } else {
    int row = (blockIdx.x-gR)*4 + (threadIdx.x>>6);
    if(row>=n) return;
    attn_row(rs+(n+1), e2, s1, s2, mapped, y2h, row, lane);
  }
}

// ================= spmm2: y4h = tanh(spmm(a1,h3h)+b2) =================
__global__ void k_spmm2(const int* __restrict__ rs, const int2* __restrict__ e1,
                        const __half* __restrict__ h, const float* __restrict__ bias,
                        __half* __restrict__ out, int n){
  int row = blockIdx.x*4 + (threadIdx.x>>6);
  if(row>=n) return;
  spmm_row(rs, e1, h, bias, out, row, threadIdx.x & 63);
}

// ================= final: out = l2norm(concat(l2norm(y3), l2norm(y4), l2norm(x))) =================
__global__ void k_final(const __half* __restrict__ y3, const __half* __restrict__ y4,
                        const float* __restrict__ x, float* __restrict__ out, int n){
  int row = blockIdx.x*4 + (threadIdx.x>>6);
  if(row>=n) return;
  int lane = threadIdx.x & 63;
  float2 a = __half22float2(((const __half2*)(y3 + (size_t)row*DD))[lane]);
  float2 b = __half22float2(((const __half2*)(y4 + (size_t)row*DD))[lane]);
  float2 c = ((const float2*)(x  + (size_t)row*DD))[lane];
  float sa = a.x*a.x + a.y*a.y;
  float sb = b.x*b.x + b.y*b.y;
  float sc = c.x*c.x + c.y*c.y;
  #pragma unroll
  for(int off=32; off; off>>=1){
    sa += __shfl_xor(sa, off, 64);
    sb += __shfl_xor(sb, off, 64);
    sc += __shfl_xor(sc, off, 64);
  }
  float ia = rsqrtf(fmaxf(sa, 1e-12f));
  float ib = rsqrtf(fmaxf(sb, 1e-12f));
  float ic = rsqrtf(fmaxf(sc, 1e-12f));
  float tot = sa*ia*ia + sb*ib*ib + sc*ic*ic;
  float f = rsqrtf(fmaxf(tot, 1e-12f));
  float fa = ia*f, fb = ib*f, fc = ic*f;
  float2* o = (float2*)(out + (size_t)row*(3*DD));
  o[lane]     = make_float2(a.x*fa, a.y*fa);
  o[64+lane]  = make_float2(b.x*fb, b.y*fb);
  o[128+lane] = make_float2(c.x*fc, c.y*fc);
}

// ================= launch =================
extern "C" void kernel_launch(void* const* d_in, const int* in_sizes, int n_in,
                              void* d_out, int out_size, void* d_ws, size_t ws_size,
                              hipStream_t stream){
  const float* x   = (const float*)d_in[0];
  const int*   a1r = (const int*)d_in[1];
  const int*   a1c = (const int*)d_in[2];
  const float* a1v = (const float*)d_in[3];
  const int*   a2r = (const int*)d_in[4];
  const int*   a2c = (const int*)d_in[5];
  const float* w1  = (const float*)d_in[7];
  const float* b1  = (const float*)d_in[8];
  const float* watt= (const float*)d_in[9];
  const float* m1  = (const float*)d_in[10];
  const float* m2  = (const float*)d_in[11];
  const float* whw = (const float*)d_in[12];
  const float* w2  = (const float*)d_in[13];
  const float* b2  = (const float*)d_in[14];

  const int N = in_sizes[0]/DD;
  const int E = in_sizes[1];
  const float BN = (float)(1.0/sqrt(1.0+1e-3));
  const size_t NB = (size_t)N*DD;

  int tile = 8192, nt = (E+tile-1)/tile;
  while(nt > 256){ tile <<= 1; nt = (E+tile-1)/tile; }
  const int nbk = (N + (1<<BSH) - 1) >> BSH;

  // workspace layout (f16 activations)
  f16* Bh = (f16*)d_ws;             // h1h -> h3h   (CSR staging alias)
  f16* Ch = Bh + NB;                // mapped -> y3h
  f16* Dh = Ch + NB;                // y1h -> y4h
  f16* Eh = Dh + NB;                // y2h
  f16* wh = Eh + NB;                // 6*16384
  float* s1 = (float*)(wh + 6*16384);   // N
  float* s2 = s1 + N;               // N
  int*  rs  = (int*)(s2 + N);       // 2*(N+1)
  uintptr_t pa = ((uintptr_t)(rs + 2*(N+1)) + 15) & ~(uintptr_t)15;
  int2* e1  = (int2*)pa;            // E
  int*  e2  = (int*)(e1 + E);       // E
  int*  hist = e2 + E;              // 2*nt*256
  int*  colsum = hist + (size_t)2*nt*256; // 512
  int*  base = colsum + 512;        // 2*257

  int2* st1 = (int2*)Bh;            // E (alias, dead before h1h written)
  int*  st2 = (int*)(st1 + E);      // E

  const int gR = (N+3)/4;
  const int gM = (N+63)/64;
  float* out = (float*)d_out;

  // ---- prep: weights to f16^T ----
  k_wprep<<<6,256,0,stream>>>(w1, watt, m1, m2, whw, w2, wh);

  // ---- CSR build ----
  k_hist<<<nt,256,0,stream>>>(a1r, a2r, hist, E, tile, nt);
  k_colscan<<<512,256,0,stream>>>(hist, colsum, nt);
  k_basescan<<<1,512,0,stream>>>(colsum, base);
  k_partition<<<nt,256,0,stream>>>(a1r,a1c,a1v, a2r,a2c, hist, base, st1, st2, E, tile, nt);
  k_csr_bucket<<<2*nbk,256,0,stream>>>(st1, st2, base, e1, e2, rs, N, nbk);

  // ---- fused x GEMMs: h1h(Bh), mapped(Ch), s1, s2 ----
  k_xgemms<<<gM,256,0,stream>>>(x, wh, Bh, Ch, s1, s2, BN, BN*BN, N);

  // ---- merged aggregation: y1h(Dh) + y2h(Eh) ----
  k_agg1<<<2*gR,256,0,stream>>>(rs, e1, (const __half*)Bh, b1, (__half*)Dh,
                                e2, s1, s2, (const __half*)Ch, (__half*)Eh, N, gR);

  // ---- highway + gcn2 GEMMs: y3h(Ch), h3h(Bh) ----
  k_hw2<<<gM,256,0,stream>>>(Eh, Dh, wh, Ch, Bh, BN, N);

  // ---- GCN2 aggregate: y4h(Dh) ----
  k_spmm2<<<gR,256,0,stream>>>(rs, e1, (const __half*)Bh, b2, (__half*)Dh, N);

  // ---- final ----
  k_final<<<gR,256,0,stream>>>((const __half*)Ch, (const __half*)Dh, x, out, N);
}

// Round 9
// 438.340 us; speedup vs baseline: 3.5337x; 1.1345x over previous
//
#include <hip/hip_runtime.h>
#include <hip/hip_fp16.h>
#include <math.h>
#include <stdint.h>

#define DD 128
#define BSH 9            // bucket shift: 512 rows per bucket

typedef _Float16 f16;
typedef _Float16 f16x8 __attribute__((ext_vector_type(8)));
typedef float f32x4 __attribute__((ext_vector_type(4)));

// ================= merged: weight prep (blocks 0..5) + edge histogram (blocks 6..) =================
__global__ __launch_bounds__(256) void k_ph(
    const float* __restrict__ w0, const float* __restrict__ w1, const float* __restrict__ w2,
    const float* __restrict__ w3, const float* __restrict__ w4, const float* __restrict__ w5,
    f16* __restrict__ wh,
    const int* __restrict__ r1, const int* __restrict__ r2, int* __restrict__ hist,
    int E, int tile, int nt){
  __shared__ __align__(16) unsigned char smem[128*136*2];
  int t = threadIdx.x;
  if((int)blockIdx.x < 6){
    auto tw = (f16 (*)[136])smem;
    int b = blockIdx.x;
    const float* W = (b==0)?w0:(b==1)?w1:(b==2)?w2:(b==3)?w3:(b==4)?w4:w5;
    for(int j=0;j<16;++j){
      int f = j*256+t; int k = f>>5, c4 = f&31;
      float4 v = *(const float4*)(W + (size_t)k*DD + c4*4);
      tw[c4*4+0][k]=(f16)v.x; tw[c4*4+1][k]=(f16)v.y; tw[c4*4+2][k]=(f16)v.z; tw[c4*4+3][k]=(f16)v.w;
    }
    __syncthreads();
    f16* dst = wh + (size_t)b*16384;
    for(int j=0;j<8;++j){
      int f = j*256+t; int c = f>>4, seg = f&15;
      *(int4*)&dst[(size_t)c*DD + seg*8] = *(int4*)&tw[c][seg*8];
    }
  } else {
    int* h1 = (int*)smem; int* h2 = h1+256;
    h1[t]=0; h2[t]=0; __syncthreads();
    int hb = blockIdx.x - 6;
    int e0 = hb*tile, e1 = min(e0+tile, E);
    for(int e=e0+t; e<e1; e+=256){
      atomicAdd(&h1[r1[e]>>BSH], 1);
      atomicAdd(&h2[r2[e]>>BSH], 1);
    }
    __syncthreads();
    hist[(size_t)hb*256 + t] = h1[t];
    hist[(size_t)nt*256 + (size_t)hb*256 + t] = h2[t];
  }
}

__global__ void k_colscan(int* __restrict__ hist, int* __restrict__ colsum, int nt){
  __shared__ int sh[256];
  int g = blockIdx.x>>8, b = blockIdx.x&255;
  int t = threadIdx.x;
  int* H = hist + (size_t)g*nt*256;
  int v = (t<nt)? H[(size_t)t*256+b] : 0;
  sh[t]=v; __syncthreads();
  for(int off=1; off<256; off<<=1){
    int add = (t>=off)? sh[t-off] : 0;
    __syncthreads(); sh[t]+=add; __syncthreads();
  }
  if(t<nt) H[(size_t)t*256+b] = sh[t]-v;
  if(t==255) colsum[g*256+b] = sh[255];
}

__global__ void k_basescan(const int* __restrict__ colsum, int* __restrict__ base){
  __shared__ int sh[512];
  int t = threadIdx.x;
  int g = t>>8, st = t&255;
  int v = colsum[t];
  sh[t]=v; __syncthreads();
  for(int off=1; off<256; off<<=1){
    int add = (st>=off)? sh[t-off] : 0;
    __syncthreads(); sh[t]+=add; __syncthreads();
  }
  base[g*257+st] = sh[t]-v;
  if(st==255) base[g*257+256] = sh[t];
}

// ================= merged: partition (blocks 0..nt-1) + x-GEMMs (blocks nt..) =================
// st1/st2 are DEDICATED buffers (no alias with h1h!) — R8 crash was this alias.
__global__ __launch_bounds__(256) void k_px(
    const int* __restrict__ r1, const int* __restrict__ c1, const float* __restrict__ v1,
    const int* __restrict__ r2, const int* __restrict__ c2,
    const int* __restrict__ hist, const int* __restrict__ base,
    int2* __restrict__ st1, int* __restrict__ st2, int E, int tile, int nt,
    const float* __restrict__ x, const f16* __restrict__ wh,
    f16* __restrict__ h1h, f16* __restrict__ mapped,
    float* __restrict__ s1, float* __restrict__ s2,
    float bn, float sscale, int n){
  __shared__ __align__(16) unsigned char smem[52224];
  int t = threadIdx.x;
  if((int)blockIdx.x < nt){
    int* l1 = (int*)smem; int* l2 = l1+256;
    l1[t]=0; l2[t]=0; __syncthreads();
    int bx = blockIdx.x;
    int e0 = bx*tile, e1e = min(e0+tile, E);
    const int* off1 = hist + (size_t)bx*256;
    const int* off2 = hist + (size_t)nt*256 + (size_t)bx*256;
    for(int e=e0+t; e<e1e; e+=256){
      {
        int r = r1[e]; int b = r>>BSH;
        int rank = atomicAdd(&l1[b], 1);
        int dst = base[b] + off1[b] + rank;
        st1[dst] = make_int2(((r - (b<<BSH))<<17) | c1[e], __float_as_int(v1[e]));
      }
      {
        int r = r2[e]; int b = r>>BSH;
        int rank = atomicAdd(&l2[b], 1);
        int dst = base[257+b] + off2[b] + rank;
        st2[dst] = ((r - (b<<BSH))<<17) | c2[e];
      }
    }
  } else {
    auto at = (f16 (*)[136])smem;
    auto wt = (f16 (*)[136])(smem + 64*136*2);
    int r0 = (blockIdx.x - nt)*64;
    int l = t&63, w = t>>6, li = l&15, g = l>>4;
    for(int p=0;p<4;++p){
      int row = p*16 + (t>>4), seg = t&15;
      union{ f16 h[8]; int4 v; } u;
      u.v = make_int4(0,0,0,0);
      if(r0+row < n){
        const float* src = x + (size_t)(r0+row)*DD + seg*8;
        float4 a = *(const float4*)src, b = *(const float4*)(src+4);
        u.h[0]=(f16)a.x; u.h[1]=(f16)a.y; u.h[2]=(f16)a.z; u.h[3]=(f16)a.w;
        u.h[4]=(f16)b.x; u.h[5]=(f16)b.y; u.h[6]=(f16)b.z; u.h[7]=(f16)b.w;
      }
      *(int4*)&at[row][seg*8] = u.v;
    }
    for(int p=0;p<4;++p){
      __syncthreads();
      const f16* Wp = wh + (size_t)p*16384;
      for(int j=0;j<8;++j){
        int f = j*256+t; int c = f>>4, seg = f&15;
        *(int4*)&wt[c][seg*8] = *(const int4*)(Wp + (size_t)c*DD + seg*8);
      }
      __syncthreads();
      f32x4 acc[8];
      #pragma unroll
      for(int ct=0;ct<8;++ct) acc[ct] = (f32x4){0.f,0.f,0.f,0.f};
      #pragma unroll
      for(int ks=0;ks<4;++ks){
        f16x8 a = *(const f16x8*)&at[w*16+li][ks*32+g*8];
        #pragma unroll
        for(int ct=0;ct<8;++ct){
          f16x8 b = *(const f16x8*)&wt[ct*16+li][ks*32+g*8];
          acc[ct] = __builtin_amdgcn_mfma_f32_16x16x32_f16(a, b, acc[ct], 0,0,0);
        }
      }
      if(p<2){
        f16* out = p ? mapped : h1h;
        __syncthreads();
        #pragma unroll
        for(int ct=0;ct<8;++ct)
          #pragma unroll
          for(int reg=0;reg<4;++reg)
            wt[w*16+g*4+reg][ct*16+li] = (f16)(acc[ct][reg]*bn);
        __syncthreads();
        for(int j=0;j<4;++j){
          int f = j*256+t; int row = f>>4, seg = f&15;
          if(r0+row < n) *(int4*)&out[(size_t)(r0+row)*DD + seg*8] = *(int4*)&wt[row][seg*8];
        }
      } else {
        float* sd = (p==2) ? s1 : s2;
        #pragma unroll
        for(int reg=0;reg<4;++reg){
          float pd = 0.f;
          #pragma unroll
          for(int ct=0;ct<8;++ct)
            pd += acc[ct][reg]*(float)at[w*16+g*4+reg][ct*16+li];
          pd += __shfl_xor(pd,1,64); pd += __shfl_xor(pd,2,64);
          pd += __shfl_xor(pd,4,64); pd += __shfl_xor(pd,8,64);
          if(li==0){
            int grow = r0 + w*16 + g*4 + reg;
            if(grow < n) sd[grow] = tanhf(sscale*pd);
          }
        }
      }
    }
  }
}

__global__ void k_csr_bucket(const int2* __restrict__ st1, const int* __restrict__ st2,
                             const int* __restrict__ base,
                             int2* __restrict__ e1, int* __restrict__ e2,
                             int* __restrict__ rs, int N, int nbk){
  __shared__ int cnt[512];
  __shared__ int cur[512];
  __shared__ int sc[256];
  int g = blockIdx.x / nbk;
  int b = blockIdx.x % nbk;
  int t = threadIdx.x;
  cnt[t]=0; cnt[256+t]=0;
  __syncthreads();
  int ebeg = base[g*257+b], eend = base[g*257+b+1];
  if(g==0){
    for(int i=ebeg+t; i<eend; i+=256) atomicAdd(&cnt[st1[i].x>>17], 1);
  } else {
    for(int i=ebeg+t; i<eend; i+=256) atomicAdd(&cnt[st2[i]>>17], 1);
  }
  __syncthreads();
  int a0 = cnt[2*t], a1 = cnt[2*t+1];
  int s = a0+a1;
  sc[t]=s; __syncthreads();
  for(int off=1; off<256; off<<=1){
    int add = (t>=off)? sc[t-off] : 0;
    __syncthreads(); sc[t]+=add; __syncthreads();
  }
  int ex = sc[t]-s;
  cur[2*t] = ex; cur[2*t+1] = ex + a0;
  __syncthreads();
  int r0 = b<<BSH;
  int* rsg = rs + (size_t)g*(N+1);
  for(int i=t; i<512; i+=256){
    int r = r0+i;
    if(r<N) rsg[r] = ebeg + cur[i];
  }
  if(b==nbk-1 && t==0) rsg[N] = base[g*257+256];
  __syncthreads();
  if(g==0){
    for(int i=ebeg+t; i<eend; i+=256){
      int2 w = st1[i];
      int lr = w.x>>17;
      int p = ebeg + atomicAdd(&cur[lr], 1);
      e1[p] = make_int2(w.x & 0x1FFFF, w.y);
    }
  } else {
    for(int i=ebeg+t; i<eend; i+=256){
      int w = st2[i];
      int lr = w>>17;
      int p = ebeg + atomicAdd(&cur[lr], 1);
      e2[p] = w & 0x1FFFF;
    }
  }
}

// ================= highway GEMM + gcn2 GEMM fused (y2h -> y3h -> h3h) =================
__global__ __launch_bounds__(256) void k_hw2(
    const f16* __restrict__ y2h, const f16* __restrict__ y1h,
    const f16* __restrict__ wh, f16* __restrict__ y3h, f16* __restrict__ h3h,
    float bn, int n){
  __shared__ __align__(16) f16 at[64][136];
  __shared__ __align__(16) f16 wt[128][136];
  int t = threadIdx.x;
  int r0 = blockIdx.x*64;
  int l = t&63, w = t>>6, li = l&15, g = l>>4;
  for(int p=0;p<4;++p){
    int row = p*16 + (t>>4), seg = t&15;
    int4 v = make_int4(0,0,0,0);
    if(r0+row < n) v = *(const int4*)(y2h + (size_t)(r0+row)*DD + seg*8);
    *(int4*)&at[row][seg*8] = v;
  }
  __syncthreads();
  for(int j=0;j<8;++j){
    int f = j*256+t; int c = f>>4, seg = f&15;
    *(int4*)&wt[c][seg*8] = *(const int4*)(wh + (size_t)4*16384 + (size_t)c*DD + seg*8);
  }
  __syncthreads();
  f32x4 acc[8];
  #pragma unroll
  for(int ct=0;ct<8;++ct) acc[ct] = (f32x4){0.f,0.f,0.f,0.f};
  #pragma unroll
  for(int ks=0;ks<4;++ks){
    f16x8 a = *(const f16x8*)&at[w*16+li][ks*32+g*8];
    #pragma unroll
    for(int ct=0;ct<8;++ct){
      f16x8 b = *(const f16x8*)&wt[ct*16+li][ks*32+g*8];
      acc[ct] = __builtin_amdgcn_mfma_f32_16x16x32_f16(a, b, acc[ct], 0,0,0);
    }
  }
  float res[8][4];
  #pragma unroll
  for(int ct=0;ct<8;++ct)
    #pragma unroll
    for(int reg=0;reg<4;++reg){
      int lrow = w*16+g*4+reg, col = ct*16+li;
      int grow = r0+lrow;
      float gt = tanhf(bn*acc[ct][reg]); gt = fmaxf(gt, 0.f);
      float y1v = (grow<n)? (float)y1h[(size_t)grow*DD+col] : 0.f;
      float y2v = (float)at[lrow][col];
      res[ct][reg] = tanhf(bn*(y1v*(1.f-gt) + y2v*gt));
    }
  #pragma unroll
  for(int ct=0;ct<8;++ct)
    #pragma unroll
    for(int reg=0;reg<4;++reg)
      at[w*16+g*4+reg][ct*16+li] = (f16)res[ct][reg];
  __syncthreads();
  for(int j=0;j<4;++j){
    int f = j*256+t; int row = f>>4, seg = f&15;
    if(r0+row < n) *(int4*)&y3h[(size_t)(r0+row)*DD + seg*8] = *(int4*)&at[row][seg*8];
  }
  __syncthreads();
  for(int j=0;j<8;++j){
    int f = j*256+t; int c = f>>4, seg = f&15;
    *(int4*)&wt[c][seg*8] = *(const int4*)(wh + (size_t)5*16384 + (size_t)c*DD + seg*8);
  }
  __syncthreads();
  #pragma unroll
  for(int ct=0;ct<8;++ct) acc[ct] = (f32x4){0.f,0.f,0.f,0.f};
  #pragma unroll
  for(int ks=0;ks<4;++ks){
    f16x8 a = *(const f16x8*)&at[w*16+li][ks*32+g*8];
    #pragma unroll
    for(int ct=0;ct<8;++ct){
      f16x8 b = *(const f16x8*)&wt[ct*16+li][ks*32+g*8];
      acc[ct] = __builtin_amdgcn_mfma_f32_16x16x32_f16(a, b, acc[ct], 0,0,0);
    }
  }
  __syncthreads();
  #pragma unroll
  for(int ct=0;ct<8;++ct)
    #pragma unroll
    for(int reg=0;reg<4;++reg)
      wt[w*16+g*4+reg][ct*16+li] = (f16)(acc[ct][reg]*bn);
  __syncthreads();
  for(int j=0;j<4;++j){
    int f = j*256+t; int row = f>>4, seg = f&15;
    if(r0+row < n) *(int4*)&h3h[(size_t)(r0+row)*DD + seg*8] = *(int4*)&wt[row][seg*8];
  }
}

// ================= 32-lane-row gather helpers (2 rows per wave) =================
__device__ __forceinline__ void spmm_row32(const int* __restrict__ rs, const int2* __restrict__ e1,
                                           const __half* __restrict__ h, const float* __restrict__ bias,
                                           __half* __restrict__ out, int row, int l /*0..31*/){
  int beg = rs[row], end = rs[row+1];
  float a0=0.f, a1=0.f, a2=0.f, a3=0.f;
  if(end > beg){
    for(int k=beg; k<end; k+=8){
      int2 cv[8]; uint2 hh[8];
      #pragma unroll
      for(int j=0;j<8;++j){ int kk = min(k+j, end-1); cv[j] = e1[kk]; }
      #pragma unroll
      for(int j=0;j<8;++j) hh[j] = ((const uint2*)(h + (size_t)cv[j].x*DD))[l];
      #pragma unroll
      for(int j=0;j<8;++j){
        float v = (k+j<end)? __int_as_float(cv[j].y) : 0.f;
        float2 f0 = __half22float2(*(__half2*)&hh[j].x);
        float2 f1 = __half22float2(*(__half2*)&hh[j].y);
        a0 += v*f0.x; a1 += v*f0.y; a2 += v*f1.x; a3 += v*f1.y;
      }
    }
  }
  float4 b4 = ((const float4*)bias)[l];
  __half2 o0 = __floats2half2_rn(tanhf(a0+b4.x), tanhf(a1+b4.y));
  __half2 o1 = __floats2half2_rn(tanhf(a2+b4.z), tanhf(a3+b4.w));
  uint2 u; u.x = *(unsigned*)&o0; u.y = *(unsigned*)&o1;
  ((uint2*)(out + (size_t)row*DD))[l] = u;
}

__device__ __forceinline__ void attn_row32(const int* __restrict__ rs, const int* __restrict__ e2,
                                           const float* __restrict__ s1, const float* __restrict__ s2,
                                           const __half* __restrict__ mapped, __half* __restrict__ out,
                                           int row, int l){
  int beg = rs[row], end = rs[row+1];
  float s1r = s1[row];
  float a0=0.f, a1=0.f, a2=0.f, a3=0.f, den=0.f;
  if(end > beg){
    for(int k=beg; k<end; k+=8){
      int cs[8]; float sv[8]; uint2 mh[8];
      #pragma unroll
      for(int j=0;j<8;++j){ int kk = min(k+j, end-1); cs[j] = e2[kk]; }
      #pragma unroll
      for(int j=0;j<8;++j) sv[j] = s2[cs[j]];
      #pragma unroll
      for(int j=0;j<8;++j) mh[j] = ((const uint2*)(mapped + (size_t)cs[j]*DD))[l];
      #pragma unroll
      for(int j=0;j<8;++j){
        float e = s1r + sv[j]; e = (e>=0.f)? e : 0.2f*e;
        float ex = (k+j<end)? __expf(e) : 0.f;
        float2 f0 = __half22float2(*(__half2*)&mh[j].x);
        float2 f1 = __half22float2(*(__half2*)&mh[j].y);
        den += ex;
        a0 += ex*f0.x; a1 += ex*f0.y; a2 += ex*f1.x; a3 += ex*f1.y;
      }
    }
  }
  float inv = (end > beg) ? 1.0f/den : 0.0f;
  __half2 o0 = __floats2half2_rn(a0*inv, a1*inv);
  __half2 o1 = __floats2half2_rn(a2*inv, a3*inv);
  uint2 u; u.x = *(unsigned*)&o0; u.y = *(unsigned*)&o1;
  ((uint2*)(out + (size_t)row*DD))[l] = u;
}

// ================= merged aggregation 1: spmm(a1)->y1h AND attn->y2h (8 rows/block) =================
__global__ void k_agg1(const int* __restrict__ rs, const int2* __restrict__ e1,
                       const __half* __restrict__ h1h, const float* __restrict__ b1, __half* __restrict__ y1h,
                       const int* __restrict__ e2, const float* __restrict__ s1, const float* __restrict__ s2,
                       const __half* __restrict__ mapped, __half* __restrict__ y2h,
                       int n, int gS){
  int l = threadIdx.x & 31;
  if((int)blockIdx.x < gS){
    int row = blockIdx.x*8 + (threadIdx.x>>5);
    if(row>=n) return;
    spmm_row32(rs, e1, h1h, b1, y1h, row, l);
  } else {
    int row = (blockIdx.x-gS)*8 + (threadIdx.x>>5);
    if(row>=n) return;
    attn_row32(rs+(n+1), e2, s1, s2, mapped, y2h, row, l);
  }
}

// ================= spmm2: y4h = tanh(spmm(a1,h3h)+b2) =================
__global__ void k_spmm2(const int* __restrict__ rs, const int2* __restrict__ e1,
                        const __half* __restrict__ h, const float* __restrict__ bias,
                        __half* __restrict__ out, int n){
  int row = blockIdx.x*8 + (threadIdx.x>>5);
  if(row>=n) return;
  spmm_row32(rs, e1, h, bias, out, row, threadIdx.x & 31);
}

// ================= final: out = l2norm(concat(l2norm(y3), l2norm(y4), l2norm(x))) =================
__global__ void k_final(const __half* __restrict__ y3, const __half* __restrict__ y4,
                        const float* __restrict__ x, float* __restrict__ out, int n){
  int row = blockIdx.x*4 + (threadIdx.x>>6);
  if(row>=n) return;
  int lane = threadIdx.x & 63;
  float2 a = __half22float2(((const __half2*)(y3 + (size_t)row*DD))[lane]);
  float2 b = __half22float2(((const __half2*)(y4 + (size_t)row*DD))[lane]);
  float2 c = ((const float2*)(x  + (size_t)row*DD))[lane];
  float sa = a.x*a.x + a.y*a.y;
  float sb = b.x*b.x + b.y*b.y;
  float sc = c.x*c.x + c.y*c.y;
  #pragma unroll
  for(int off=32; off; off>>=1){
    sa += __shfl_xor(sa, off, 64);
    sb += __shfl_xor(sb, off, 64);
    sc += __shfl_xor(sc, off, 64);
  }
  float ia = rsqrtf(fmaxf(sa, 1e-12f));
  float ib = rsqrtf(fmaxf(sb, 1e-12f));
  float ic = rsqrtf(fmaxf(sc, 1e-12f));
  float tot = sa*ia*ia + sb*ib*ib + sc*ic*ic;
  float f = rsqrtf(fmaxf(tot, 1e-12f));
  float fa = ia*f, fb = ib*f, fc = ic*f;
  float2* o = (float2*)(out + (size_t)row*(3*DD));
  o[lane]     = make_float2(a.x*fa, a.y*fa);
  o[64+lane]  = make_float2(b.x*fb, b.y*fb);
  o[128+lane] = make_float2(c.x*fc, c.y*fc);
}

// ================= launch =================
extern "C" void kernel_launch(void* const* d_in, const int* in_sizes, int n_in,
                              void* d_out, int out_size, void* d_ws, size_t ws_size,
                              hipStream_t stream){
  const float* x   = (const float*)d_in[0];
  const int*   a1r = (const int*)d_in[1];
  const int*   a1c = (const int*)d_in[2];
  const float* a1v = (const float*)d_in[3];
  const int*   a2r = (const int*)d_in[4];
  const int*   a2c = (const int*)d_in[5];
  const float* w1  = (const float*)d_in[7];
  const float* b1  = (const float*)d_in[8];
  const float* watt= (const float*)d_in[9];
  const float* m1  = (const float*)d_in[10];
  const float* m2  = (const float*)d_in[11];
  const float* whw = (const float*)d_in[12];
  const float* w2  = (const float*)d_in[13];
  const float* b2  = (const float*)d_in[14];

  const int N = in_sizes[0]/DD;
  const int E = in_sizes[1];
  const float BN = (float)(1.0/sqrt(1.0+1e-3));
  const size_t NB = (size_t)N*DD;

  int tile = 8192, nt = (E+tile-1)/tile;
  while(nt > 256){ tile <<= 1; nt = (E+tile-1)/tile; }
  const int nbk = (N + (1<<BSH) - 1) >> BSH;

  // workspace layout (f16 activations; st1/st2 DEDICATED — no alias with Bh)
  f16* Bh = (f16*)d_ws;             // h1h -> h3h
  f16* Ch = Bh + NB;                // mapped -> y3h
  f16* Dh = Ch + NB;                // y1h -> y4h
  f16* Eh = Dh + NB;                // y2h
  f16* wh = Eh + NB;                // 6*16384
  float* s1 = (float*)(wh + 6*16384);   // N
  float* s2 = s1 + N;               // N
  int*  rs  = (int*)(s2 + N);       // 2*(N+1)
  uintptr_t pa = ((uintptr_t)(rs + 2*(N+1)) + 15) & ~(uintptr_t)15;
  int2* e1  = (int2*)pa;            // E
  int*  e2  = (int*)(e1 + E);       // E
  uintptr_t pb = ((uintptr_t)(e2 + E) + 15) & ~(uintptr_t)15;
  int2* st1 = (int2*)pb;            // E (dedicated)
  int*  st2 = (int*)(st1 + E);      // E (dedicated)
  int*  hist = st2 + E;             // 2*nt*256
  int*  colsum = hist + (size_t)2*nt*256; // 512
  int*  base = colsum + 512;        // 2*257

  const int gR = (N+3)/4;
  const int gS = (N+7)/8;
  const int gM = (N+63)/64;
  float* out = (float*)d_out;

  // ---- wprep + hist (merged) ----
  k_ph<<<6+nt,256,0,stream>>>(w1, watt, m1, m2, whw, w2, wh, a1r, a2r, hist, E, tile, nt);

  // ---- scans ----
  k_colscan<<<512,256,0,stream>>>(hist, colsum, nt);
  k_basescan<<<1,512,0,stream>>>(colsum, base);

  // ---- partition + x-GEMMs (merged): st1/st2, h1h(Bh), mapped(Ch), s1, s2 ----
  k_px<<<nt+gM,256,0,stream>>>(a1r,a1c,a1v, a2r,a2c, hist, base, st1, st2, E, tile, nt,
                               x, wh, Bh, Ch, s1, s2, BN, BN*BN, N);

  // ---- CSR finalize ----
  k_csr_bucket<<<2*nbk,256,0,stream>>>(st1, st2, base, e1, e2, rs, N, nbk);

  // ---- merged aggregation: y1h(Dh) + y2h(Eh) ----
  k_agg1<<<2*gS,256,0,stream>>>(rs, e1, (const __half*)Bh, b1, (__half*)Dh,
                                e2, s1, s2, (const __half*)Ch, (__half*)Eh, N, gS);

  // ---- highway + gcn2 GEMMs: y3h(Ch), h3h(Bh) ----
  k_hw2<<<gM,256,0,stream>>>(Eh, Dh, wh, Ch, Bh, BN, N);

  // ---- GCN2 aggregate: y4h(Dh) ----
  k_spmm2<<<gS,256,0,stream>>>(rs, e1, (const __half*)Bh, b2, (__half*)Dh, N);

  // ---- final ----
  k_final<<<gR,256,0,stream>>>((const __half*)Ch, (const __half*)Dh, x, out, N);
}

// Round 10
// 425.087 us; speedup vs baseline: 3.6439x; 1.0312x over previous
//
#include <hip/hip_runtime.h>
#include <hip/hip_fp16.h>
#include <math.h>
#include <stdint.h>

#define DD 128
#define BSH 9            // bucket shift: 512 rows per bucket

typedef _Float16 f16;
typedef _Float16 f16x8 __attribute__((ext_vector_type(8)));
typedef float f32x4 __attribute__((ext_vector_type(4)));

// ================= merged: weight prep (blocks 0..5) + edge histogram (blocks 6..) =================
__global__ __launch_bounds__(256) void k_ph(
    const float* __restrict__ w0, const float* __restrict__ w1, const float* __restrict__ w2,
    const float* __restrict__ w3, const float* __restrict__ w4, const float* __restrict__ w5,
    f16* __restrict__ wh,
    const int* __restrict__ r1, const int* __restrict__ r2, int* __restrict__ hist,
    int E, int tile, int nt){
  __shared__ __align__(16) unsigned char smem[128*136*2];
  int t = threadIdx.x;
  if((int)blockIdx.x < 6){
    auto tw = (f16 (*)[136])smem;
    int b = blockIdx.x;
    const float* W = (b==0)?w0:(b==1)?w1:(b==2)?w2:(b==3)?w3:(b==4)?w4:w5;
    for(int j=0;j<16;++j){
      int f = j*256+t; int k = f>>5, c4 = f&31;
      float4 v = *(const float4*)(W + (size_t)k*DD + c4*4);
      tw[c4*4+0][k]=(f16)v.x; tw[c4*4+1][k]=(f16)v.y; tw[c4*4+2][k]=(f16)v.z; tw[c4*4+3][k]=(f16)v.w;
    }
    __syncthreads();
    f16* dst = wh + (size_t)b*16384;
    for(int j=0;j<8;++j){
      int f = j*256+t; int c = f>>4, seg = f&15;
      *(int4*)&dst[(size_t)c*DD + seg*8] = *(int4*)&tw[c][seg*8];
    }
  } else {
    int* h1 = (int*)smem; int* h2 = h1+256;
    h1[t]=0; h2[t]=0; __syncthreads();
    int hb = blockIdx.x - 6;
    int e0 = hb*tile, e1 = min(e0+tile, E);
    for(int e=e0+t; e<e1; e+=256){
      atomicAdd(&h1[r1[e]>>BSH], 1);
      atomicAdd(&h2[r2[e]>>BSH], 1);
    }
    __syncthreads();
    hist[(size_t)hb*256 + t] = h1[t];
    hist[(size_t)nt*256 + (size_t)hb*256 + t] = h2[t];
  }
}

__global__ void k_colscan(int* __restrict__ hist, int* __restrict__ colsum, int nt){
  __shared__ int sh[256];
  int g = blockIdx.x>>8, b = blockIdx.x&255;
  int t = threadIdx.x;
  int* H = hist + (size_t)g*nt*256;
  int v = (t<nt)? H[(size_t)t*256+b] : 0;
  sh[t]=v; __syncthreads();
  for(int off=1; off<256; off<<=1){
    int add = (t>=off)? sh[t-off] : 0;
    __syncthreads(); sh[t]+=add; __syncthreads();
  }
  if(t<nt) H[(size_t)t*256+b] = sh[t]-v;
  if(t==255) colsum[g*256+b] = sh[255];
}

__global__ void k_basescan(const int* __restrict__ colsum, int* __restrict__ base){
  __shared__ int sh[512];
  int t = threadIdx.x;
  int g = t>>8, st = t&255;
  int v = colsum[t];
  sh[t]=v; __syncthreads();
  for(int off=1; off<256; off<<=1){
    int add = (st>=off)? sh[t-off] : 0;
    __syncthreads(); sh[t]+=add; __syncthreads();
  }
  base[g*257+st] = sh[t]-v;
  if(st==255) base[g*257+256] = sh[t];
}

// ================= merged: partition (blocks 0..nt-1) + x-GEMMs (blocks nt..) =================
__global__ __launch_bounds__(256) void k_px(
    const int* __restrict__ r1, const int* __restrict__ c1, const float* __restrict__ v1,
    const int* __restrict__ r2, const int* __restrict__ c2,
    const int* __restrict__ hist, const int* __restrict__ base,
    int2* __restrict__ st1, int* __restrict__ st2, int E, int tile, int nt,
    const float* __restrict__ x, const f16* __restrict__ wh,
    f16* __restrict__ h1h, f16* __restrict__ mapped,
    float* __restrict__ s1, float* __restrict__ s2,
    float bn, float sscale, int n){
  __shared__ __align__(16) unsigned char smem[52224];
  int t = threadIdx.x;
  if((int)blockIdx.x < nt){
    int* l1 = (int*)smem; int* l2 = l1+256;
    l1[t]=0; l2[t]=0; __syncthreads();
    int bx = blockIdx.x;
    int e0 = bx*tile, e1e = min(e0+tile, E);
    const int* off1 = hist + (size_t)bx*256;
    const int* off2 = hist + (size_t)nt*256 + (size_t)bx*256;
    for(int e=e0+t; e<e1e; e+=256){
      {
        int r = r1[e]; int b = r>>BSH;
        int rank = atomicAdd(&l1[b], 1);
        int dst = base[b] + off1[b] + rank;
        st1[dst] = make_int2(((r - (b<<BSH))<<17) | c1[e], __float_as_int(v1[e]));
      }
      {
        int r = r2[e]; int b = r>>BSH;
        int rank = atomicAdd(&l2[b], 1);
        int dst = base[257+b] + off2[b] + rank;
        st2[dst] = ((r - (b<<BSH))<<17) | c2[e];
      }
    }
  } else {
    auto at = (f16 (*)[136])smem;
    auto wt = (f16 (*)[136])(smem + 64*136*2);
    int r0 = (blockIdx.x - nt)*64;
    int l = t&63, w = t>>6, li = l&15, g = l>>4;
    for(int p=0;p<4;++p){
      int row = p*16 + (t>>4), seg = t&15;
      union{ f16 h[8]; int4 v; } u;
      u.v = make_int4(0,0,0,0);
      if(r0+row < n){
        const float* src = x + (size_t)(r0+row)*DD + seg*8;
        float4 a = *(const float4*)src, b = *(const float4*)(src+4);
        u.h[0]=(f16)a.x; u.h[1]=(f16)a.y; u.h[2]=(f16)a.z; u.h[3]=(f16)a.w;
        u.h[4]=(f16)b.x; u.h[5]=(f16)b.y; u.h[6]=(f16)b.z; u.h[7]=(f16)b.w;
      }
      *(int4*)&at[row][seg*8] = u.v;
    }
    for(int p=0;p<4;++p){
      __syncthreads();
      const f16* Wp = wh + (size_t)p*16384;
      for(int j=0;j<8;++j){
        int f = j*256+t; int c = f>>4, seg = f&15;
        *(int4*)&wt[c][seg*8] = *(const int4*)(Wp + (size_t)c*DD + seg*8);
      }
      __syncthreads();
      f32x4 acc[8];
      #pragma unroll
      for(int ct=0;ct<8;++ct) acc[ct] = (f32x4){0.f,0.f,0.f,0.f};
      #pragma unroll
      for(int ks=0;ks<4;++ks){
        f16x8 a = *(const f16x8*)&at[w*16+li][ks*32+g*8];
        #pragma unroll
        for(int ct=0;ct<8;++ct){
          f16x8 b = *(const f16x8*)&wt[ct*16+li][ks*32+g*8];
          acc[ct] = __builtin_amdgcn_mfma_f32_16x16x32_f16(a, b, acc[ct], 0,0,0);
        }
      }
      if(p<2){
        f16* out = p ? mapped : h1h;
        __syncthreads();
        #pragma unroll
        for(int ct=0;ct<8;++ct)
          #pragma unroll
          for(int reg=0;reg<4;++reg)
            wt[w*16+g*4+reg][ct*16+li] = (f16)(acc[ct][reg]*bn);
        __syncthreads();
        for(int j=0;j<4;++j){
          int f = j*256+t; int row = f>>4, seg = f&15;
          if(r0+row < n) *(int4*)&out[(size_t)(r0+row)*DD + seg*8] = *(int4*)&wt[row][seg*8];
        }
      } else {
        float* sd = (p==2) ? s1 : s2;
        #pragma unroll
        for(int reg=0;reg<4;++reg){
          float pd = 0.f;
          #pragma unroll
          for(int ct=0;ct<8;++ct)
            pd += acc[ct][reg]*(float)at[w*16+g*4+reg][ct*16+li];
          pd += __shfl_xor(pd,1,64); pd += __shfl_xor(pd,2,64);
          pd += __shfl_xor(pd,4,64); pd += __shfl_xor(pd,8,64);
          if(li==0){
            int grow = r0 + w*16 + g*4 + reg;
            if(grow < n) sd[grow] = tanhf(sscale*pd);
          }
        }
      }
    }
  }
}

__global__ void k_csr_bucket(const int2* __restrict__ st1, const int* __restrict__ st2,
                             const int* __restrict__ base,
                             int2* __restrict__ e1, int* __restrict__ e2,
                             int* __restrict__ rs, int N, int nbk){
  __shared__ int cnt[512];
  __shared__ int cur[512];
  __shared__ int sc[256];
  int g = blockIdx.x / nbk;
  int b = blockIdx.x % nbk;
  int t = threadIdx.x;
  cnt[t]=0; cnt[256+t]=0;
  __syncthreads();
  int ebeg = base[g*257+b], eend = base[g*257+b+1];
  if(g==0){
    for(int i=ebeg+t; i<eend; i+=256) atomicAdd(&cnt[st1[i].x>>17], 1);
  } else {
    for(int i=ebeg+t; i<eend; i+=256) atomicAdd(&cnt[st2[i]>>17], 1);
  }
  __syncthreads();
  int a0 = cnt[2*t], a1 = cnt[2*t+1];
  int s = a0+a1;
  sc[t]=s; __syncthreads();
  for(int off=1; off<256; off<<=1){
    int add = (t>=off)? sc[t-off] : 0;
    __syncthreads(); sc[t]+=add; __syncthreads();
  }
  int ex = sc[t]-s;
  cur[2*t] = ex; cur[2*t+1] = ex + a0;
  __syncthreads();
  int r0 = b<<BSH;
  int* rsg = rs + (size_t)g*(N+1);
  for(int i=t; i<512; i+=256){
    int r = r0+i;
    if(r<N) rsg[r] = ebeg + cur[i];
  }
  if(b==nbk-1 && t==0) rsg[N] = base[g*257+256];
  __syncthreads();
  if(g==0){
    for(int i=ebeg+t; i<eend; i+=256){
      int2 w = st1[i];
      int lr = w.x>>17;
      int p = ebeg + atomicAdd(&cur[lr], 1);
      e1[p] = make_int2(w.x & 0x1FFFF, w.y);
    }
  } else {
    for(int i=ebeg+t; i<eend; i+=256){
      int w = st2[i];
      int lr = w>>17;
      int p = ebeg + atomicAdd(&cur[lr], 1);
      e2[p] = w & 0x1FFFF;
    }
  }
}

// ================= highway GEMM + gcn2 GEMM fused (y2h -> y3h -> h3h) =================
__global__ __launch_bounds__(256) void k_hw2(
    const f16* __restrict__ y2h, const f16* __restrict__ y1h,
    const f16* __restrict__ wh, f16* __restrict__ y3h, f16* __restrict__ h3h,
    float bn, int n){
  __shared__ __align__(16) f16 at[64][136];
  __shared__ __align__(16) f16 wt[128][136];
  int t = threadIdx.x;
  int r0 = blockIdx.x*64;
  int l = t&63, w = t>>6, li = l&15, g = l>>4;
  for(int p=0;p<4;++p){
    int row = p*16 + (t>>4), seg = t&15;
    int4 v = make_int4(0,0,0,0);
    if(r0+row < n) v = *(const int4*)(y2h + (size_t)(r0+row)*DD + seg*8);
    *(int4*)&at[row][seg*8] = v;
  }
  __syncthreads();
  for(int j=0;j<8;++j){
    int f = j*256+t; int c = f>>4, seg = f&15;
    *(int4*)&wt[c][seg*8] = *(const int4*)(wh + (size_t)4*16384 + (size_t)c*DD + seg*8);
  }
  __syncthreads();
  f32x4 acc[8];
  #pragma unroll
  for(int ct=0;ct<8;++ct) acc[ct] = (f32x4){0.f,0.f,0.f,0.f};
  #pragma unroll
  for(int ks=0;ks<4;++ks){
    f16x8 a = *(const f16x8*)&at[w*16+li][ks*32+g*8];
    #pragma unroll
    for(int ct=0;ct<8;++ct){
      f16x8 b = *(const f16x8*)&wt[ct*16+li][ks*32+g*8];
      acc[ct] = __builtin_amdgcn_mfma_f32_16x16x32_f16(a, b, acc[ct], 0,0,0);
    }
  }
  float res[8][4];
  #pragma unroll
  for(int ct=0;ct<8;++ct)
    #pragma unroll
    for(int reg=0;reg<4;++reg){
      int lrow = w*16+g*4+reg, col = ct*16+li;
      int grow = r0+lrow;
      float gt = tanhf(bn*acc[ct][reg]); gt = fmaxf(gt, 0.f);
      float y1v = (grow<n)? (float)y1h[(size_t)grow*DD+col] : 0.f;
      float y2v = (float)at[lrow][col];
      res[ct][reg] = tanhf(bn*(y1v*(1.f-gt) + y2v*gt));
    }
  #pragma unroll
  for(int ct=0;ct<8;++ct)
    #pragma unroll
    for(int reg=0;reg<4;++reg)
      at[w*16+g*4+reg][ct*16+li] = (f16)res[ct][reg];
  __syncthreads();
  for(int j=0;j<4;++j){
    int f = j*256+t; int row = f>>4, seg = f&15;
    if(r0+row < n) *(int4*)&y3h[(size_t)(r0+row)*DD + seg*8] = *(int4*)&at[row][seg*8];
  }
  __syncthreads();
  for(int j=0;j<8;++j){
    int f = j*256+t; int c = f>>4, seg = f&15;
    *(int4*)&wt[c][seg*8] = *(const int4*)(wh + (size_t)5*16384 + (size_t)c*DD + seg*8);
  }
  __syncthreads();
  #pragma unroll
  for(int ct=0;ct<8;++ct) acc[ct] = (f32x4){0.f,0.f,0.f,0.f};
  #pragma unroll
  for(int ks=0;ks<4;++ks){
    f16x8 a = *(const f16x8*)&at[w*16+li][ks*32+g*8];
    #pragma unroll
    for(int ct=0;ct<8;++ct){
      f16x8 b = *(const f16x8*)&wt[ct*16+li][ks*32+g*8];
      acc[ct] = __builtin_amdgcn_mfma_f32_16x16x32_f16(a, b, acc[ct], 0,0,0);
    }
  }
  __syncthreads();
  #pragma unroll
  for(int ct=0;ct<8;++ct)
    #pragma unroll
    for(int reg=0;reg<4;++reg)
      wt[w*16+g*4+reg][ct*16+li] = (f16)(acc[ct][reg]*bn);
  __syncthreads();
  for(int j=0;j<4;++j){
    int f = j*256+t; int row = f>>4, seg = f&15;
    if(r0+row < n) *(int4*)&h3h[(size_t)(r0+row)*DD + seg*8] = *(int4*)&wt[row][seg*8];
  }
}

// ================= 16-lane-row gather helpers (4 rows per wave, uint4 payload) =================
__device__ __forceinline__ void spmm_row16(const int* __restrict__ rs, const int2* __restrict__ e1,
                                           const __half* __restrict__ h, const float* __restrict__ bias,
                                           __half* __restrict__ out, int row, int l /*0..15*/){
  int beg = rs[row], end = rs[row+1];
  float a[8] = {0.f,0.f,0.f,0.f,0.f,0.f,0.f,0.f};
  for(int k=beg; k<end; k+=8){
    int2 cv[8];
    union{ uint4 v; __half2 h2[4]; } hh[8];
    #pragma unroll
    for(int j=0;j<8;++j){ int kk = min(k+j, end-1); cv[j] = e1[kk]; }
    #pragma unroll
    for(int j=0;j<8;++j) hh[j].v = ((const uint4*)(h + (size_t)cv[j].x*DD))[l];
    #pragma unroll
    for(int j=0;j<8;++j){
      float v = (k+j<end)? __int_as_float(cv[j].y) : 0.f;
      #pragma unroll
      for(int q=0;q<4;++q){
        float2 f = __half22float2(hh[j].h2[q]);
        a[2*q]   += v*f.x;
        a[2*q+1] += v*f.y;
      }
    }
  }
  float4 b0 = ((const float4*)bias)[2*l], b1 = ((const float4*)bias)[2*l+1];
  union{ uint4 v; __half2 h2[4]; } o;
  o.h2[0] = __floats2half2_rn(tanhf(a[0]+b0.x), tanhf(a[1]+b0.y));
  o.h2[1] = __floats2half2_rn(tanhf(a[2]+b0.z), tanhf(a[3]+b0.w));
  o.h2[2] = __floats2half2_rn(tanhf(a[4]+b1.x), tanhf(a[5]+b1.y));
  o.h2[3] = __floats2half2_rn(tanhf(a[6]+b1.z), tanhf(a[7]+b1.w));
  ((uint4*)(out + (size_t)row*DD))[l] = o.v;
}

__device__ __forceinline__ void attn_row16(const int* __restrict__ rs, const int* __restrict__ e2,
                                           const float* __restrict__ s1, const float* __restrict__ s2,
                                           const __half* __restrict__ mapped, __half* __restrict__ out,
                                           int row, int l){
  int beg = rs[row], end = rs[row+1];
  float s1r = s1[row];
  float a[8] = {0.f,0.f,0.f,0.f,0.f,0.f,0.f,0.f};
  float den = 0.f;
  for(int k=beg; k<end; k+=8){
    int cs[8]; float sv[8];
    union{ uint4 v; __half2 h2[4]; } mh[8];
    #pragma unroll
    for(int j=0;j<8;++j){ int kk = min(k+j, end-1); cs[j] = e2[kk]; }
    #pragma unroll
    for(int j=0;j<8;++j) sv[j] = s2[cs[j]];
    #pragma unroll
    for(int j=0;j<8;++j) mh[j].v = ((const uint4*)(mapped + (size_t)cs[j]*DD))[l];
    #pragma unroll
    for(int j=0;j<8;++j){
      float e = s1r + sv[j]; e = (e>=0.f)? e : 0.2f*e;
      float ex = (k+j<end)? __expf(e) : 0.f;
      den += ex;
      #pragma unroll
      for(int q=0;q<4;++q){
        float2 f = __half22float2(mh[j].h2[q]);
        a[2*q]   += ex*f.x;
        a[2*q+1] += ex*f.y;
      }
    }
  }
  float inv = (end > beg) ? 1.0f/den : 0.0f;
  union{ uint4 v; __half2 h2[4]; } o;
  o.h2[0] = __floats2half2_rn(a[0]*inv, a[1]*inv);
  o.h2[1] = __floats2half2_rn(a[2]*inv, a[3]*inv);
  o.h2[2] = __floats2half2_rn(a[4]*inv, a[5]*inv);
  o.h2[3] = __floats2half2_rn(a[6]*inv, a[7]*inv);
  ((uint4*)(out + (size_t)row*DD))[l] = o.v;
}

// ================= merged aggregation 1: spmm(a1)->y1h AND attn->y2h (16 rows/block) =================
__global__ void k_agg1(const int* __restrict__ rs, const int2* __restrict__ e1,
                       const __half* __restrict__ h1h, const float* __restrict__ b1, __half* __restrict__ y1h,
                       const int* __restrict__ e2, const float* __restrict__ s1, const float* __restrict__ s2,
                       const __half* __restrict__ mapped, __half* __restrict__ y2h,
                       int n, int gT){
  int l = threadIdx.x & 15;
  if((int)blockIdx.x < gT){
    int row = blockIdx.x*16 + (threadIdx.x>>4);
    if(row>=n) return;
    spmm_row16(rs, e1, h1h, b1, y1h, row, l);
  } else {
    int row = (blockIdx.x-gT)*16 + (threadIdx.x>>4);
    if(row>=n) return;
    attn_row16(rs+(n+1), e2, s1, s2, mapped, y2h, row, l);
  }
}

// ================= spmm2: y4h = tanh(spmm(a1,h3h)+b2) =================
__global__ void k_spmm2(const int* __restrict__ rs, const int2* __restrict__ e1,
                        const __half* __restrict__ h, const float* __restrict__ bias,
                        __half* __restrict__ out, int n){
  int row = blockIdx.x*16 + (threadIdx.x>>4);
  if(row>=n) return;
  spmm_row16(rs, e1, h, bias, out, row, threadIdx.x & 15);
}

// ================= final: out = l2norm(concat(l2norm(y3), l2norm(y4), l2norm(x))) =================
__global__ void k_final(const __half* __restrict__ y3, const __half* __restrict__ y4,
                        const float* __restrict__ x, float* __restrict__ out, int n){
  int row = blockIdx.x*4 + (threadIdx.x>>6);
  if(row>=n) return;
  int lane = threadIdx.x & 63;
  float2 a = __half22float2(((const __half2*)(y3 + (size_t)row*DD))[lane]);
  float2 b = __half22float2(((const __half2*)(y4 + (size_t)row*DD))[lane]);
  float2 c = ((const float2*)(x  + (size_t)row*DD))[lane];
  float sa = a.x*a.x + a.y*a.y;
  float sb = b.x*b.x + b.y*b.y;
  float sc = c.x*c.x + c.y*c.y;
  #pragma unroll
  for(int off=32; off; off>>=1){
    sa += __shfl_xor(sa, off, 64);
    sb += __shfl_xor(sb, off, 64);
    sc += __shfl_xor(sc, off, 64);
  }
  float ia = rsqrtf(fmaxf(sa, 1e-12f));
  float ib = rsqrtf(fmaxf(sb, 1e-12f));
  float ic = rsqrtf(fmaxf(sc, 1e-12f));
  float tot = sa*ia*ia + sb*ib*ib + sc*ic*ic;
  float f = rsqrtf(fmaxf(tot, 1e-12f));
  float fa = ia*f, fb = ib*f, fc = ic*f;
  float2* o = (float2*)(out + (size_t)row*(3*DD));
  o[lane]     = make_float2(a.x*fa, a.y*fa);
  o[64+lane]  = make_float2(b.x*fb, b.y*fb);
  o[128+lane] = make_float2(c.x*fc, c.y*fc);
}

// ================= launch =================
extern "C" void kernel_launch(void* const* d_in, const int* in_sizes, int n_in,
                              void* d_out, int out_size, void* d_ws, size_t ws_size,
                              hipStream_t stream){
  const float* x   = (const float*)d_in[0];
  const int*   a1r = (const int*)d_in[1];
  const int*   a1c = (const int*)d_in[2];
  const float* a1v = (const float*)d_in[3];
  const int*   a2r = (const int*)d_in[4];
  const int*   a2c = (const int*)d_in[5];
  const float* w1  = (const float*)d_in[7];
  const float* b1  = (const float*)d_in[8];
  const float* watt= (const float*)d_in[9];
  const float* m1  = (const float*)d_in[10];
  const float* m2  = (const float*)d_in[11];
  const float* whw = (const float*)d_in[12];
  const float* w2  = (const float*)d_in[13];
  const float* b2  = (const float*)d_in[14];

  const int N = in_sizes[0]/DD;
  const int E = in_sizes[1];
  const float BN = (float)(1.0/sqrt(1.0+1e-3));
  const size_t NB = (size_t)N*DD;

  int tile = 8192, nt = (E+tile-1)/tile;
  while(nt > 256){ tile <<= 1; nt = (E+tile-1)/tile; }
  const int nbk = (N + (1<<BSH) - 1) >> BSH;

  // workspace layout (f16 activations; st1/st2 DEDICATED — no alias with Bh)
  f16* Bh = (f16*)d_ws;             // h1h -> h3h
  f16* Ch = Bh + NB;                // mapped -> y3h
  f16* Dh = Ch + NB;                // y1h -> y4h
  f16* Eh = Dh + NB;                // y2h
  f16* wh = Eh + NB;                // 6*16384
  float* s1 = (float*)(wh + 6*16384);   // N
  float* s2 = s1 + N;               // N
  int*  rs  = (int*)(s2 + N);       // 2*(N+1)
  uintptr_t pa = ((uintptr_t)(rs + 2*(N+1)) + 15) & ~(uintptr_t)15;
  int2* e1  = (int2*)pa;            // E
  int*  e2  = (int*)(e1 + E);       // E
  uintptr_t pb = ((uintptr_t)(e2 + E) + 15) & ~(uintptr_t)15;
  int2* st1 = (int2*)pb;            // E (dedicated)
  int*  st2 = (int*)(st1 + E);      // E (dedicated)
  int*  hist = st2 + E;             // 2*nt*256
  int*  colsum = hist + (size_t)2*nt*256; // 512
  int*  base = colsum + 512;        // 2*257

  const int gR = (N+3)/4;
  const int gT = (N+15)/16;
  const int gM = (N+63)/64;
  float* out = (float*)d_out;

  // ---- wprep + hist (merged) ----
  k_ph<<<6+nt,256,0,stream>>>(w1, watt, m1, m2, whw, w2, wh, a1r, a2r, hist, E, tile, nt);

  // ---- scans ----
  k_colscan<<<512,256,0,stream>>>(hist, colsum, nt);
  k_basescan<<<1,512,0,stream>>>(colsum, base);

  // ---- partition + x-GEMMs (merged): st1/st2, h1h(Bh), mapped(Ch), s1, s2 ----
  k_px<<<nt+gM,256,0,stream>>>(a1r,a1c,a1v, a2r,a2c, hist, base, st1, st2, E, tile, nt,
                               x, wh, Bh, Ch, s1, s2, BN, BN*BN, N);

  // ---- CSR finalize ----
  k_csr_bucket<<<2*nbk,256,0,stream>>>(st1, st2, base, e1, e2, rs, N, nbk);

  // ---- merged aggregation: y1h(Dh) + y2h(Eh) ----
  k_agg1<<<2*gT,256,0,stream>>>(rs, e1, (const __half*)Bh, b1, (__half*)Dh,
                                e2, s1, s2, (const __half*)Ch, (__half*)Eh, N, gT);

  // ---- highway + gcn2 GEMMs: y3h(Ch), h3h(Bh) ----
  k_hw2<<<gM,256,0,stream>>>(Eh, Dh, wh, Ch, Bh, BN, N);

  // ---- GCN2 aggregate: y4h(Dh) ----
  k_spmm2<<<gT,256,0,stream>>>(rs, e1, (const __half*)Bh, b2, (__half*)Dh, N);

  // ---- final ----
  k_final<<<gR,256,0,stream>>>((const __half*)Ch, (const __half*)Dh, x, out, N);
}

// Round 11
// 406.905 us; speedup vs baseline: 3.8067x; 1.0447x over previous
//
#include <hip/hip_runtime.h>
#include <hip/hip_fp16.h>
#include <math.h>
#include <stdint.h>

#define DD 128
#define BSH 9            // bucket shift: 512 rows per bucket

typedef _Float16 f16;
typedef _Float16 f16x2 __attribute__((ext_vector_type(2)));
typedef _Float16 f16x8 __attribute__((ext_vector_type(8)));
typedef float f32x4 __attribute__((ext_vector_type(4)));

// ================= merged: weight prep (blocks 0..5) + edge histogram (blocks 6..) =================
__global__ __launch_bounds__(256) void k_ph(
    const float* __restrict__ w0, const float* __restrict__ w1, const float* __restrict__ w2,
    const float* __restrict__ w3, const float* __restrict__ w4, const float* __restrict__ w5,
    f16* __restrict__ wh,
    const int* __restrict__ r1, const int* __restrict__ r2, int* __restrict__ hist,
    int E, int tile, int nt){
  __shared__ __align__(16) unsigned char smem[128*136*2];
  int t = threadIdx.x;
  if((int)blockIdx.x < 6){
    auto tw = (f16 (*)[136])smem;
    int b = blockIdx.x;
    const float* W = (b==0)?w0:(b==1)?w1:(b==2)?w2:(b==3)?w3:(b==4)?w4:w5;
    for(int j=0;j<16;++j){
      int f = j*256+t; int k = f>>5, c4 = f&31;
      float4 v = *(const float4*)(W + (size_t)k*DD + c4*4);
      tw[c4*4+0][k]=(f16)v.x; tw[c4*4+1][k]=(f16)v.y; tw[c4*4+2][k]=(f16)v.z; tw[c4*4+3][k]=(f16)v.w;
    }
    __syncthreads();
    f16* dst = wh + (size_t)b*16384;
    for(int j=0;j<8;++j){
      int f = j*256+t; int c = f>>4, seg = f&15;
      *(int4*)&dst[(size_t)c*DD + seg*8] = *(int4*)&tw[c][seg*8];
    }
  } else {
    int* h1 = (int*)smem; int* h2 = h1+256;
    h1[t]=0; h2[t]=0; __syncthreads();
    int hb = blockIdx.x - 6;
    int e0 = hb*tile, e1 = min(e0+tile, E);
    for(int e=e0+t; e<e1; e+=256){
      atomicAdd(&h1[r1[e]>>BSH], 1);
      atomicAdd(&h2[r2[e]>>BSH], 1);
    }
    __syncthreads();
    hist[(size_t)hb*256 + t] = h1[t];
    hist[(size_t)nt*256 + (size_t)hb*256 + t] = h2[t];
  }
}

__global__ void k_colscan(int* __restrict__ hist, int* __restrict__ colsum, int nt){
  __shared__ int sh[256];
  int g = blockIdx.x>>8, b = blockIdx.x&255;
  int t = threadIdx.x;
  int* H = hist + (size_t)g*nt*256;
  int v = (t<nt)? H[(size_t)t*256+b] : 0;
  sh[t]=v; __syncthreads();
  for(int off=1; off<256; off<<=1){
    int add = (t>=off)? sh[t-off] : 0;
    __syncthreads(); sh[t]+=add; __syncthreads();
  }
  if(t<nt) H[(size_t)t*256+b] = sh[t]-v;
  if(t==255) colsum[g*256+b] = sh[255];
}

__global__ void k_basescan(const int* __restrict__ colsum, int* __restrict__ base){
  __shared__ int sh[512];
  int t = threadIdx.x;
  int g = t>>8, st = t&255;
  int v = colsum[t];
  sh[t]=v; __syncthreads();
  for(int off=1; off<256; off<<=1){
    int add = (st>=off)? sh[t-off] : 0;
    __syncthreads(); sh[t]+=add; __syncthreads();
  }
  base[g*257+st] = sh[t]-v;
  if(st==255) base[g*257+256] = sh[t];
}

// ================= merged: partition (blocks 0..nt-1) + x-GEMMs (blocks nt..) =================
__global__ __launch_bounds__(256) void k_px(
    const int* __restrict__ r1, const int* __restrict__ c1, const float* __restrict__ v1,
    const int* __restrict__ r2, const int* __restrict__ c2,
    const int* __restrict__ hist, const int* __restrict__ base,
    int2* __restrict__ st1, int* __restrict__ st2, int E, int tile, int nt,
    const float* __restrict__ x, const f16* __restrict__ wh,
    f16* __restrict__ h1h, f16* __restrict__ mapped,
    float* __restrict__ s1, float* __restrict__ s2,
    float bn, float sscale, int n){
  __shared__ __align__(16) unsigned char smem[52224];
  int t = threadIdx.x;
  if((int)blockIdx.x < nt){
    int* l1 = (int*)smem; int* l2 = l1+256;
    l1[t]=0; l2[t]=0; __syncthreads();
    int bx = blockIdx.x;
    int e0 = bx*tile, e1e = min(e0+tile, E);
    const int* off1 = hist + (size_t)bx*256;
    const int* off2 = hist + (size_t)nt*256 + (size_t)bx*256;
    for(int e=e0+t; e<e1e; e+=256){
      {
        int r = r1[e]; int b = r>>BSH;
        int rank = atomicAdd(&l1[b], 1);
        int dst = base[b] + off1[b] + rank;
        st1[dst] = make_int2(((r - (b<<BSH))<<17) | c1[e], __float_as_int(v1[e]));
      }
      {
        int r = r2[e]; int b = r>>BSH;
        int rank = atomicAdd(&l2[b], 1);
        int dst = base[257+b] + off2[b] + rank;
        st2[dst] = ((r - (b<<BSH))<<17) | c2[e];
      }
    }
  } else {
    auto at = (f16 (*)[136])smem;
    auto wt = (f16 (*)[136])(smem + 64*136*2);
    int r0 = (blockIdx.x - nt)*64;
    int l = t&63, w = t>>6, li = l&15, g = l>>4;
    for(int p=0;p<4;++p){
      int row = p*16 + (t>>4), seg = t&15;
      union{ f16 h[8]; int4 v; } u;
      u.v = make_int4(0,0,0,0);
      if(r0+row < n){
        const float* src = x + (size_t)(r0+row)*DD + seg*8;
        float4 a = *(const float4*)src, b = *(const float4*)(src+4);
        u.h[0]=(f16)a.x; u.h[1]=(f16)a.y; u.h[2]=(f16)a.z; u.h[3]=(f16)a.w;
        u.h[4]=(f16)b.x; u.h[5]=(f16)b.y; u.h[6]=(f16)b.z; u.h[7]=(f16)b.w;
      }
      *(int4*)&at[row][seg*8] = u.v;
    }
    for(int p=0;p<4;++p){
      __syncthreads();
      const f16* Wp = wh + (size_t)p*16384;
      for(int j=0;j<8;++j){
        int f = j*256+t; int c = f>>4, seg = f&15;
        *(int4*)&wt[c][seg*8] = *(const int4*)(Wp + (size_t)c*DD + seg*8);
      }
      __syncthreads();
      f32x4 acc[8];
      #pragma unroll
      for(int ct=0;ct<8;++ct) acc[ct] = (f32x4){0.f,0.f,0.f,0.f};
      #pragma unroll
      for(int ks=0;ks<4;++ks){
        f16x8 a = *(const f16x8*)&at[w*16+li][ks*32+g*8];
        #pragma unroll
        for(int ct=0;ct<8;++ct){
          f16x8 b = *(const f16x8*)&wt[ct*16+li][ks*32+g*8];
          acc[ct] = __builtin_amdgcn_mfma_f32_16x16x32_f16(a, b, acc[ct], 0,0,0);
        }
      }
      if(p<2){
        f16* out = p ? mapped : h1h;
        __syncthreads();
        #pragma unroll
        for(int ct=0;ct<8;++ct)
          #pragma unroll
          for(int reg=0;reg<4;++reg)
            wt[w*16+g*4+reg][ct*16+li] = (f16)(acc[ct][reg]*bn);
        __syncthreads();
        for(int j=0;j<4;++j){
          int f = j*256+t; int row = f>>4, seg = f&15;
          if(r0+row < n) *(int4*)&out[(size_t)(r0+row)*DD + seg*8] = *(int4*)&wt[row][seg*8];
        }
      } else {
        float* sd = (p==2) ? s1 : s2;
        #pragma unroll
        for(int reg=0;reg<4;++reg){
          float pd = 0.f;
          #pragma unroll
          for(int ct=0;ct<8;++ct)
            pd += acc[ct][reg]*(float)at[w*16+g*4+reg][ct*16+li];
          pd += __shfl_xor(pd,1,64); pd += __shfl_xor(pd,2,64);
          pd += __shfl_xor(pd,4,64); pd += __shfl_xor(pd,8,64);
          if(li==0){
            int grow = r0 + w*16 + g*4 + reg;
            if(grow < n) sd[grow] = tanhf(sscale*pd);
          }
        }
      }
    }
  }
}

__global__ void k_csr_bucket(const int2* __restrict__ st1, const int* __restrict__ st2,
                             const int* __restrict__ base,
                             int2* __restrict__ e1, int* __restrict__ e2,
                             int* __restrict__ rs, int N, int nbk){
  __shared__ int cnt[512];
  __shared__ int cur[512];
  __shared__ int sc[256];
  int g = blockIdx.x / nbk;
  int b = blockIdx.x % nbk;
  int t = threadIdx.x;
  cnt[t]=0; cnt[256+t]=0;
  __syncthreads();
  int ebeg = base[g*257+b], eend = base[g*257+b+1];
  if(g==0){
    for(int i=ebeg+t; i<eend; i+=256) atomicAdd(&cnt[st1[i].x>>17], 1);
  } else {
    for(int i=ebeg+t; i<eend; i+=256) atomicAdd(&cnt[st2[i]>>17], 1);
  }
  __syncthreads();
  int a0 = cnt[2*t], a1 = cnt[2*t+1];
  int s = a0+a1;
  sc[t]=s; __syncthreads();
  for(int off=1; off<256; off<<=1){
    int add = (t>=off)? sc[t-off] : 0;
    __syncthreads(); sc[t]+=add; __syncthreads();
  }
  int ex = sc[t]-s;
  cur[2*t] = ex; cur[2*t+1] = ex + a0;
  __syncthreads();
  int r0 = b<<BSH;
  int* rsg = rs + (size_t)g*(N+1);
  for(int i=t; i<512; i+=256){
    int r = r0+i;
    if(r<N) rsg[r] = ebeg + cur[i];
  }
  if(b==nbk-1 && t==0) rsg[N] = base[g*257+256];
  __syncthreads();
  if(g==0){
    for(int i=ebeg+t; i<eend; i+=256){
      int2 w = st1[i];
      int lr = w.x>>17;
      int p = ebeg + atomicAdd(&cur[lr], 1);
      e1[p] = make_int2(w.x & 0x1FFFF, w.y);
    }
  } else {
    for(int i=ebeg+t; i<eend; i+=256){
      int w = st2[i];
      int lr = w>>17;
      int p = ebeg + atomicAdd(&cur[lr], 1);
      e2[p] = w & 0x1FFFF;
    }
  }
}

// ================= highway GEMM + gcn2 GEMM fused (y2h -> y3h -> h3h) =================
__global__ __launch_bounds__(256) void k_hw2(
    const f16* __restrict__ y2h, const f16* __restrict__ y1h,
    const f16* __restrict__ wh, f16* __restrict__ y3h, f16* __restrict__ h3h,
    float bn, int n){
  __shared__ __align__(16) f16 at[64][136];
  __shared__ __align__(16) f16 wt[128][136];
  int t = threadIdx.x;
  int r0 = blockIdx.x*64;
  int l = t&63, w = t>>6, li = l&15, g = l>>4;
  for(int p=0;p<4;++p){
    int row = p*16 + (t>>4), seg = t&15;
    int4 v = make_int4(0,0,0,0);
    if(r0+row < n) v = *(const int4*)(y2h + (size_t)(r0+row)*DD + seg*8);
    *(int4*)&at[row][seg*8] = v;
  }
  __syncthreads();
  for(int j=0;j<8;++j){
    int f = j*256+t; int c = f>>4, seg = f&15;
    *(int4*)&wt[c][seg*8] = *(const int4*)(wh + (size_t)4*16384 + (size_t)c*DD + seg*8);
  }
  __syncthreads();
  f32x4 acc[8];
  #pragma unroll
  for(int ct=0;ct<8;++ct) acc[ct] = (f32x4){0.f,0.f,0.f,0.f};
  #pragma unroll
  for(int ks=0;ks<4;++ks){
    f16x8 a = *(const f16x8*)&at[w*16+li][ks*32+g*8];
    #pragma unroll
    for(int ct=0;ct<8;++ct){
      f16x8 b = *(const f16x8*)&wt[ct*16+li][ks*32+g*8];
      acc[ct] = __builtin_amdgcn_mfma_f32_16x16x32_f16(a, b, acc[ct], 0,0,0);
    }
  }
  float res[8][4];
  #pragma unroll
  for(int ct=0;ct<8;++ct)
    #pragma unroll
    for(int reg=0;reg<4;++reg){
      int lrow = w*16+g*4+reg, col = ct*16+li;
      int grow = r0+lrow;
      float gt = tanhf(bn*acc[ct][reg]); gt = fmaxf(gt, 0.f);
      float y1v = (grow<n)? (float)y1h[(size_t)grow*DD+col] : 0.f;
      float y2v = (float)at[lrow][col];
      res[ct][reg] = tanhf(bn*(y1v*(1.f-gt) + y2v*gt));
    }
  #pragma unroll
  for(int ct=0;ct<8;++ct)
    #pragma unroll
    for(int reg=0;reg<4;++reg)
      at[w*16+g*4+reg][ct*16+li] = (f16)res[ct][reg];
  __syncthreads();
  for(int j=0;j<4;++j){
    int f = j*256+t; int row = f>>4, seg = f&15;
    if(r0+row < n) *(int4*)&y3h[(size_t)(r0+row)*DD + seg*8] = *(int4*)&at[row][seg*8];
  }
  __syncthreads();
  for(int j=0;j<8;++j){
    int f = j*256+t; int c = f>>4, seg = f&15;
    *(int4*)&wt[c][seg*8] = *(const int4*)(wh + (size_t)5*16384 + (size_t)c*DD + seg*8);
  }
  __syncthreads();
  #pragma unroll
  for(int ct=0;ct<8;++ct) acc[ct] = (f32x4){0.f,0.f,0.f,0.f};
  #pragma unroll
  for(int ks=0;ks<4;++ks){
    f16x8 a = *(const f16x8*)&at[w*16+li][ks*32+g*8];
    #pragma unroll
    for(int ct=0;ct<8;++ct){
      f16x8 b = *(const f16x8*)&wt[ct*16+li][ks*32+g*8];
      acc[ct] = __builtin_amdgcn_mfma_f32_16x16x32_f16(a, b, acc[ct], 0,0,0);
    }
  }
  __syncthreads();
  #pragma unroll
  for(int ct=0;ct<8;++ct)
    #pragma unroll
    for(int reg=0;reg<4;++reg)
      wt[w*16+g*4+reg][ct*16+li] = (f16)(acc[ct][reg]*bn);
  __syncthreads();
  for(int j=0;j<4;++j){
    int f = j*256+t; int row = f>>4, seg = f&15;
    if(r0+row < n) *(int4*)&h3h[(size_t)(r0+row)*DD + seg*8] = *(int4*)&wt[row][seg*8];
  }
}

// ================= 16-lane-row gather helpers (pk_fma f16 accumulation) =================
__device__ __forceinline__ void spmm_row16_h(const int* __restrict__ rs, const int2* __restrict__ e1,
                                             const __half* __restrict__ h, int row, int l,
                                             f16x2 acc2[4]){
  int beg = rs[row], end = rs[row+1];
  #pragma unroll
  for(int q=0;q<4;++q) acc2[q] = (f16x2){(f16)0.f,(f16)0.f};
  for(int k=beg; k<end; k+=8){
    int2 cv[8];
    union{ uint4 v; f16x2 h2[4]; } hh[8];
    #pragma unroll
    for(int j=0;j<8;++j){ int kk = min(k+j, end-1); cv[j] = e1[kk]; }
    #pragma unroll
    for(int j=0;j<8;++j) hh[j].v = ((const uint4*)(h + (size_t)cv[j].x*DD))[l];
    #pragma unroll
    for(int j=0;j<8;++j){
      float v = (k+j<end)? __int_as_float(cv[j].y) : 0.f;
      f16 vh = (f16)v;
      f16x2 vv = {vh, vh};
      #pragma unroll
      for(int q=0;q<4;++q) acc2[q] += hh[j].h2[q]*vv;
    }
  }
}

__device__ __forceinline__ void attn_row16(const int* __restrict__ rs, const int* __restrict__ e2,
                                           const float* __restrict__ s1, const float* __restrict__ s2,
                                           const __half* __restrict__ mapped, __half* __restrict__ out,
                                           int row, int l){
  int beg = rs[row], end = rs[row+1];
  float s1r = s1[row];
  f16x2 a2[4];
  #pragma unroll
  for(int q=0;q<4;++q) a2[q] = (f16x2){(f16)0.f,(f16)0.f};
  float den = 0.f;
  for(int k=beg; k<end; k+=8){
    int cs[8]; float sv[8];
    union{ uint4 v; f16x2 h2[4]; } mh[8];
    #pragma unroll
    for(int j=0;j<8;++j){ int kk = min(k+j, end-1); cs[j] = e2[kk]; }
    #pragma unroll
    for(int j=0;j<8;++j) sv[j] = s2[cs[j]];
    #pragma unroll
    for(int j=0;j<8;++j) mh[j].v = ((const uint4*)(mapped + (size_t)cs[j]*DD))[l];
    #pragma unroll
    for(int j=0;j<8;++j){
      float e = s1r + sv[j]; e = (e>=0.f)? e : 0.2f*e;
      float ex = (k+j<end)? __expf(e) : 0.f;
      den += ex;
      f16 xh = (f16)ex;
      f16x2 xx = {xh, xh};
      #pragma unroll
      for(int q=0;q<4;++q) a2[q] += mh[j].h2[q]*xx;
    }
  }
  float inv = (end > beg) ? 1.0f/den : 0.0f;
  union{ uint4 v; __half2 h2[4]; } o;
  #pragma unroll
  for(int q=0;q<4;++q)
    o.h2[q] = __floats2half2_rn((float)a2[q].x*inv, (float)a2[q].y*inv);
  ((uint4*)(out + (size_t)row*DD))[l] = o.v;
}

// ================= merged aggregation 1: spmm(a1)->y1h AND attn->y2h (16 rows/block) =================
__global__ void k_agg1(const int* __restrict__ rs, const int2* __restrict__ e1,
                       const __half* __restrict__ h1h, const float* __restrict__ b1, __half* __restrict__ y1h,
                       const int* __restrict__ e2, const float* __restrict__ s1, const float* __restrict__ s2,
                       const __half* __restrict__ mapped, __half* __restrict__ y2h,
                       int n, int gT){
  int l = threadIdx.x & 15;
  if((int)blockIdx.x < gT){
    int row = blockIdx.x*16 + (threadIdx.x>>4);
    if(row>=n) return;
    f16x2 acc2[4];
    spmm_row16_h(rs, e1, h1h, row, l, acc2);
    float4 b0 = ((const float4*)b1)[2*l], bb1 = ((const float4*)b1)[2*l+1];
    union{ uint4 v; __half2 h2[4]; } o;
    o.h2[0] = __floats2half2_rn(tanhf((float)acc2[0].x+b0.x), tanhf((float)acc2[0].y+b0.y));
    o.h2[1] = __floats2half2_rn(tanhf((float)acc2[1].x+b0.z), tanhf((float)acc2[1].y+b0.w));
    o.h2[2] = __floats2half2_rn(tanhf((float)acc2[2].x+bb1.x), tanhf((float)acc2[2].y+bb1.y));
    o.h2[3] = __floats2half2_rn(tanhf((float)acc2[3].x+bb1.z), tanhf((float)acc2[3].y+bb1.w));
    ((uint4*)(y1h + (size_t)row*DD))[l] = o.v;
  } else {
    int row = (blockIdx.x-gT)*16 + (threadIdx.x>>4);
    if(row>=n) return;
    attn_row16(rs+(n+1), e2, s1, s2, mapped, y2h, row, l);
  }
}

// ================= spmm2 + final fused: y4 row -> l2norms -> output =================
__global__ void k_spmm_final(const int* __restrict__ rs, const int2* __restrict__ e1,
                             const __half* __restrict__ h, const float* __restrict__ bias,
                             const __half* __restrict__ y3, const float* __restrict__ x,
                             float* __restrict__ out, int n){
  int row = blockIdx.x*16 + (threadIdx.x>>4);
  if(row>=n) return;
  int l = threadIdx.x & 15;
  f16x2 acc2[4];
  spmm_row16_h(rs, e1, h, row, l, acc2);
  float4 b0 = ((const float4*)bias)[2*l], b1 = ((const float4*)bias)[2*l+1];
  float y4v[8];
  y4v[0]=tanhf((float)acc2[0].x+b0.x); y4v[1]=tanhf((float)acc2[0].y+b0.y);
  y4v[2]=tanhf((float)acc2[1].x+b0.z); y4v[3]=tanhf((float)acc2[1].y+b0.w);
  y4v[4]=tanhf((float)acc2[2].x+b1.x); y4v[5]=tanhf((float)acc2[2].y+b1.y);
  y4v[6]=tanhf((float)acc2[3].x+b1.z); y4v[7]=tanhf((float)acc2[3].y+b1.w);
  // load y3 row (8 f16) and x row (8 f32)
  union{ uint4 v; __half2 h2[4]; } y3u;
  y3u.v = ((const uint4*)(y3 + (size_t)row*DD))[l];
  float y3v[8];
  #pragma unroll
  for(int q=0;q<4;++q){
    float2 f = __half22float2(y3u.h2[q]);
    y3v[2*q] = f.x; y3v[2*q+1] = f.y;
  }
  const float* xp = x + (size_t)row*DD + l*8;
  float4 xa = *(const float4*)xp, xb = *(const float4*)(xp+4);
  float xv[8] = {xa.x,xa.y,xa.z,xa.w,xb.x,xb.y,xb.z,xb.w};
  float sa=0.f, sb=0.f, sc=0.f;
  #pragma unroll
  for(int q=0;q<8;++q){ sa += y3v[q]*y3v[q]; sb += y4v[q]*y4v[q]; sc += xv[q]*xv[q]; }
  #pragma unroll
  for(int off=1; off<16; off<<=1){
    sa += __shfl_xor(sa, off, 64);
    sb += __shfl_xor(sb, off, 64);
    sc += __shfl_xor(sc, off, 64);
  }
  float ia = rsqrtf(fmaxf(sa, 1e-12f));
  float ib = rsqrtf(fmaxf(sb, 1e-12f));
  float ic = rsqrtf(fmaxf(sc, 1e-12f));
  float tot = sa*ia*ia + sb*ib*ib + sc*ic*ic;
  float f = rsqrtf(fmaxf(tot, 1e-12f));
  float fa = ia*f, fb = ib*f, fc = ic*f;
  float* o = out + (size_t)row*(3*DD);
  *(float4*)(o + l*8)     = make_float4(y3v[0]*fa, y3v[1]*fa, y3v[2]*fa, y3v[3]*fa);
  *(float4*)(o + l*8 + 4) = make_float4(y3v[4]*fa, y3v[5]*fa, y3v[6]*fa, y3v[7]*fa);
  *(float4*)(o + DD + l*8)     = make_float4(y4v[0]*fb, y4v[1]*fb, y4v[2]*fb, y4v[3]*fb);
  *(float4*)(o + DD + l*8 + 4) = make_float4(y4v[4]*fb, y4v[5]*fb, y4v[6]*fb, y4v[7]*fb);
  *(float4*)(o + 2*DD + l*8)     = make_float4(xv[0]*fc, xv[1]*fc, xv[2]*fc, xv[3]*fc);
  *(float4*)(o + 2*DD + l*8 + 4) = make_float4(xv[4]*fc, xv[5]*fc, xv[6]*fc, xv[7]*fc);
}

// ================= launch =================
extern "C" void kernel_launch(void* const* d_in, const int* in_sizes, int n_in,
                              void* d_out, int out_size, void* d_ws, size_t ws_size,
                              hipStream_t stream){
  const float* x   = (const float*)d_in[0];
  const int*   a1r = (const int*)d_in[1];
  const int*   a1c = (const int*)d_in[2];
  const float* a1v = (const float*)d_in[3];
  const int*   a2r = (const int*)d_in[4];
  const int*   a2c = (const int*)d_in[5];
  const float* w1  = (const float*)d_in[7];
  const float* b1  = (const float*)d_in[8];
  const float* watt= (const float*)d_in[9];
  const float* m1  = (const float*)d_in[10];
  const float* m2  = (const float*)d_in[11];
  const float* whw = (const float*)d_in[12];
  const float* w2  = (const float*)d_in[13];
  const float* b2  = (const float*)d_in[14];

  const int N = in_sizes[0]/DD;
  const int E = in_sizes[1];
  const float BN = (float)(1.0/sqrt(1.0+1e-3));
  const size_t NB = (size_t)N*DD;

  int tile = 8192, nt = (E+tile-1)/tile;
  while(nt > 256){ tile <<= 1; nt = (E+tile-1)/tile; }
  const int nbk = (N + (1<<BSH) - 1) >> BSH;

  // workspace layout (f16 activations; st1/st2 dedicated)
  f16* Bh = (f16*)d_ws;             // h1h -> h3h
  f16* Ch = Bh + NB;                // mapped -> y3h
  f16* Dh = Ch + NB;                // y1h
  f16* Eh = Dh + NB;                // y2h
  f16* wh = Eh + NB;                // 6*16384
  float* s1 = (float*)(wh + 6*16384);   // N
  float* s2 = s1 + N;               // N
  int*  rs  = (int*)(s2 + N);       // 2*(N+1)
  uintptr_t pa = ((uintptr_t)(rs + 2*(N+1)) + 15) & ~(uintptr_t)15;
  int2* e1  = (int2*)pa;            // E
  int*  e2  = (int*)(e1 + E);       // E
  uintptr_t pb = ((uintptr_t)(e2 + E) + 15) & ~(uintptr_t)15;
  int2* st1 = (int2*)pb;            // E (dedicated)
  int*  st2 = (int*)(st1 + E);      // E (dedicated)
  int*  hist = st2 + E;             // 2*nt*256
  int*  colsum = hist + (size_t)2*nt*256; // 512
  int*  base = colsum + 512;        // 2*257

  const int gT = (N+15)/16;
  const int gM = (N+63)/64;
  float* out = (float*)d_out;

  // ---- wprep + hist (merged) ----
  k_ph<<<6+nt,256,0,stream>>>(w1, watt, m1, m2, whw, w2, wh, a1r, a2r, hist, E, tile, nt);

  // ---- scans ----
  k_colscan<<<512,256,0,stream>>>(hist, colsum, nt);
  k_basescan<<<1,512,0,stream>>>(colsum, base);

  // ---- partition + x-GEMMs (merged): st1/st2, h1h(Bh), mapped(Ch), s1, s2 ----
  k_px<<<nt+gM,256,0,stream>>>(a1r,a1c,a1v, a2r,a2c, hist, base, st1, st2, E, tile, nt,
                               x, wh, Bh, Ch, s1, s2, BN, BN*BN, N);

  // ---- CSR finalize ----
  k_csr_bucket<<<2*nbk,256,0,stream>>>(st1, st2, base, e1, e2, rs, N, nbk);

  // ---- merged aggregation: y1h(Dh) + y2h(Eh) ----
  k_agg1<<<2*gT,256,0,stream>>>(rs, e1, (const __half*)Bh, b1, (__half*)Dh,
                                e2, s1, s2, (const __half*)Ch, (__half*)Eh, N, gT);

  // ---- highway + gcn2 GEMMs: y3h(Ch), h3h(Bh) ----
  k_hw2<<<gM,256,0,stream>>>(Eh, Dh, wh, Ch, Bh, BN, N);

  // ---- GCN2 aggregate + final fused ----
  k_spmm_final<<<gT,256,0,stream>>>(rs, e1, (const __half*)Bh, b2,
                                    (const __half*)Ch, x, out, N);
}